// Round 1
// baseline (1096.919 us; speedup 1.0000x reference)
//
#include <hip/hip_runtime.h>
#include <cstddef>
#include <cstdint>

#define NEG_SLOPE 0.2f

// ---------------- CSR build ----------------

__global__ void init_cnt_k(int* cnt, int n) {
    int i = blockIdx.x * blockDim.x + threadIdx.x;
    if (i < n) cnt[i] = 1;   // self-loop pre-count
}

__global__ void hist_k(const int* __restrict__ dst, int E, int* __restrict__ cnt) {
    for (int e = blockIdx.x * blockDim.x + threadIdx.x; e < E; e += gridDim.x * blockDim.x)
        atomicAdd(&cnt[dst[e]], 1);
}

// single-block exclusive scan over n counts -> row_ptr[n+1], pos[n]
__global__ __launch_bounds__(1024) void scan_k(const int* __restrict__ cnt,
                                               int* __restrict__ row_ptr,
                                               int* __restrict__ pos, int n) {
    __shared__ int partial[1024];
    const int tid = threadIdx.x;
    const int chunk = (n + 1023) / 1024;
    const int lo = tid * chunk;
    const int hi = min(lo + chunk, n);
    int sum = 0;
    for (int i = lo; i < hi; ++i) sum += cnt[i];
    partial[tid] = sum;
    __syncthreads();
    // Hillis-Steele inclusive scan
    for (int o = 1; o < 1024; o <<= 1) {
        int v = (tid >= o) ? partial[tid - o] : 0;
        __syncthreads();
        partial[tid] += v;
        __syncthreads();
    }
    int run = (tid == 0) ? 0 : partial[tid - 1];
    for (int i = lo; i < hi; ++i) {
        int c = cnt[i];
        row_ptr[i] = run;
        pos[i] = run;
        run += c;
    }
    if (tid == 1023) row_ptr[n] = run;   // total = E + n
}

// scatter edges (and self loops) into CSR by dst
__global__ void scatter_k(const int* __restrict__ ei, int E, int n,
                          int* __restrict__ pos, int* __restrict__ col) {
    const int total = E + n;
    for (int e = blockIdx.x * blockDim.x + threadIdx.x; e < total; e += gridDim.x * blockDim.x) {
        int s, d;
        if (e < E) { s = ei[e]; d = ei[E + e]; }
        else       { s = e - E; d = s; }
        int p = atomicAdd(&pos[d], 1);
        col[p] = s;
    }
}

// ---------------- dense: h = x @ W, s_src = h.a_s, s_dst = h.a_d ----------------
// One sub-group of F lanes per node; W column cached in VGPRs; x read as
// wave-broadcast float4 (same address within sub-group -> single transaction).

template <int K, int F>
__launch_bounds__(256)
__global__ void gemm_dots_k(const float* __restrict__ x, const float* __restrict__ W,
                            const float* __restrict__ a_s, const float* __restrict__ a_d,
                            float* __restrict__ h, float* __restrict__ ss,
                            float* __restrict__ sd, int n) {
    constexpr int NPW = 64 / F;                 // nodes per wave
    const int lane = threadIdx.x & 63;
    const int sub  = lane / F;
    const int f    = lane % F;
    const int wave   = (blockIdx.x * blockDim.x + threadIdx.x) >> 6;
    const int nwaves = (gridDim.x * blockDim.x) >> 6;

    float wreg[K];
#pragma unroll
    for (int k = 0; k < K; ++k) wreg[k] = W[k * F + f];
    const float asf = a_s[f];
    const float adf = a_d[f];

    for (int node = wave * NPW + sub; node < n; node += nwaves * NPW) {
        const float4* xr = (const float4*)(x + (size_t)node * K);
        float acc = 0.f;
#pragma unroll
        for (int kq = 0; kq < K / 4; ++kq) {
            float4 xv = xr[kq];
            acc = fmaf(xv.x, wreg[4 * kq + 0], acc);
            acc = fmaf(xv.y, wreg[4 * kq + 1], acc);
            acc = fmaf(xv.z, wreg[4 * kq + 2], acc);
            acc = fmaf(xv.w, wreg[4 * kq + 3], acc);
        }
        h[(size_t)node * F + f] = acc;
        float vs = acc * asf;
        float vd = acc * adf;
#pragma unroll
        for (int o = F / 2; o; o >>= 1) {
            vs += __shfl_xor(vs, o);
            vd += __shfl_xor(vd, o);
        }
        if (f == 0) { ss[node] = vs; sd[node] = vd; }
    }
}

// ---------------- sparse: online-softmax attention aggregation ----------------
// One F-lane sub-group per dst node, lane = output channel. Single pass over
// the node's CSR edge list with flash-style (m, s, acc) rescaling.

template <int F, bool RELU, bool LOGSM>
__launch_bounds__(256)
__global__ void gat_agg_k(const int* __restrict__ row_ptr, const int* __restrict__ col,
                          const float* __restrict__ h, const float* __restrict__ ss,
                          const float* __restrict__ sd, const float* __restrict__ bias,
                          float* __restrict__ out, int n) {
    constexpr int NPW = 64 / F;
    const int lane = threadIdx.x & 63;
    const int sub  = lane / F;
    const int f    = lane % F;
    const int wave = (blockIdx.x * blockDim.x + threadIdx.x) >> 6;
    const int node = wave * NPW + sub;
    if (node >= n) return;

    const int beg = row_ptr[node];
    const int end = row_ptr[node + 1];
    const float sdv = sd[node];

    float m = -__builtin_inff();
    float s = 0.f;
    float acc = 0.f;

    for (int base = beg; base < end; base += F) {
        const int j = base + f;
        int   c = 0;
        float logit = -__builtin_inff();
        if (j < end) {
            c = col[j];
            float z = ss[c] + sdv;
            logit = (z > 0.f) ? z : NEG_SLOPE * z;
        }
        // chunk max across sub-group
        float cm = logit;
#pragma unroll
        for (int o = F / 2; o; o >>= 1) cm = fmaxf(cm, __shfl_xor(cm, o));
        const float newm = fmaxf(m, cm);
        const float scale = __expf(m - newm);      // first iter: exp(-inf)=0
        s *= scale;
        acc *= scale;
        const float w = __expf(logit - newm);      // inactive lanes -> 0
        float wsum = w;
#pragma unroll
        for (int o = F / 2; o; o >>= 1) wsum += __shfl_xor(wsum, o);
        s += wsum;
        m = newm;

        const int cnt = min(F, end - base);
        for (int t = 0; t < cnt; ++t) {
            const float wt = __shfl(w, sub * F + t);
            const int   ct = __shfl(c, sub * F + t);
            acc = fmaf(wt, h[(size_t)ct * F + f], acc);
        }
    }

    float val = acc / (s + 1e-16f) + bias[f];
    if (RELU) val = fmaxf(val, 0.f);
    if (LOGSM) {
        float lm = val;
#pragma unroll
        for (int o = F / 2; o; o >>= 1) lm = fmaxf(lm, __shfl_xor(lm, o));
        float ex = __expf(val - lm);
#pragma unroll
        for (int o = F / 2; o; o >>= 1) ex += __shfl_xor(ex, o);
        val = val - lm - __logf(ex);
    }
    out[(size_t)node * F + f] = val;
}

// ---------------- launch ----------------

extern "C" void kernel_launch(void* const* d_in, const int* in_sizes, int n_in,
                              void* d_out, int out_size, void* d_ws, size_t ws_size,
                              hipStream_t stream) {
    const float* x  = (const float*)d_in[0];
    const int*   ei = (const int*)d_in[1];
    const float* W1 = (const float*)d_in[2];
    const float* a1s = (const float*)d_in[3];
    const float* a1d = (const float*)d_in[4];
    const float* b1  = (const float*)d_in[5];
    const float* W2 = (const float*)d_in[6];
    const float* a2s = (const float*)d_in[7];
    const float* a2d = (const float*)d_in[8];
    const float* b2  = (const float*)d_in[9];
    const float* W3 = (const float*)d_in[10];
    const float* a3s = (const float*)d_in[11];
    const float* a3d = (const float*)d_in[12];
    const float* b3  = (const float*)d_in[13];

    const int N = in_sizes[0] / 128;
    const int E = in_sizes[1] / 2;

    // workspace layout (256B aligned)
    char* wp = (char*)d_ws;
    auto alloc = [&](size_t bytes) -> void* {
        void* p = wp;
        wp += (bytes + 255) & ~(size_t)255;
        return p;
    };
    int* cnt     = (int*)alloc((size_t)N * 4);
    int* row_ptr = (int*)alloc((size_t)(N + 1) * 4);
    int* pos     = (int*)alloc((size_t)N * 4);
    int* col     = (int*)alloc((size_t)(E + N) * 4);
    float* h   = (float*)alloc((size_t)N * 64 * 4);
    float* ss  = (float*)alloc((size_t)N * 4);
    float* sd  = (float*)alloc((size_t)N * 4);
    float* o1  = (float*)alloc((size_t)N * 64 * 4);
    float* o2  = (float*)alloc((size_t)N * 64 * 4);

    // --- CSR build (dst-sorted, self-loops included) ---
    init_cnt_k<<<(N + 255) / 256, 256, 0, stream>>>(cnt, N);
    hist_k<<<2048, 256, 0, stream>>>(ei + E, E, cnt);
    scan_k<<<1, 1024, 0, stream>>>(cnt, row_ptr, pos, N);
    scatter_k<<<2048, 256, 0, stream>>>(ei, E, N, pos, col);

    const int GEMM_BLOCKS = 1024;

    // --- layer 1: 128 -> 64, relu ---
    gemm_dots_k<128, 64><<<GEMM_BLOCKS, 256, 0, stream>>>(x, W1, a1s, a1d, h, ss, sd, N);
    gat_agg_k<64, true, false><<<(N + 3) / 4, 256, 0, stream>>>(row_ptr, col, h, ss, sd, b1, o1, N);

    // --- layer 2: 64 -> 64, relu ---
    gemm_dots_k<64, 64><<<GEMM_BLOCKS, 256, 0, stream>>>(o1, W2, a2s, a2d, h, ss, sd, N);
    gat_agg_k<64, true, false><<<(N + 3) / 4, 256, 0, stream>>>(row_ptr, col, h, ss, sd, b2, o2, N);

    // --- layer 3: 64 -> 32, log_softmax ---
    gemm_dots_k<64, 32><<<GEMM_BLOCKS, 256, 0, stream>>>(o2, W3, a3s, a3d, h, ss, sd, N);
    gat_agg_k<32, false, true><<<(N + 7) / 8, 256, 0, stream>>>(row_ptr, col, h, ss, sd, b3,
                                                                (float*)d_out, N);
}

// Round 2
// 855.756 us; speedup vs baseline: 1.2818x; 1.2818x over previous
//
#include <hip/hip_runtime.h>
#include <cstddef>
#include <cstdint>

#define NEG_SLOPE 0.2f

// ---------------- CSR build ----------------

__global__ void init_cnt_k(int* cnt, int n) {
    int i = blockIdx.x * blockDim.x + threadIdx.x;
    if (i < n) cnt[i] = 1;   // self-loop pre-count
}

__global__ void hist_k(const int* __restrict__ dst, int E, int* __restrict__ cnt) {
    for (int e = blockIdx.x * blockDim.x + threadIdx.x; e < E; e += gridDim.x * blockDim.x)
        atomicAdd(&cnt[dst[e]], 1);
}

// ---- hierarchical exclusive scan: cnt[n] -> row_ptr[n+1], pos[n] ----
// pass1: per-block (1024-elem tile) sums; pass2: scan block sums (single tiny
// block); pass3: per-block scan + apply offset.

constexpr int SCAN_TILE = 1024;   // 256 threads x 4 elems

__global__ __launch_bounds__(256) void scan_pass1(const int* __restrict__ cnt,
                                                  int* __restrict__ bsum, int n) {
    const int tid = threadIdx.x;
    const int base = blockIdx.x * SCAN_TILE + tid * 4;
    int s = 0;
#pragma unroll
    for (int k = 0; k < 4; ++k) {
        int i = base + k;
        if (i < n) s += cnt[i];
    }
    for (int o = 1; o < 64; o <<= 1) s += __shfl_xor(s, o);
    __shared__ int wsum[4];
    if ((tid & 63) == 0) wsum[tid >> 6] = s;
    __syncthreads();
    if (tid == 0) bsum[blockIdx.x] = wsum[0] + wsum[1] + wsum[2] + wsum[3];
}

__global__ __launch_bounds__(256) void scan_pass2(int* __restrict__ bsum,
                                                  int* __restrict__ row_ptr,
                                                  int nb, int n) {
    __shared__ int sh[1024];
    const int tid = threadIdx.x;
    for (int i = tid; i < nb; i += 256) sh[i] = bsum[i];
    __syncthreads();
    if (tid == 0) {                      // nb ~ 98: serial in LDS is fine
        int run = 0;
        for (int i = 0; i < nb; ++i) { int c = sh[i]; sh[i] = run; run += c; }
        row_ptr[n] = run;                // grand total = E + n
    }
    __syncthreads();
    for (int i = tid; i < nb; i += 256) bsum[i] = sh[i];
}

__global__ __launch_bounds__(256) void scan_pass3(const int* __restrict__ cnt,
                                                  const int* __restrict__ bsum,
                                                  int* __restrict__ row_ptr,
                                                  int* __restrict__ pos, int n) {
    const int tid = threadIdx.x;
    const int lane = tid & 63;
    const int wid = tid >> 6;
    const int base = blockIdx.x * SCAN_TILE + tid * 4;
    int v[4];
    int tsum = 0;
#pragma unroll
    for (int k = 0; k < 4; ++k) {
        int i = base + k;
        v[k] = (i < n) ? cnt[i] : 0;
        tsum += v[k];
    }
    int inc = tsum;                      // inclusive wave scan
    for (int o = 1; o < 64; o <<= 1) {
        int t = __shfl_up(inc, o);
        if (lane >= o) inc += t;
    }
    __shared__ int wtot[4];
    if (lane == 63) wtot[wid] = inc;
    __syncthreads();
    int woff = 0;
    for (int w = 0; w < wid; ++w) woff += wtot[w];
    int off = bsum[blockIdx.x] + woff + (inc - tsum);
#pragma unroll
    for (int k = 0; k < 4; ++k) {
        int i = base + k;
        if (i < n) { row_ptr[i] = off; pos[i] = off; off += v[k]; }
    }
}

// scatter edges (and self loops) into CSR by dst
__global__ void scatter_k(const int* __restrict__ ei, int E, int n,
                          int* __restrict__ pos, int* __restrict__ col) {
    const int total = E + n;
    for (int e = blockIdx.x * blockDim.x + threadIdx.x; e < total; e += gridDim.x * blockDim.x) {
        int s, d;
        if (e < E) { s = ei[e]; d = ei[E + e]; }
        else       { s = e - E; d = s; }
        int p = atomicAdd(&pos[d], 1);
        col[p] = s;
    }
}

// ---------------- dense: h = x @ W, s_src = h.a_s, s_dst = h.a_d ----------------

template <int K, int F>
__launch_bounds__(256)
__global__ void gemm_dots_k(const float* __restrict__ x, const float* __restrict__ W,
                            const float* __restrict__ a_s, const float* __restrict__ a_d,
                            float* __restrict__ h, float* __restrict__ ss,
                            float* __restrict__ sd, int n) {
    constexpr int NPW = 64 / F;                 // nodes per wave
    const int lane = threadIdx.x & 63;
    const int sub  = lane / F;
    const int f    = lane % F;
    const int wave   = (blockIdx.x * blockDim.x + threadIdx.x) >> 6;
    const int nwaves = (gridDim.x * blockDim.x) >> 6;

    float wreg[K];
#pragma unroll
    for (int k = 0; k < K; ++k) wreg[k] = W[k * F + f];
    const float asf = a_s[f];
    const float adf = a_d[f];

    for (int node = wave * NPW + sub; node < n; node += nwaves * NPW) {
        const float4* xr = (const float4*)(x + (size_t)node * K);
        float acc = 0.f;
#pragma unroll
        for (int kq = 0; kq < K / 4; ++kq) {
            float4 xv = xr[kq];
            acc = fmaf(xv.x, wreg[4 * kq + 0], acc);
            acc = fmaf(xv.y, wreg[4 * kq + 1], acc);
            acc = fmaf(xv.z, wreg[4 * kq + 2], acc);
            acc = fmaf(xv.w, wreg[4 * kq + 3], acc);
        }
        h[(size_t)node * F + f] = acc;
        float vs = acc * asf;
        float vd = acc * adf;
#pragma unroll
        for (int o = F / 2; o; o >>= 1) {
            vs += __shfl_xor(vs, o);
            vd += __shfl_xor(vd, o);
        }
        if (f == 0) { ss[node] = vs; sd[node] = vd; }
    }
}

// ---------------- sparse: online-softmax attention aggregation ----------------

template <int F, bool RELU, bool LOGSM>
__launch_bounds__(256)
__global__ void gat_agg_k(const int* __restrict__ row_ptr, const int* __restrict__ col,
                          const float* __restrict__ h, const float* __restrict__ ss,
                          const float* __restrict__ sd, const float* __restrict__ bias,
                          float* __restrict__ out, int n) {
    constexpr int NPW = 64 / F;
    const int lane = threadIdx.x & 63;
    const int sub  = lane / F;
    const int f    = lane % F;
    const int wave = (blockIdx.x * blockDim.x + threadIdx.x) >> 6;
    const int node = wave * NPW + sub;
    if (node >= n) return;

    const int beg = row_ptr[node];
    const int end = row_ptr[node + 1];
    const float sdv = sd[node];

    float m = -__builtin_inff();
    float s = 0.f;
    float acc = 0.f;

    for (int base = beg; base < end; base += F) {
        const int j = base + f;
        int   c = 0;
        float logit = -__builtin_inff();
        if (j < end) {
            c = col[j];
            float z = ss[c] + sdv;
            logit = (z > 0.f) ? z : NEG_SLOPE * z;
        }
        float cm = logit;
#pragma unroll
        for (int o = F / 2; o; o >>= 1) cm = fmaxf(cm, __shfl_xor(cm, o));
        const float newm = fmaxf(m, cm);
        const float scale = __expf(m - newm);      // first iter: exp(-inf)=0
        s *= scale;
        acc *= scale;
        const float w = __expf(logit - newm);      // inactive lanes -> 0
        float wsum = w;
#pragma unroll
        for (int o = F / 2; o; o >>= 1) wsum += __shfl_xor(wsum, o);
        s += wsum;
        m = newm;

        const int cnt = min(F, end - base);
        for (int t = 0; t < cnt; ++t) {
            const float wt = __shfl(w, sub * F + t);
            const int   ct = __shfl(c, sub * F + t);
            acc = fmaf(wt, h[(size_t)ct * F + f], acc);
        }
    }

    float val = acc / (s + 1e-16f) + bias[f];
    if (RELU) val = fmaxf(val, 0.f);
    if (LOGSM) {
        float lm = val;
#pragma unroll
        for (int o = F / 2; o; o >>= 1) lm = fmaxf(lm, __shfl_xor(lm, o));
        float ex = __expf(val - lm);
#pragma unroll
        for (int o = F / 2; o; o >>= 1) ex += __shfl_xor(ex, o);
        val = val - lm - __logf(ex);
    }
    out[(size_t)node * F + f] = val;
}

// ---------------- launch ----------------

extern "C" void kernel_launch(void* const* d_in, const int* in_sizes, int n_in,
                              void* d_out, int out_size, void* d_ws, size_t ws_size,
                              hipStream_t stream) {
    const float* x  = (const float*)d_in[0];
    const int*   ei = (const int*)d_in[1];
    const float* W1 = (const float*)d_in[2];
    const float* a1s = (const float*)d_in[3];
    const float* a1d = (const float*)d_in[4];
    const float* b1  = (const float*)d_in[5];
    const float* W2 = (const float*)d_in[6];
    const float* a2s = (const float*)d_in[7];
    const float* a2d = (const float*)d_in[8];
    const float* b2  = (const float*)d_in[9];
    const float* W3 = (const float*)d_in[10];
    const float* a3s = (const float*)d_in[11];
    const float* a3d = (const float*)d_in[12];
    const float* b3  = (const float*)d_in[13];

    const int N = in_sizes[0] / 128;
    const int E = in_sizes[1] / 2;

    // workspace layout (256B aligned)
    char* wp = (char*)d_ws;
    auto alloc = [&](size_t bytes) -> void* {
        void* p = wp;
        wp += (bytes + 255) & ~(size_t)255;
        return p;
    };
    int* cnt     = (int*)alloc((size_t)N * 4);
    int* row_ptr = (int*)alloc((size_t)(N + 1) * 4);
    int* pos     = (int*)alloc((size_t)N * 4);
    int* col     = (int*)alloc((size_t)(E + N) * 4);
    float* h   = (float*)alloc((size_t)N * 64 * 4);
    float* ss  = (float*)alloc((size_t)N * 4);
    float* sd  = (float*)alloc((size_t)N * 4);
    float* o1  = (float*)alloc((size_t)N * 64 * 4);
    float* o2  = (float*)alloc((size_t)N * 64 * 4);
    const int NB = (N + SCAN_TILE - 1) / SCAN_TILE;
    int* bsum  = (int*)alloc((size_t)NB * 4);

    // --- CSR build (dst-sorted, self-loops included) ---
    init_cnt_k<<<(N + 255) / 256, 256, 0, stream>>>(cnt, N);
    hist_k<<<2048, 256, 0, stream>>>(ei + E, E, cnt);
    scan_pass1<<<NB, 256, 0, stream>>>(cnt, bsum, N);
    scan_pass2<<<1, 256, 0, stream>>>(bsum, row_ptr, NB, N);
    scan_pass3<<<NB, 256, 0, stream>>>(cnt, bsum, row_ptr, pos, N);
    scatter_k<<<2048, 256, 0, stream>>>(ei, E, N, pos, col);

    const int GEMM_BLOCKS = 1024;

    // --- layer 1: 128 -> 64, relu ---
    gemm_dots_k<128, 64><<<GEMM_BLOCKS, 256, 0, stream>>>(x, W1, a1s, a1d, h, ss, sd, N);
    gat_agg_k<64, true, false><<<(N + 3) / 4, 256, 0, stream>>>(row_ptr, col, h, ss, sd, b1, o1, N);

    // --- layer 2: 64 -> 64, relu ---
    gemm_dots_k<64, 64><<<GEMM_BLOCKS, 256, 0, stream>>>(o1, W2, a2s, a2d, h, ss, sd, N);
    gat_agg_k<64, true, false><<<(N + 3) / 4, 256, 0, stream>>>(row_ptr, col, h, ss, sd, b2, o2, N);

    // --- layer 3: 64 -> 32, log_softmax ---
    gemm_dots_k<64, 32><<<GEMM_BLOCKS, 256, 0, stream>>>(o2, W3, a3s, a3d, h, ss, sd, N);
    gat_agg_k<32, false, true><<<(N + 7) / 8, 256, 0, stream>>>(row_ptr, col, h, ss, sd, b3,
                                                                (float*)d_out, N);
}

// Round 3
// 683.009 us; speedup vs baseline: 1.6060x; 1.2529x over previous
//
#include <hip/hip_runtime.h>
#include <cstddef>
#include <cstdint>

#define NEG_SLOPE 0.2f

// ---------------- CSR build ----------------

__global__ void init_cnt_k(int* cnt, int n) {
    int i = blockIdx.x * blockDim.x + threadIdx.x;
    if (i < n) cnt[i] = 1;   // self-loop pre-count
}

__global__ void hist_k(const int* __restrict__ dst, int E, int* __restrict__ cnt) {
    for (int e = blockIdx.x * blockDim.x + threadIdx.x; e < E; e += gridDim.x * blockDim.x)
        atomicAdd(&cnt[dst[e]], 1);
}

// ---- hierarchical exclusive scan: cnt[n] -> row_ptr[n+1], pos[n] ----

constexpr int SCAN_TILE = 1024;   // 256 threads x 4 elems

__global__ __launch_bounds__(256) void scan_pass1(const int* __restrict__ cnt,
                                                  int* __restrict__ bsum, int n) {
    const int tid = threadIdx.x;
    const int base = blockIdx.x * SCAN_TILE + tid * 4;
    int s = 0;
#pragma unroll
    for (int k = 0; k < 4; ++k) {
        int i = base + k;
        if (i < n) s += cnt[i];
    }
    for (int o = 1; o < 64; o <<= 1) s += __shfl_xor(s, o);
    __shared__ int wsum[4];
    if ((tid & 63) == 0) wsum[tid >> 6] = s;
    __syncthreads();
    if (tid == 0) bsum[blockIdx.x] = wsum[0] + wsum[1] + wsum[2] + wsum[3];
}

__global__ __launch_bounds__(256) void scan_pass2(int* __restrict__ bsum,
                                                  int* __restrict__ row_ptr,
                                                  int nb, int n) {
    __shared__ int sh[1024];
    const int tid = threadIdx.x;
    for (int i = tid; i < nb; i += 256) sh[i] = bsum[i];
    __syncthreads();
    if (tid == 0) {                      // nb ~ 98: serial in LDS is fine
        int run = 0;
        for (int i = 0; i < nb; ++i) { int c = sh[i]; sh[i] = run; run += c; }
        row_ptr[n] = run;                // grand total = E + n
    }
    __syncthreads();
    for (int i = tid; i < nb; i += 256) bsum[i] = sh[i];
}

__global__ __launch_bounds__(256) void scan_pass3(const int* __restrict__ cnt,
                                                  const int* __restrict__ bsum,
                                                  int* __restrict__ row_ptr,
                                                  int* __restrict__ pos, int n) {
    const int tid = threadIdx.x;
    const int lane = tid & 63;
    const int wid = tid >> 6;
    const int base = blockIdx.x * SCAN_TILE + tid * 4;
    int v[4];
    int tsum = 0;
#pragma unroll
    for (int k = 0; k < 4; ++k) {
        int i = base + k;
        v[k] = (i < n) ? cnt[i] : 0;
        tsum += v[k];
    }
    int inc = tsum;                      // inclusive wave scan
    for (int o = 1; o < 64; o <<= 1) {
        int t = __shfl_up(inc, o);
        if (lane >= o) inc += t;
    }
    __shared__ int wtot[4];
    if (lane == 63) wtot[wid] = inc;
    __syncthreads();
    int woff = 0;
    for (int w = 0; w < wid; ++w) woff += wtot[w];
    int off = bsum[blockIdx.x] + woff + (inc - tsum);
#pragma unroll
    for (int k = 0; k < 4; ++k) {
        int i = base + k;
        if (i < n) { row_ptr[i] = off; pos[i] = off; off += v[k]; }
    }
}

// scatter edges (and self loops) into CSR by dst
__global__ void scatter_k(const int* __restrict__ ei, int E, int n,
                          int* __restrict__ pos, int* __restrict__ col) {
    const int total = E + n;
    for (int e = blockIdx.x * blockDim.x + threadIdx.x; e < total; e += gridDim.x * blockDim.x) {
        int s, d;
        if (e < E) { s = ei[e]; d = ei[E + e]; }
        else       { s = e - E; d = s; }
        int p = atomicAdd(&pos[d], 1);
        col[p] = s;
    }
}

// ---------------- dense: LDS-tiled GEMM + fused attention dots ----------------
// h = x @ W, ss = h.a_s, sd = h.a_d.
// Block = 256 threads; tile = MT nodes x F channels; K chunked at KC=64.
// Each thread: 4 nodes x 4 channels micro-tile, float4 reads along K.
// xs padded +4 floats -> a-reads are 2-way bank aliased (free, m136).

template <int K, int F>
__launch_bounds__(256)
__global__ void gemm_tile_k(const float* __restrict__ x, const float* __restrict__ W,
                            const float* __restrict__ a_s, const float* __restrict__ a_d,
                            float* __restrict__ h, float* __restrict__ ss,
                            float* __restrict__ sd, int n) {
    constexpr int KC = 64;
    constexpr int NCHUNK = K / KC;
    constexpr int CG = F / 4;            // col groups (16 or 8)
    constexpr int MT = 256 / CG * 4;     // 64 nodes (F=64) or 128 (F=32)
    constexpr int XS_STRIDE = KC + 4;

    __shared__ float xs[MT][XS_STRIDE];
    __shared__ float ws[KC][F];

    const int tid = threadIdx.x;
    const int cg = tid % CG;             // channel group: cols 4*cg..4*cg+3
    const int rg = tid / CG;             // row group: rows 4*rg..4*rg+3
    const int base = blockIdx.x * MT;

    float4 acc[4];
#pragma unroll
    for (int i = 0; i < 4; ++i) acc[i] = make_float4(0.f, 0.f, 0.f, 0.f);

    for (int kc = 0; kc < NCHUNK; ++kc) {
        // stage x chunk: MT x KC, coalesced float4
#pragma unroll
        for (int i = 0; i < MT * KC / 4 / 256; ++i) {
            int flat = tid + i * 256;
            int row = flat / (KC / 4);
            int c4 = flat % (KC / 4);
            float4 v = make_float4(0.f, 0.f, 0.f, 0.f);
            if (base + row < n)
                v = *(const float4*)&x[(size_t)(base + row) * K + kc * KC + 4 * c4];
            *(float4*)&xs[row][4 * c4] = v;
        }
        // stage W chunk: KC x F, coalesced float4
#pragma unroll
        for (int i = 0; i < KC * F / 4 / 256; ++i) {
            int flat = tid + i * 256;
            int wrow = flat / (F / 4);
            int wc4 = flat % (F / 4);
            *(float4*)&ws[wrow][4 * wc4] =
                *(const float4*)&W[(size_t)(kc * KC + wrow) * F + 4 * wc4];
        }
        __syncthreads();

#pragma unroll
        for (int k = 0; k < KC; k += 4) {
            float4 w0 = *(const float4*)&ws[k + 0][cg * 4];
            float4 w1 = *(const float4*)&ws[k + 1][cg * 4];
            float4 w2 = *(const float4*)&ws[k + 2][cg * 4];
            float4 w3 = *(const float4*)&ws[k + 3][cg * 4];
#pragma unroll
            for (int i = 0; i < 4; ++i) {
                float4 a = *(const float4*)&xs[rg * 4 + i][k];
                acc[i].x = fmaf(a.x, w0.x, acc[i].x);
                acc[i].y = fmaf(a.x, w0.y, acc[i].y);
                acc[i].z = fmaf(a.x, w0.z, acc[i].z);
                acc[i].w = fmaf(a.x, w0.w, acc[i].w);
                acc[i].x = fmaf(a.y, w1.x, acc[i].x);
                acc[i].y = fmaf(a.y, w1.y, acc[i].y);
                acc[i].z = fmaf(a.y, w1.z, acc[i].z);
                acc[i].w = fmaf(a.y, w1.w, acc[i].w);
                acc[i].x = fmaf(a.z, w2.x, acc[i].x);
                acc[i].y = fmaf(a.z, w2.y, acc[i].y);
                acc[i].z = fmaf(a.z, w2.z, acc[i].z);
                acc[i].w = fmaf(a.z, w2.w, acc[i].w);
                acc[i].x = fmaf(a.w, w3.x, acc[i].x);
                acc[i].y = fmaf(a.w, w3.y, acc[i].y);
                acc[i].z = fmaf(a.w, w3.z, acc[i].z);
                acc[i].w = fmaf(a.w, w3.w, acc[i].w);
            }
        }
        __syncthreads();
    }

    // epilogue: write h rows, fused ss/sd dots
    const float4 as4 = *(const float4*)&a_s[4 * cg];
    const float4 ad4 = *(const float4*)&a_d[4 * cg];
#pragma unroll
    for (int i = 0; i < 4; ++i) {
        const int node = base + rg * 4 + i;
        float ps = acc[i].x * as4.x + acc[i].y * as4.y + acc[i].z * as4.z + acc[i].w * as4.w;
        float pd = acc[i].x * ad4.x + acc[i].y * ad4.y + acc[i].z * ad4.z + acc[i].w * ad4.w;
#pragma unroll
        for (int o = CG / 2; o; o >>= 1) {
            ps += __shfl_xor(ps, o);
            pd += __shfl_xor(pd, o);
        }
        if (node < n) {
            *(float4*)&h[(size_t)node * F + 4 * cg] = acc[i];
            if (cg == 0) { ss[node] = ps; sd[node] = pd; }
        }
    }
}

// ---------------- sparse: online-softmax attention aggregation ----------------

template <int F, bool RELU, bool LOGSM>
__launch_bounds__(256)
__global__ void gat_agg_k(const int* __restrict__ row_ptr, const int* __restrict__ col,
                          const float* __restrict__ h, const float* __restrict__ ss,
                          const float* __restrict__ sd, const float* __restrict__ bias,
                          float* __restrict__ out, int n) {
    constexpr int NPW = 64 / F;
    const int lane = threadIdx.x & 63;
    const int sub  = lane / F;
    const int f    = lane % F;
    const int wave = (blockIdx.x * blockDim.x + threadIdx.x) >> 6;
    const int node = wave * NPW + sub;
    if (node >= n) return;

    const int beg = row_ptr[node];
    const int end = row_ptr[node + 1];
    const float sdv = sd[node];

    float m = -__builtin_inff();
    float s = 0.f;
    float acc = 0.f;

    for (int base = beg; base < end; base += F) {
        const int j = base + f;
        int   c = 0;
        float logit = -__builtin_inff();
        if (j < end) {
            c = col[j];
            float z = ss[c] + sdv;
            logit = (z > 0.f) ? z : NEG_SLOPE * z;
        }
        float cm = logit;
#pragma unroll
        for (int o = F / 2; o; o >>= 1) cm = fmaxf(cm, __shfl_xor(cm, o));
        const float newm = fmaxf(m, cm);
        const float scale = __expf(m - newm);      // first iter: exp(-inf)=0
        s *= scale;
        acc *= scale;
        const float w = __expf(logit - newm);      // inactive lanes -> 0
        float wsum = w;
#pragma unroll
        for (int o = F / 2; o; o >>= 1) wsum += __shfl_xor(wsum, o);
        s += wsum;
        m = newm;

        const int cnt = min(F, end - base);
        for (int t = 0; t < cnt; ++t) {
            const float wt = __shfl(w, sub * F + t);
            const int   ct = __shfl(c, sub * F + t);
            acc = fmaf(wt, h[(size_t)ct * F + f], acc);
        }
    }

    float val = acc / (s + 1e-16f) + bias[f];
    if (RELU) val = fmaxf(val, 0.f);
    if (LOGSM) {
        float lm = val;
#pragma unroll
        for (int o = F / 2; o; o >>= 1) lm = fmaxf(lm, __shfl_xor(lm, o));
        float ex = __expf(val - lm);
#pragma unroll
        for (int o = F / 2; o; o >>= 1) ex += __shfl_xor(ex, o);
        val = val - lm - __logf(ex);
    }
    out[(size_t)node * F + f] = val;
}

// ---------------- launch ----------------

extern "C" void kernel_launch(void* const* d_in, const int* in_sizes, int n_in,
                              void* d_out, int out_size, void* d_ws, size_t ws_size,
                              hipStream_t stream) {
    const float* x  = (const float*)d_in[0];
    const int*   ei = (const int*)d_in[1];
    const float* W1 = (const float*)d_in[2];
    const float* a1s = (const float*)d_in[3];
    const float* a1d = (const float*)d_in[4];
    const float* b1  = (const float*)d_in[5];
    const float* W2 = (const float*)d_in[6];
    const float* a2s = (const float*)d_in[7];
    const float* a2d = (const float*)d_in[8];
    const float* b2  = (const float*)d_in[9];
    const float* W3 = (const float*)d_in[10];
    const float* a3s = (const float*)d_in[11];
    const float* a3d = (const float*)d_in[12];
    const float* b3  = (const float*)d_in[13];

    const int N = in_sizes[0] / 128;
    const int E = in_sizes[1] / 2;

    // workspace layout (256B aligned)
    char* wp = (char*)d_ws;
    auto alloc = [&](size_t bytes) -> void* {
        void* p = wp;
        wp += (bytes + 255) & ~(size_t)255;
        return p;
    };
    int* cnt     = (int*)alloc((size_t)N * 4);
    int* row_ptr = (int*)alloc((size_t)(N + 1) * 4);
    int* pos     = (int*)alloc((size_t)N * 4);
    int* col     = (int*)alloc((size_t)(E + N) * 4);
    float* h   = (float*)alloc((size_t)N * 64 * 4);
    float* ss  = (float*)alloc((size_t)N * 4);
    float* sd  = (float*)alloc((size_t)N * 4);
    float* o1  = (float*)alloc((size_t)N * 64 * 4);
    float* o2  = (float*)alloc((size_t)N * 64 * 4);
    const int NB = (N + SCAN_TILE - 1) / SCAN_TILE;
    int* bsum  = (int*)alloc((size_t)NB * 4);

    // --- CSR build (dst-sorted, self-loops included) ---
    init_cnt_k<<<(N + 255) / 256, 256, 0, stream>>>(cnt, N);
    hist_k<<<2048, 256, 0, stream>>>(ei + E, E, cnt);
    scan_pass1<<<NB, 256, 0, stream>>>(cnt, bsum, N);
    scan_pass2<<<1, 256, 0, stream>>>(bsum, row_ptr, NB, N);
    scan_pass3<<<NB, 256, 0, stream>>>(cnt, bsum, row_ptr, pos, N);
    scatter_k<<<2048, 256, 0, stream>>>(ei, E, N, pos, col);

    // --- layer 1: 128 -> 64, relu ---
    gemm_tile_k<128, 64><<<(N + 63) / 64, 256, 0, stream>>>(x, W1, a1s, a1d, h, ss, sd, N);
    gat_agg_k<64, true, false><<<(N + 3) / 4, 256, 0, stream>>>(row_ptr, col, h, ss, sd, b1, o1, N);

    // --- layer 2: 64 -> 64, relu ---
    gemm_tile_k<64, 64><<<(N + 63) / 64, 256, 0, stream>>>(o1, W2, a2s, a2d, h, ss, sd, N);
    gat_agg_k<64, true, false><<<(N + 3) / 4, 256, 0, stream>>>(row_ptr, col, h, ss, sd, b2, o2, N);

    // --- layer 3: 64 -> 32, log_softmax ---
    gemm_tile_k<64, 32><<<(N + 127) / 128, 256, 0, stream>>>(o2, W3, a3s, a3d, h, ss, sd, N);
    gat_agg_k<32, false, true><<<(N + 7) / 8, 256, 0, stream>>>(row_ptr, col, h, ss, sd, b3,
                                                                (float*)d_out, N);
}

// Round 4
// 551.682 us; speedup vs baseline: 1.9883x; 1.2380x over previous
//
#include <hip/hip_runtime.h>
#include <cstddef>
#include <cstdint>

#define NEG_SLOPE 0.2f

// ---------------- hierarchical exclusive scan: in[n] -> out[n+1] ----------------
// pass1: per-1024-tile sums; pass2: scan tile sums (1 block, writes total to
// out[n]); pass3: per-tile scan + offset apply.

constexpr int SCAN_TILE = 1024;   // 256 threads x 4 elems

__global__ __launch_bounds__(256) void scan_pass1(const int* __restrict__ in,
                                                  int* __restrict__ bsum, int n) {
    const int tid = threadIdx.x;
    const int base = blockIdx.x * SCAN_TILE + tid * 4;
    int s = 0;
#pragma unroll
    for (int k = 0; k < 4; ++k) {
        int i = base + k;
        if (i < n) s += in[i];
    }
    for (int o = 1; o < 64; o <<= 1) s += __shfl_xor(s, o);
    __shared__ int wsum[4];
    if ((tid & 63) == 0) wsum[tid >> 6] = s;
    __syncthreads();
    if (tid == 0) bsum[blockIdx.x] = wsum[0] + wsum[1] + wsum[2] + wsum[3];
}

__global__ __launch_bounds__(256) void scan_pass2(int* __restrict__ bsum,
                                                  int* __restrict__ out,
                                                  int nb, int n) {
    __shared__ int sh[1024];
    const int tid = threadIdx.x;
    for (int i = tid; i < nb; i += 256) sh[i] = bsum[i];
    __syncthreads();
    if (tid == 0) {                      // nb <= ~100: serial in LDS is fine
        int run = 0;
        for (int i = 0; i < nb; ++i) { int c = sh[i]; sh[i] = run; run += c; }
        out[n] = run;                    // grand total
    }
    __syncthreads();
    for (int i = tid; i < nb; i += 256) bsum[i] = sh[i];
}

__global__ __launch_bounds__(256) void scan_pass3(const int* __restrict__ in,
                                                  const int* __restrict__ bsum,
                                                  int* __restrict__ out, int n) {
    const int tid = threadIdx.x;
    const int lane = tid & 63;
    const int wid = tid >> 6;
    const int base = blockIdx.x * SCAN_TILE + tid * 4;
    int v[4];
    int tsum = 0;
#pragma unroll
    for (int k = 0; k < 4; ++k) {
        int i = base + k;
        v[k] = (i < n) ? in[i] : 0;
        tsum += v[k];
    }
    int inc = tsum;                      // inclusive wave scan
    for (int o = 1; o < 64; o <<= 1) {
        int t = __shfl_up(inc, o);
        if (lane >= o) inc += t;
    }
    __shared__ int wtot[4];
    if (lane == 63) wtot[wid] = inc;
    __syncthreads();
    int woff = 0;
    for (int w = 0; w < wid; ++w) woff += wtot[w];
    int off = bsum[blockIdx.x] + woff + (inc - tsum);
#pragma unroll
    for (int k = 0; k < 4; ++k) {
        int i = base + k;
        if (i < n) { out[i] = off; off += v[k]; }
    }
}

// ---------------- binned CSR build ----------------
// Bucket = dst >> 7 (128 nodes/bucket). Edges packed (src<<7)|dstLow (src<2^17).
// Writes are per-block contiguous slices (bin_scatter) or per-bucket contiguous
// regions (bucket_scatter) -> lines stay in one XCD L2, ~1 writeback/line.

constexpr int BIN_BLOCKS = 128;
constexpr int MAX_NBK = 1024;            // supports N <= 131072 (= packing limit)

__global__ __launch_bounds__(256) void bin_hist_k(const int* __restrict__ dst, int E,
                                                  int* __restrict__ cntb, int nbk,
                                                  int chunk) {
    __shared__ int hist[MAX_NBK];
    for (int i = threadIdx.x; i < nbk; i += 256) hist[i] = 0;
    __syncthreads();
    const int lo = blockIdx.x * chunk;
    const int hi = min(lo + chunk, E);
    for (int e = lo + threadIdx.x; e < hi; e += 256)
        atomicAdd(&hist[dst[e] >> 7], 1);
    __syncthreads();
    for (int i = threadIdx.x; i < nbk; i += 256)
        cntb[i * gridDim.x + blockIdx.x] = hist[i];   // bucket-major
}

__global__ __launch_bounds__(256) void bin_scatter_k(const int* __restrict__ ei, int E,
                                                     const int* __restrict__ obb,
                                                     int* __restrict__ eb, int nbk,
                                                     int chunk) {
    __shared__ int cur[MAX_NBK];
    for (int i = threadIdx.x; i < nbk; i += 256) cur[i] = 0;
    __syncthreads();
    const int lo = blockIdx.x * chunk;
    const int hi = min(lo + chunk, E);
    for (int e = lo + threadIdx.x; e < hi; e += 256) {
        int s = ei[e];
        int d = ei[E + e];
        int b = d >> 7;
        int idx = atomicAdd(&cur[b], 1);
        eb[obb[b * gridDim.x + blockIdx.x] + idx] = (s << 7) | (d & 127);
    }
}

// per-bucket degree count (includes +1 self-loop) -> cnt[node]; replaces hist
__global__ __launch_bounds__(256) void bucket_cnt_k(const int* __restrict__ eb,
                                                    const int* __restrict__ obb,
                                                    int* __restrict__ cnt,
                                                    int B, int n) {
    __shared__ int c[128];
    const int b = blockIdx.x;
    const int t = threadIdx.x;
    const int beg = obb[b * B];
    const int end = obb[(b + 1) * B];    // last bucket: obb[nbk*B] = total
    if (t < 128) c[t] = 1;               // self-loop
    __syncthreads();
    for (int i = beg + t; i < end; i += 256)
        atomicAdd(&c[eb[i] & 127], 1);
    __syncthreads();
    const int node = b * 128 + t;
    if (t < 128 && node < n) cnt[node] = c[t];
}

__global__ __launch_bounds__(256) void bucket_scatter_k(const int* __restrict__ eb,
                                                        const int* __restrict__ obb,
                                                        const int* __restrict__ row_ptr,
                                                        int* __restrict__ col,
                                                        int B, int n) {
    __shared__ int c[128];
    __shared__ int rp[128];
    const int b = blockIdx.x;
    const int t = threadIdx.x;
    const int beg = obb[b * B];
    const int end = obb[(b + 1) * B];
    const int node = b * 128 + t;
    if (t < 128) {
        c[t] = 1;
        if (node < n) {
            rp[t] = row_ptr[node];
            col[rp[t]] = node;           // self-loop in slot 0
        }
    }
    __syncthreads();
    for (int i = beg + t; i < end; i += 256) {
        int p = eb[i];
        int dl = p & 127;
        int idx = atomicAdd(&c[dl], 1);
        col[rp[dl] + idx] = p >> 7;      // within bucket's contiguous region
    }
}

// ---------------- dense: LDS-tiled GEMM + fused attention dots ----------------

template <int K, int F>
__launch_bounds__(256)
__global__ void gemm_tile_k(const float* __restrict__ x, const float* __restrict__ W,
                            const float* __restrict__ a_s, const float* __restrict__ a_d,
                            float* __restrict__ h, float* __restrict__ ss,
                            float* __restrict__ sd, int n) {
    constexpr int KC = 64;
    constexpr int NCHUNK = K / KC;
    constexpr int CG = F / 4;            // col groups (16 or 8)
    constexpr int MT = 256 / CG * 4;     // 64 nodes (F=64) or 128 (F=32)
    constexpr int XS_STRIDE = KC + 4;

    __shared__ float xs[MT][XS_STRIDE];
    __shared__ float ws[KC][F];

    const int tid = threadIdx.x;
    const int cg = tid % CG;
    const int rg = tid / CG;
    const int base = blockIdx.x * MT;

    float4 acc[4];
#pragma unroll
    for (int i = 0; i < 4; ++i) acc[i] = make_float4(0.f, 0.f, 0.f, 0.f);

    for (int kc = 0; kc < NCHUNK; ++kc) {
#pragma unroll
        for (int i = 0; i < MT * KC / 4 / 256; ++i) {
            int flat = tid + i * 256;
            int row = flat / (KC / 4);
            int c4 = flat % (KC / 4);
            float4 v = make_float4(0.f, 0.f, 0.f, 0.f);
            if (base + row < n)
                v = *(const float4*)&x[(size_t)(base + row) * K + kc * KC + 4 * c4];
            *(float4*)&xs[row][4 * c4] = v;
        }
#pragma unroll
        for (int i = 0; i < KC * F / 4 / 256; ++i) {
            int flat = tid + i * 256;
            int wrow = flat / (F / 4);
            int wc4 = flat % (F / 4);
            *(float4*)&ws[wrow][4 * wc4] =
                *(const float4*)&W[(size_t)(kc * KC + wrow) * F + 4 * wc4];
        }
        __syncthreads();

#pragma unroll
        for (int k = 0; k < KC; k += 4) {
            float4 w0 = *(const float4*)&ws[k + 0][cg * 4];
            float4 w1 = *(const float4*)&ws[k + 1][cg * 4];
            float4 w2 = *(const float4*)&ws[k + 2][cg * 4];
            float4 w3 = *(const float4*)&ws[k + 3][cg * 4];
#pragma unroll
            for (int i = 0; i < 4; ++i) {
                float4 a = *(const float4*)&xs[rg * 4 + i][k];
                acc[i].x = fmaf(a.x, w0.x, acc[i].x);
                acc[i].y = fmaf(a.x, w0.y, acc[i].y);
                acc[i].z = fmaf(a.x, w0.z, acc[i].z);
                acc[i].w = fmaf(a.x, w0.w, acc[i].w);
                acc[i].x = fmaf(a.y, w1.x, acc[i].x);
                acc[i].y = fmaf(a.y, w1.y, acc[i].y);
                acc[i].z = fmaf(a.y, w1.z, acc[i].z);
                acc[i].w = fmaf(a.y, w1.w, acc[i].w);
                acc[i].x = fmaf(a.z, w2.x, acc[i].x);
                acc[i].y = fmaf(a.z, w2.y, acc[i].y);
                acc[i].z = fmaf(a.z, w2.z, acc[i].z);
                acc[i].w = fmaf(a.z, w2.w, acc[i].w);
                acc[i].x = fmaf(a.w, w3.x, acc[i].x);
                acc[i].y = fmaf(a.w, w3.y, acc[i].y);
                acc[i].z = fmaf(a.w, w3.z, acc[i].z);
                acc[i].w = fmaf(a.w, w3.w, acc[i].w);
            }
        }
        __syncthreads();
    }

    const float4 as4 = *(const float4*)&a_s[4 * cg];
    const float4 ad4 = *(const float4*)&a_d[4 * cg];
#pragma unroll
    for (int i = 0; i < 4; ++i) {
        const int node = base + rg * 4 + i;
        float ps = acc[i].x * as4.x + acc[i].y * as4.y + acc[i].z * as4.z + acc[i].w * as4.w;
        float pd = acc[i].x * ad4.x + acc[i].y * ad4.y + acc[i].z * ad4.z + acc[i].w * ad4.w;
#pragma unroll
        for (int o = CG / 2; o; o >>= 1) {
            ps += __shfl_xor(ps, o);
            pd += __shfl_xor(pd, o);
        }
        if (node < n) {
            *(float4*)&h[(size_t)node * F + 4 * cg] = acc[i];
            if (cg == 0) { ss[node] = ps; sd[node] = pd; }
        }
    }
}

// ---------------- sparse: online-softmax attention aggregation ----------------

template <int F, bool RELU, bool LOGSM>
__launch_bounds__(256)
__global__ void gat_agg_k(const int* __restrict__ row_ptr, const int* __restrict__ col,
                          const float* __restrict__ h, const float* __restrict__ ss,
                          const float* __restrict__ sd, const float* __restrict__ bias,
                          float* __restrict__ out, int n) {
    constexpr int NPW = 64 / F;
    const int lane = threadIdx.x & 63;
    const int sub  = lane / F;
    const int f    = lane % F;
    const int wave = (blockIdx.x * blockDim.x + threadIdx.x) >> 6;
    const int node = wave * NPW + sub;
    if (node >= n) return;

    const int beg = row_ptr[node];
    const int end = row_ptr[node + 1];
    const float sdv = sd[node];

    float m = -__builtin_inff();
    float s = 0.f;
    float acc = 0.f;

    for (int base = beg; base < end; base += F) {
        const int j = base + f;
        int   c = 0;
        float logit = -__builtin_inff();
        if (j < end) {
            c = col[j];
            float z = ss[c] + sdv;
            logit = (z > 0.f) ? z : NEG_SLOPE * z;
        }
        float cm = logit;
#pragma unroll
        for (int o = F / 2; o; o >>= 1) cm = fmaxf(cm, __shfl_xor(cm, o));
        const float newm = fmaxf(m, cm);
        const float scale = __expf(m - newm);
        s *= scale;
        acc *= scale;
        const float w = __expf(logit - newm);
        float wsum = w;
#pragma unroll
        for (int o = F / 2; o; o >>= 1) wsum += __shfl_xor(wsum, o);
        s += wsum;
        m = newm;

        const int cnt = min(F, end - base);
        for (int t = 0; t < cnt; ++t) {
            const float wt = __shfl(w, sub * F + t);
            const int   ct = __shfl(c, sub * F + t);
            acc = fmaf(wt, h[(size_t)ct * F + f], acc);
        }
    }

    float val = acc / (s + 1e-16f) + bias[f];
    if (RELU) val = fmaxf(val, 0.f);
    if (LOGSM) {
        float lm = val;
#pragma unroll
        for (int o = F / 2; o; o >>= 1) lm = fmaxf(lm, __shfl_xor(lm, o));
        float ex = __expf(val - lm);
#pragma unroll
        for (int o = F / 2; o; o >>= 1) ex += __shfl_xor(ex, o);
        val = val - lm - __logf(ex);
    }
    out[(size_t)node * F + f] = val;
}

// ---------------- launch ----------------

extern "C" void kernel_launch(void* const* d_in, const int* in_sizes, int n_in,
                              void* d_out, int out_size, void* d_ws, size_t ws_size,
                              hipStream_t stream) {
    const float* x  = (const float*)d_in[0];
    const int*   ei = (const int*)d_in[1];
    const float* W1 = (const float*)d_in[2];
    const float* a1s = (const float*)d_in[3];
    const float* a1d = (const float*)d_in[4];
    const float* b1  = (const float*)d_in[5];
    const float* W2 = (const float*)d_in[6];
    const float* a2s = (const float*)d_in[7];
    const float* a2d = (const float*)d_in[8];
    const float* b2  = (const float*)d_in[9];
    const float* W3 = (const float*)d_in[10];
    const float* a3s = (const float*)d_in[11];
    const float* a3d = (const float*)d_in[12];
    const float* b3  = (const float*)d_in[13];

    const int N = in_sizes[0] / 128;
    const int E = in_sizes[1] / 2;
    const int NBK = (N + 127) / 128;                 // dst buckets (128 nodes each)
    const int B = BIN_BLOCKS;

    // workspace layout (256B aligned)
    char* wp = (char*)d_ws;
    auto alloc = [&](size_t bytes) -> void* {
        void* p = wp;
        wp += (bytes + 255) & ~(size_t)255;
        return p;
    };
    int* cnt     = (int*)alloc((size_t)N * 4);
    int* row_ptr = (int*)alloc((size_t)(N + 1) * 4);
    int* col     = (int*)alloc((size_t)(E + N) * 4);
    float* h   = (float*)alloc((size_t)N * 64 * 4);
    float* ss  = (float*)alloc((size_t)N * 4);
    float* sd  = (float*)alloc((size_t)N * 4);
    float* o1  = (float*)alloc((size_t)N * 64 * 4);
    float* o2  = (float*)alloc((size_t)N * 64 * 4);
    int* cntb  = (int*)alloc((size_t)NBK * B * 4);
    int* obb   = (int*)alloc(((size_t)NBK * B + 1) * 4);
    int* bsum  = (int*)alloc(1024 * 4);
    // eb aliases o2: eb's last read (bucket_scatter) precedes o2's first write
    int* eb = (int*)o2;                               // E ints <= N*64 floats

    // --- binned CSR build (dst-sorted col, self-loops in slot 0) ---
    const int chunk = (E + B - 1) / B;
    const int nb2 = (NBK * B + SCAN_TILE - 1) / SCAN_TILE;
    const int nbn = (N + SCAN_TILE - 1) / SCAN_TILE;

    bin_hist_k<<<B, 256, 0, stream>>>(ei + E, E, cntb, NBK, chunk);
    scan_pass1<<<nb2, 256, 0, stream>>>(cntb, bsum, NBK * B);
    scan_pass2<<<1, 256, 0, stream>>>(bsum, obb, nb2, NBK * B);
    scan_pass3<<<nb2, 256, 0, stream>>>(cntb, bsum, obb, NBK * B);
    bin_scatter_k<<<B, 256, 0, stream>>>(ei, E, obb, eb, NBK, chunk);
    bucket_cnt_k<<<NBK, 256, 0, stream>>>(eb, obb, cnt, B, N);
    scan_pass1<<<nbn, 256, 0, stream>>>(cnt, bsum, N);
    scan_pass2<<<1, 256, 0, stream>>>(bsum, row_ptr, nbn, N);
    scan_pass3<<<nbn, 256, 0, stream>>>(cnt, bsum, row_ptr, N);
    bucket_scatter_k<<<NBK, 256, 0, stream>>>(eb, obb, row_ptr, col, B, N);

    // --- layer 1: 128 -> 64, relu ---
    gemm_tile_k<128, 64><<<(N + 63) / 64, 256, 0, stream>>>(x, W1, a1s, a1d, h, ss, sd, N);
    gat_agg_k<64, true, false><<<(N + 3) / 4, 256, 0, stream>>>(row_ptr, col, h, ss, sd, b1, o1, N);

    // --- layer 2: 64 -> 64, relu ---
    gemm_tile_k<64, 64><<<(N + 63) / 64, 256, 0, stream>>>(o1, W2, a2s, a2d, h, ss, sd, N);
    gat_agg_k<64, true, false><<<(N + 3) / 4, 256, 0, stream>>>(row_ptr, col, h, ss, sd, b2, o2, N);

    // --- layer 3: 64 -> 32, log_softmax ---
    gemm_tile_k<64, 32><<<(N + 127) / 128, 256, 0, stream>>>(o2, W3, a3s, a3d, h, ss, sd, N);
    gat_agg_k<32, false, true><<<(N + 7) / 8, 256, 0, stream>>>(row_ptr, col, h, ss, sd, b3,
                                                                (float*)d_out, N);
}

// Round 5
// 434.377 us; speedup vs baseline: 2.5253x; 1.2701x over previous
//
#include <hip/hip_runtime.h>
#include <cstddef>
#include <cstdint>

#define NEG_SLOPE 0.2f

// ---------------- hierarchical exclusive scan: in[n] -> out[n+1] ----------------

constexpr int SCAN_TILE = 1024;   // 256 threads x 4 elems

__global__ __launch_bounds__(256) void scan_pass1(const int* __restrict__ in,
                                                  int* __restrict__ bsum, int n) {
    const int tid = threadIdx.x;
    const int base = blockIdx.x * SCAN_TILE + tid * 4;
    int s = 0;
#pragma unroll
    for (int k = 0; k < 4; ++k) {
        int i = base + k;
        if (i < n) s += in[i];
    }
    for (int o = 1; o < 64; o <<= 1) s += __shfl_xor(s, o);
    __shared__ int wsum[4];
    if ((tid & 63) == 0) wsum[tid >> 6] = s;
    __syncthreads();
    if (tid == 0) bsum[blockIdx.x] = wsum[0] + wsum[1] + wsum[2] + wsum[3];
}

__global__ __launch_bounds__(256) void scan_pass2(int* __restrict__ bsum,
                                                  int* __restrict__ out,
                                                  int nb, int n) {
    __shared__ int sh[1024];
    const int tid = threadIdx.x;
    for (int i = tid; i < nb; i += 256) sh[i] = bsum[i];
    __syncthreads();
    if (tid == 0) {
        int run = 0;
        for (int i = 0; i < nb; ++i) { int c = sh[i]; sh[i] = run; run += c; }
        out[n] = run;                    // grand total
    }
    __syncthreads();
    for (int i = tid; i < nb; i += 256) bsum[i] = sh[i];
}

__global__ __launch_bounds__(256) void scan_pass3(const int* __restrict__ in,
                                                  const int* __restrict__ bsum,
                                                  int* __restrict__ out, int n) {
    const int tid = threadIdx.x;
    const int lane = tid & 63;
    const int wid = tid >> 6;
    const int base = blockIdx.x * SCAN_TILE + tid * 4;
    int v[4];
    int tsum = 0;
#pragma unroll
    for (int k = 0; k < 4; ++k) {
        int i = base + k;
        v[k] = (i < n) ? in[i] : 0;
        tsum += v[k];
    }
    int inc = tsum;
    for (int o = 1; o < 64; o <<= 1) {
        int t = __shfl_up(inc, o);
        if (lane >= o) inc += t;
    }
    __shared__ int wtot[4];
    if (lane == 63) wtot[wid] = inc;
    __syncthreads();
    int woff = 0;
    for (int w = 0; w < wid; ++w) woff += wtot[w];
    int off = bsum[blockIdx.x] + woff + (inc - tsum);
#pragma unroll
    for (int k = 0; k < 4; ++k) {
        int i = base + k;
        if (i < n) { out[i] = off; off += v[k]; }
    }
}

// ---------------- binned CSR build ----------------

constexpr int BIN_BLOCKS = 128;
constexpr int MAX_NBK = 1024;            // supports N <= 131072 (= packing limit)

__global__ __launch_bounds__(256) void bin_hist_k(const int* __restrict__ dst, int E,
                                                  int* __restrict__ cntb, int nbk,
                                                  int chunk) {
    __shared__ int hist[MAX_NBK];
    for (int i = threadIdx.x; i < nbk; i += 256) hist[i] = 0;
    __syncthreads();
    const int lo = blockIdx.x * chunk;
    const int hi = min(lo + chunk, E);
    for (int e = lo + threadIdx.x; e < hi; e += 256)
        atomicAdd(&hist[dst[e] >> 7], 1);
    __syncthreads();
    for (int i = threadIdx.x; i < nbk; i += 256)
        cntb[i * gridDim.x + blockIdx.x] = hist[i];   // bucket-major
}

__global__ __launch_bounds__(256) void bin_scatter_k(const int* __restrict__ ei, int E,
                                                     const int* __restrict__ obb,
                                                     int* __restrict__ eb, int nbk,
                                                     int chunk) {
    __shared__ int cur[MAX_NBK];
    for (int i = threadIdx.x; i < nbk; i += 256) cur[i] = 0;
    __syncthreads();
    const int lo = blockIdx.x * chunk;
    const int hi = min(lo + chunk, E);
    for (int e = lo + threadIdx.x; e < hi; e += 256) {
        int s = ei[e];
        int d = ei[E + e];
        int b = d >> 7;
        int idx = atomicAdd(&cur[b], 1);
        eb[obb[b * gridDim.x + blockIdx.x] + idx] = (s << 7) | (d & 127);
    }
}

__global__ __launch_bounds__(256) void bucket_cnt_k(const int* __restrict__ eb,
                                                    const int* __restrict__ obb,
                                                    int* __restrict__ cnt,
                                                    int B, int n) {
    __shared__ int c[128];
    const int b = blockIdx.x;
    const int t = threadIdx.x;
    const int beg = obb[b * B];
    const int end = obb[(b + 1) * B];
    if (t < 128) c[t] = 1;               // self-loop
    __syncthreads();
    for (int i = beg + t; i < end; i += 256)
        atomicAdd(&c[eb[i] & 127], 1);
    __syncthreads();
    const int node = b * 128 + t;
    if (t < 128 && node < n) cnt[node] = c[t];
}

__global__ __launch_bounds__(256) void bucket_scatter_k(const int* __restrict__ eb,
                                                        const int* __restrict__ obb,
                                                        const int* __restrict__ row_ptr,
                                                        int* __restrict__ col,
                                                        int B, int n) {
    __shared__ int c[128];
    __shared__ int rp[128];
    const int b = blockIdx.x;
    const int t = threadIdx.x;
    const int beg = obb[b * B];
    const int end = obb[(b + 1) * B];
    const int node = b * 128 + t;
    if (t < 128) {
        c[t] = 1;
        if (node < n) {
            rp[t] = row_ptr[node];
            col[rp[t]] = node;           // self-loop in slot 0
        }
    }
    __syncthreads();
    for (int i = beg + t; i < end; i += 256) {
        int p = eb[i];
        int dl = p & 127;
        int idx = atomicAdd(&c[dl], 1);
        col[rp[dl] + idx] = p >> 7;
    }
}

// ---------------- dense: LDS-tiled GEMM + fused attention dots ----------------

template <int K, int F>
__launch_bounds__(256)
__global__ void gemm_tile_k(const float* __restrict__ x, const float* __restrict__ W,
                            const float* __restrict__ a_s, const float* __restrict__ a_d,
                            float* __restrict__ h, float* __restrict__ ss,
                            float* __restrict__ sd, int n) {
    constexpr int KC = 64;
    constexpr int NCHUNK = K / KC;
    constexpr int CG = F / 4;
    constexpr int MT = 256 / CG * 4;
    constexpr int XS_STRIDE = KC + 4;

    __shared__ float xs[MT][XS_STRIDE];
    __shared__ float ws[KC][F];

    const int tid = threadIdx.x;
    const int cg = tid % CG;
    const int rg = tid / CG;
    const int base = blockIdx.x * MT;

    float4 acc[4];
#pragma unroll
    for (int i = 0; i < 4; ++i) acc[i] = make_float4(0.f, 0.f, 0.f, 0.f);

    for (int kc = 0; kc < NCHUNK; ++kc) {
#pragma unroll
        for (int i = 0; i < MT * KC / 4 / 256; ++i) {
            int flat = tid + i * 256;
            int row = flat / (KC / 4);
            int c4 = flat % (KC / 4);
            float4 v = make_float4(0.f, 0.f, 0.f, 0.f);
            if (base + row < n)
                v = *(const float4*)&x[(size_t)(base + row) * K + kc * KC + 4 * c4];
            *(float4*)&xs[row][4 * c4] = v;
        }
#pragma unroll
        for (int i = 0; i < KC * F / 4 / 256; ++i) {
            int flat = tid + i * 256;
            int wrow = flat / (F / 4);
            int wc4 = flat % (F / 4);
            *(float4*)&ws[wrow][4 * wc4] =
                *(const float4*)&W[(size_t)(kc * KC + wrow) * F + 4 * wc4];
        }
        __syncthreads();

#pragma unroll
        for (int k = 0; k < KC; k += 4) {
            float4 w0 = *(const float4*)&ws[k + 0][cg * 4];
            float4 w1 = *(const float4*)&ws[k + 1][cg * 4];
            float4 w2 = *(const float4*)&ws[k + 2][cg * 4];
            float4 w3 = *(const float4*)&ws[k + 3][cg * 4];
#pragma unroll
            for (int i = 0; i < 4; ++i) {
                float4 a = *(const float4*)&xs[rg * 4 + i][k];
                acc[i].x = fmaf(a.x, w0.x, acc[i].x);
                acc[i].y = fmaf(a.x, w0.y, acc[i].y);
                acc[i].z = fmaf(a.x, w0.z, acc[i].z);
                acc[i].w = fmaf(a.x, w0.w, acc[i].w);
                acc[i].x = fmaf(a.y, w1.x, acc[i].x);
                acc[i].y = fmaf(a.y, w1.y, acc[i].y);
                acc[i].z = fmaf(a.y, w1.z, acc[i].z);
                acc[i].w = fmaf(a.y, w1.w, acc[i].w);
                acc[i].x = fmaf(a.z, w2.x, acc[i].x);
                acc[i].y = fmaf(a.z, w2.y, acc[i].y);
                acc[i].z = fmaf(a.z, w2.z, acc[i].z);
                acc[i].w = fmaf(a.z, w2.w, acc[i].w);
                acc[i].x = fmaf(a.w, w3.x, acc[i].x);
                acc[i].y = fmaf(a.w, w3.y, acc[i].y);
                acc[i].z = fmaf(a.w, w3.z, acc[i].z);
                acc[i].w = fmaf(a.w, w3.w, acc[i].w);
            }
        }
        __syncthreads();
    }

    const float4 as4 = *(const float4*)&a_s[4 * cg];
    const float4 ad4 = *(const float4*)&a_d[4 * cg];
#pragma unroll
    for (int i = 0; i < 4; ++i) {
        const int node = base + rg * 4 + i;
        float ps = acc[i].x * as4.x + acc[i].y * as4.y + acc[i].z * as4.z + acc[i].w * as4.w;
        float pd = acc[i].x * ad4.x + acc[i].y * ad4.y + acc[i].z * ad4.z + acc[i].w * ad4.w;
#pragma unroll
        for (int o = CG / 2; o; o >>= 1) {
            ps += __shfl_xor(ps, o);
            pd += __shfl_xor(pd, o);
        }
        if (node < n) {
            *(float4*)&h[(size_t)node * F + 4 * cg] = acc[i];
            if (cg == 0) { ss[node] = ps; sd[node] = pd; }
        }
    }
}

// ---------------- sparse: online-softmax attention aggregation (float4 lanes) ----
// Subgroup of F lanes per node: lane = q*NL + cl, NL = F/4 channel-quads,
// q = 4 parallel edge slots. Chunk = F edges: each lane computes one logit
// (coalesced col load + ss gather); gather loop does 4 edges/iteration, each
// lane loading float4 of h and doing 4 fma. Epilogue: butterfly-reduce acc
// across q, then bias/relu/log-softmax.

template <int F, bool RELU, bool LOGSM>
__launch_bounds__(256)
__global__ void gat_agg_k(const int* __restrict__ row_ptr, const int* __restrict__ col,
                          const float* __restrict__ h, const float* __restrict__ ss,
                          const float* __restrict__ sd, const float* __restrict__ bias,
                          float* __restrict__ out, int n) {
    constexpr int NPW = 64 / F;          // nodes per wave
    constexpr int NL = F / 4;            // lanes per channel dim (float4 each)
    const int lane = threadIdx.x & 63;
    const int ls   = lane % F;           // lane in subgroup
    const int q    = ls / NL;            // edge slot 0..3
    const int cl   = ls % NL;            // channel quad
    const int lbase = lane - ls;         // first lane of subgroup
    const int wave = (blockIdx.x * blockDim.x + threadIdx.x) >> 6;
    const int node = wave * NPW + (ls == lane ? 0 : 1) * 0 + (lane / F);
    if (node >= n) return;

    const int beg = row_ptr[node];
    const int end = row_ptr[node + 1];
    const float sdv = sd[node];

    float m = -__builtin_inff();
    float s = 0.f;
    float4 acc = make_float4(0.f, 0.f, 0.f, 0.f);

    for (int base = beg; base < end; base += F) {
        const int j = base + ls;
        int   c = 0;
        float logit = -__builtin_inff();
        if (j < end) {
            c = col[j];
            float z = ss[c] + sdv;
            logit = (z > 0.f) ? z : NEG_SLOPE * z;
        }
        float cm = logit;
#pragma unroll
        for (int o = F / 2; o; o >>= 1) cm = fmaxf(cm, __shfl_xor(cm, o));
        const float newm = fmaxf(m, cm);
        const float scale = __expf(m - newm);     // first iter: exp(-inf)=0
        s *= scale;
        acc.x *= scale; acc.y *= scale; acc.z *= scale; acc.w *= scale;
        const float w = __expf(logit - newm);     // inactive lanes -> 0
        float wsum = w;
#pragma unroll
        for (int o = F / 2; o; o >>= 1) wsum += __shfl_xor(wsum, o);
        s += wsum;
        m = newm;

        const int cnt = min(F, end - base);
        for (int t = 0; 4 * t < cnt; ++t) {
            const int e = 4 * t + q;              // edge in chunk for this slot
            const float wt = __shfl(w, lbase + e);   // 0 for e >= cnt
            const int   ct = __shfl(c, lbase + e);   // 0 for e >= cnt (safe)
            const float4 hv = *(const float4*)&h[(size_t)ct * F + 4 * cl];
            acc.x = fmaf(wt, hv.x, acc.x);
            acc.y = fmaf(wt, hv.y, acc.y);
            acc.z = fmaf(wt, hv.z, acc.z);
            acc.w = fmaf(wt, hv.w, acc.w);
        }
    }

    // butterfly-reduce partial sums across the 4 q-slots (all lanes get total)
#pragma unroll
    for (int o = NL; o < F; o <<= 1) {
        acc.x += __shfl_xor(acc.x, o);
        acc.y += __shfl_xor(acc.y, o);
        acc.z += __shfl_xor(acc.z, o);
        acc.w += __shfl_xor(acc.w, o);
    }

    const float inv = 1.f / (s + 1e-16f);
    const float4 b4 = *(const float4*)&bias[4 * cl];
    float4 val;
    val.x = acc.x * inv + b4.x;
    val.y = acc.y * inv + b4.y;
    val.z = acc.z * inv + b4.z;
    val.w = acc.w * inv + b4.w;
    if (RELU) {
        val.x = fmaxf(val.x, 0.f); val.y = fmaxf(val.y, 0.f);
        val.z = fmaxf(val.z, 0.f); val.w = fmaxf(val.w, 0.f);
    }
    if (LOGSM) {
        // reduce over channels: in-lane 4 comps + across the NL cl-lanes only
        float lm = fmaxf(fmaxf(val.x, val.y), fmaxf(val.z, val.w));
#pragma unroll
        for (int o = 1; o < NL; o <<= 1) lm = fmaxf(lm, __shfl_xor(lm, o));
        float ex = __expf(val.x - lm) + __expf(val.y - lm) +
                   __expf(val.z - lm) + __expf(val.w - lm);
#pragma unroll
        for (int o = 1; o < NL; o <<= 1) ex += __shfl_xor(ex, o);
        const float lse = lm + __logf(ex);
        val.x -= lse; val.y -= lse; val.z -= lse; val.w -= lse;
    }
    if (q == 0)
        *(float4*)&out[(size_t)node * F + 4 * cl] = val;
}

// ---------------- launch ----------------

extern "C" void kernel_launch(void* const* d_in, const int* in_sizes, int n_in,
                              void* d_out, int out_size, void* d_ws, size_t ws_size,
                              hipStream_t stream) {
    const float* x  = (const float*)d_in[0];
    const int*   ei = (const int*)d_in[1];
    const float* W1 = (const float*)d_in[2];
    const float* a1s = (const float*)d_in[3];
    const float* a1d = (const float*)d_in[4];
    const float* b1  = (const float*)d_in[5];
    const float* W2 = (const float*)d_in[6];
    const float* a2s = (const float*)d_in[7];
    const float* a2d = (const float*)d_in[8];
    const float* b2  = (const float*)d_in[9];
    const float* W3 = (const float*)d_in[10];
    const float* a3s = (const float*)d_in[11];
    const float* a3d = (const float*)d_in[12];
    const float* b3  = (const float*)d_in[13];

    const int N = in_sizes[0] / 128;
    const int E = in_sizes[1] / 2;
    const int NBK = (N + 127) / 128;
    const int B = BIN_BLOCKS;

    char* wp = (char*)d_ws;
    auto alloc = [&](size_t bytes) -> void* {
        void* p = wp;
        wp += (bytes + 255) & ~(size_t)255;
        return p;
    };
    int* cnt     = (int*)alloc((size_t)N * 4);
    int* row_ptr = (int*)alloc((size_t)(N + 1) * 4);
    int* col     = (int*)alloc((size_t)(E + N) * 4);
    float* h   = (float*)alloc((size_t)N * 64 * 4);
    float* ss  = (float*)alloc((size_t)N * 4);
    float* sd  = (float*)alloc((size_t)N * 4);
    float* o1  = (float*)alloc((size_t)N * 64 * 4);
    float* o2  = (float*)alloc((size_t)N * 64 * 4);
    int* cntb  = (int*)alloc((size_t)NBK * B * 4);
    int* obb   = (int*)alloc(((size_t)NBK * B + 1) * 4);
    int* bsum  = (int*)alloc(1024 * 4);
    int* eb = (int*)o2;                               // alias: dead ranges don't overlap

    const int chunk = (E + B - 1) / B;
    const int nb2 = (NBK * B + SCAN_TILE - 1) / SCAN_TILE;
    const int nbn = (N + SCAN_TILE - 1) / SCAN_TILE;

    bin_hist_k<<<B, 256, 0, stream>>>(ei + E, E, cntb, NBK, chunk);
    scan_pass1<<<nb2, 256, 0, stream>>>(cntb, bsum, NBK * B);
    scan_pass2<<<1, 256, 0, stream>>>(bsum, obb, nb2, NBK * B);
    scan_pass3<<<nb2, 256, 0, stream>>>(cntb, bsum, obb, NBK * B);
    bin_scatter_k<<<B, 256, 0, stream>>>(ei, E, obb, eb, NBK, chunk);
    bucket_cnt_k<<<NBK, 256, 0, stream>>>(eb, obb, cnt, B, N);
    scan_pass1<<<nbn, 256, 0, stream>>>(cnt, bsum, N);
    scan_pass2<<<1, 256, 0, stream>>>(bsum, row_ptr, nbn, N);
    scan_pass3<<<nbn, 256, 0, stream>>>(cnt, bsum, row_ptr, N);
    bucket_scatter_k<<<NBK, 256, 0, stream>>>(eb, obb, row_ptr, col, B, N);

    // --- layer 1: 128 -> 64, relu ---
    gemm_tile_k<128, 64><<<(N + 63) / 64, 256, 0, stream>>>(x, W1, a1s, a1d, h, ss, sd, N);
    gat_agg_k<64, true, false><<<(N + 3) / 4, 256, 0, stream>>>(row_ptr, col, h, ss, sd, b1, o1, N);

    // --- layer 2: 64 -> 64, relu ---
    gemm_tile_k<64, 64><<<(N + 63) / 64, 256, 0, stream>>>(o1, W2, a2s, a2d, h, ss, sd, N);
    gat_agg_k<64, true, false><<<(N + 3) / 4, 256, 0, stream>>>(row_ptr, col, h, ss, sd, b2, o2, N);

    // --- layer 3: 64 -> 32, log_softmax ---
    gemm_tile_k<64, 32><<<(N + 127) / 128, 256, 0, stream>>>(o2, W3, a3s, a3d, h, ss, sd, N);
    gat_agg_k<32, false, true><<<(N + 7) / 8, 256, 0, stream>>>(row_ptr, col, h, ss, sd, b3,
                                                                (float*)d_out, N);
}

// Round 6
// 392.048 us; speedup vs baseline: 2.7979x; 1.1080x over previous
//
#include <hip/hip_runtime.h>
#include <cstddef>
#include <cstdint>

#define NEG_SLOPE 0.2f

__device__ __forceinline__ unsigned short f2bf(float f) {
    unsigned int u = __float_as_uint(f);
    u = (u + 0x7fff + ((u >> 16) & 1)) >> 16;   // round-to-nearest-even
    return (unsigned short)u;
}
__device__ __forceinline__ float bf_lo(unsigned int u) { return __uint_as_float(u << 16); }
__device__ __forceinline__ float bf_hi(unsigned int u) { return __uint_as_float(u & 0xffff0000u); }

// ---------------- hierarchical exclusive scan: in[n] -> out[n+1] ----------------

constexpr int SCAN_TILE = 1024;   // 256 threads x 4 elems

__global__ __launch_bounds__(256) void scan_pass1(const int* __restrict__ in,
                                                  int* __restrict__ bsum, int n) {
    const int tid = threadIdx.x;
    const int base = blockIdx.x * SCAN_TILE + tid * 4;
    int s = 0;
#pragma unroll
    for (int k = 0; k < 4; ++k) {
        int i = base + k;
        if (i < n) s += in[i];
    }
    for (int o = 1; o < 64; o <<= 1) s += __shfl_xor(s, o);
    __shared__ int wsum[4];
    if ((tid & 63) == 0) wsum[tid >> 6] = s;
    __syncthreads();
    if (tid == 0) bsum[blockIdx.x] = wsum[0] + wsum[1] + wsum[2] + wsum[3];
}

__global__ __launch_bounds__(256) void scan_pass2(int* __restrict__ bsum,
                                                  int* __restrict__ out,
                                                  int nb, int n) {
    __shared__ int sh[1024];
    const int tid = threadIdx.x;
    for (int i = tid; i < nb; i += 256) sh[i] = bsum[i];
    __syncthreads();
    if (tid == 0) {
        int run = 0;
        for (int i = 0; i < nb; ++i) { int c = sh[i]; sh[i] = run; run += c; }
        out[n] = run;                    // grand total
    }
    __syncthreads();
    for (int i = tid; i < nb; i += 256) bsum[i] = sh[i];
}

__global__ __launch_bounds__(256) void scan_pass3(const int* __restrict__ in,
                                                  const int* __restrict__ bsum,
                                                  int* __restrict__ out, int n) {
    const int tid = threadIdx.x;
    const int lane = tid & 63;
    const int wid = tid >> 6;
    const int base = blockIdx.x * SCAN_TILE + tid * 4;
    int v[4];
    int tsum = 0;
#pragma unroll
    for (int k = 0; k < 4; ++k) {
        int i = base + k;
        v[k] = (i < n) ? in[i] : 0;
        tsum += v[k];
    }
    int inc = tsum;
    for (int o = 1; o < 64; o <<= 1) {
        int t = __shfl_up(inc, o);
        if (lane >= o) inc += t;
    }
    __shared__ int wtot[4];
    if (lane == 63) wtot[wid] = inc;
    __syncthreads();
    int woff = 0;
    for (int w = 0; w < wid; ++w) woff += wtot[w];
    int off = bsum[blockIdx.x] + woff + (inc - tsum);
#pragma unroll
    for (int k = 0; k < 4; ++k) {
        int i = base + k;
        if (i < n) { out[i] = off; off += v[k]; }
    }
}

// ---------------- binned CSR build ----------------

constexpr int BIN_BLOCKS = 128;
constexpr int MAX_NBK = 1024;            // supports N <= 131072 (= packing limit)

__global__ __launch_bounds__(256) void bin_hist_k(const int* __restrict__ dst, int E,
                                                  int* __restrict__ cntb, int nbk,
                                                  int chunk) {
    __shared__ int hist[MAX_NBK];
    for (int i = threadIdx.x; i < nbk; i += 256) hist[i] = 0;
    __syncthreads();
    const int lo = blockIdx.x * chunk;
    const int hi = min(lo + chunk, E);
    for (int e = lo + threadIdx.x; e < hi; e += 256)
        atomicAdd(&hist[dst[e] >> 7], 1);
    __syncthreads();
    for (int i = threadIdx.x; i < nbk; i += 256)
        cntb[i * gridDim.x + blockIdx.x] = hist[i];   // bucket-major
}

__global__ __launch_bounds__(256) void bin_scatter_k(const int* __restrict__ ei, int E,
                                                     const int* __restrict__ obb,
                                                     int* __restrict__ eb, int nbk,
                                                     int chunk) {
    __shared__ int cur[MAX_NBK];
    for (int i = threadIdx.x; i < nbk; i += 256) cur[i] = 0;
    __syncthreads();
    const int lo = blockIdx.x * chunk;
    const int hi = min(lo + chunk, E);
    for (int e = lo + threadIdx.x; e < hi; e += 256) {
        int s = ei[e];
        int d = ei[E + e];
        int b = d >> 7;
        int idx = atomicAdd(&cur[b], 1);
        eb[obb[b * gridDim.x + blockIdx.x] + idx] = (s << 7) | (d & 127);
    }
}

__global__ __launch_bounds__(256) void bucket_cnt_k(const int* __restrict__ eb,
                                                    const int* __restrict__ obb,
                                                    int* __restrict__ cnt,
                                                    int B, int n) {
    __shared__ int c[128];
    const int b = blockIdx.x;
    const int t = threadIdx.x;
    const int beg = obb[b * B];
    const int end = obb[(b + 1) * B];
    if (t < 128) c[t] = 1;               // self-loop
    __syncthreads();
    for (int i = beg + t; i < end; i += 256)
        atomicAdd(&c[eb[i] & 127], 1);
    __syncthreads();
    const int node = b * 128 + t;
    if (t < 128 && node < n) cnt[node] = c[t];
}

__global__ __launch_bounds__(256) void bucket_scatter_k(const int* __restrict__ eb,
                                                        const int* __restrict__ obb,
                                                        const int* __restrict__ row_ptr,
                                                        int* __restrict__ col,
                                                        int B, int n) {
    __shared__ int c[128];
    __shared__ int rp[128];
    const int b = blockIdx.x;
    const int t = threadIdx.x;
    const int beg = obb[b * B];
    const int end = obb[(b + 1) * B];
    const int node = b * 128 + t;
    if (t < 128) {
        c[t] = 1;
        if (node < n) {
            rp[t] = row_ptr[node];
            col[rp[t]] = node;           // self-loop in slot 0
        }
    }
    __syncthreads();
    for (int i = beg + t; i < end; i += 256) {
        int p = eb[i];
        int dl = p & 127;
        int idx = atomicAdd(&c[dl], 1);
        col[rp[dl] + idx] = p >> 7;
    }
}

// ---------------- dense: LDS-tiled GEMM -> bf16 h + fused attention dots -------

template <int K, int F>
__launch_bounds__(256)
__global__ void gemm_tile_k(const float* __restrict__ x, const float* __restrict__ W,
                            const float* __restrict__ a_s, const float* __restrict__ a_d,
                            unsigned short* __restrict__ hb, float* __restrict__ ss,
                            float* __restrict__ sd, int n) {
    constexpr int KC = 64;
    constexpr int NCHUNK = K / KC;
    constexpr int CG = F / 4;
    constexpr int MT = 256 / CG * 4;
    constexpr int XS_STRIDE = KC + 4;

    __shared__ float xs[MT][XS_STRIDE];
    __shared__ float ws[KC][F];

    const int tid = threadIdx.x;
    const int cg = tid % CG;
    const int rg = tid / CG;
    const int base = blockIdx.x * MT;

    float4 acc[4];
#pragma unroll
    for (int i = 0; i < 4; ++i) acc[i] = make_float4(0.f, 0.f, 0.f, 0.f);

    for (int kc = 0; kc < NCHUNK; ++kc) {
#pragma unroll
        for (int i = 0; i < MT * KC / 4 / 256; ++i) {
            int flat = tid + i * 256;
            int row = flat / (KC / 4);
            int c4 = flat % (KC / 4);
            float4 v = make_float4(0.f, 0.f, 0.f, 0.f);
            if (base + row < n)
                v = *(const float4*)&x[(size_t)(base + row) * K + kc * KC + 4 * c4];
            *(float4*)&xs[row][4 * c4] = v;
        }
#pragma unroll
        for (int i = 0; i < KC * F / 4 / 256; ++i) {
            int flat = tid + i * 256;
            int wrow = flat / (F / 4);
            int wc4 = flat % (F / 4);
            *(float4*)&ws[wrow][4 * wc4] =
                *(const float4*)&W[(size_t)(kc * KC + wrow) * F + 4 * wc4];
        }
        __syncthreads();

#pragma unroll
        for (int k = 0; k < KC; k += 4) {
            float4 w0 = *(const float4*)&ws[k + 0][cg * 4];
            float4 w1 = *(const float4*)&ws[k + 1][cg * 4];
            float4 w2 = *(const float4*)&ws[k + 2][cg * 4];
            float4 w3 = *(const float4*)&ws[k + 3][cg * 4];
#pragma unroll
            for (int i = 0; i < 4; ++i) {
                float4 a = *(const float4*)&xs[rg * 4 + i][k];
                acc[i].x = fmaf(a.x, w0.x, acc[i].x);
                acc[i].y = fmaf(a.x, w0.y, acc[i].y);
                acc[i].z = fmaf(a.x, w0.z, acc[i].z);
                acc[i].w = fmaf(a.x, w0.w, acc[i].w);
                acc[i].x = fmaf(a.y, w1.x, acc[i].x);
                acc[i].y = fmaf(a.y, w1.y, acc[i].y);
                acc[i].z = fmaf(a.y, w1.z, acc[i].z);
                acc[i].w = fmaf(a.y, w1.w, acc[i].w);
                acc[i].x = fmaf(a.z, w2.x, acc[i].x);
                acc[i].y = fmaf(a.z, w2.y, acc[i].y);
                acc[i].z = fmaf(a.z, w2.z, acc[i].z);
                acc[i].w = fmaf(a.z, w2.w, acc[i].w);
                acc[i].x = fmaf(a.w, w3.x, acc[i].x);
                acc[i].y = fmaf(a.w, w3.y, acc[i].y);
                acc[i].z = fmaf(a.w, w3.z, acc[i].z);
                acc[i].w = fmaf(a.w, w3.w, acc[i].w);
            }
        }
        __syncthreads();
    }

    const float4 as4 = *(const float4*)&a_s[4 * cg];
    const float4 ad4 = *(const float4*)&a_d[4 * cg];
#pragma unroll
    for (int i = 0; i < 4; ++i) {
        const int node = base + rg * 4 + i;
        float ps = acc[i].x * as4.x + acc[i].y * as4.y + acc[i].z * as4.z + acc[i].w * as4.w;
        float pd = acc[i].x * ad4.x + acc[i].y * ad4.y + acc[i].z * ad4.z + acc[i].w * ad4.w;
#pragma unroll
        for (int o = CG / 2; o; o >>= 1) {
            ps += __shfl_xor(ps, o);
            pd += __shfl_xor(pd, o);
        }
        if (node < n) {
            ushort4 hv;
            hv.x = f2bf(acc[i].x); hv.y = f2bf(acc[i].y);
            hv.z = f2bf(acc[i].z); hv.w = f2bf(acc[i].w);
            *(ushort4*)&hb[(size_t)node * F + 4 * cg] = hv;
            if (cg == 0) { ss[node] = ps; sd[node] = pd; }
        }
    }
}

// ---------------- sparse: online-softmax aggregation, bf16 gather payload ------
// Subgroup of F lanes per node: lane = q*NL + cl. NL = F/8 lanes per row (each
// loads 16 B = 8 bf16 channels), Q = 8 parallel edge slots. Logit phase: chunk
// of F edges, one logit/lane (exact fp32 ss/sd). Gather loop: 8 edges per
// iteration; unpack bf16 pairs, fp32 accumulate. Epilogue: butterfly-reduce
// across q slots, bias/relu/log-softmax, fp32 out.

template <int F, bool RELU, bool LOGSM>
__launch_bounds__(256)
__global__ void gat_agg_k(const int* __restrict__ row_ptr, const int* __restrict__ col,
                          const unsigned short* __restrict__ hb,
                          const float* __restrict__ ss, const float* __restrict__ sd,
                          const float* __restrict__ bias,
                          float* __restrict__ out, int n) {
    constexpr int NPW = 64 / F;          // nodes per wave
    constexpr int NL = F / 8;            // lanes per row (8 bf16 channels each)
    constexpr int Q = 8;                 // edge slots
    const int lane = threadIdx.x & 63;
    const int ls   = lane % F;           // lane in subgroup
    const int q    = ls / NL;            // edge slot 0..7
    const int cl   = ls % NL;            // channel octet index
    const int lbase = lane - ls;         // first lane of subgroup
    const int wave = (blockIdx.x * blockDim.x + threadIdx.x) >> 6;
    const int node = wave * NPW + lane / F;
    if (node >= n) return;

    const int beg = row_ptr[node];
    const int end = row_ptr[node + 1];
    const float sdv = sd[node];

    float m = -__builtin_inff();
    float s = 0.f;
    float acc[8];
#pragma unroll
    for (int i = 0; i < 8; ++i) acc[i] = 0.f;

    for (int base = beg; base < end; base += F) {
        const int j = base + ls;
        int   c = 0;
        float logit = -__builtin_inff();
        if (j < end) {
            c = col[j];
            float z = ss[c] + sdv;
            logit = (z > 0.f) ? z : NEG_SLOPE * z;
        }
        float cm = logit;
#pragma unroll
        for (int o = F / 2; o; o >>= 1) cm = fmaxf(cm, __shfl_xor(cm, o));
        const float newm = fmaxf(m, cm);
        const float scale = __expf(m - newm);     // first iter: exp(-inf)=0
        s *= scale;
#pragma unroll
        for (int i = 0; i < 8; ++i) acc[i] *= scale;
        const float w = __expf(logit - newm);     // inactive lanes -> 0
        float wsum = w;
#pragma unroll
        for (int o = F / 2; o; o >>= 1) wsum += __shfl_xor(wsum, o);
        s += wsum;
        m = newm;

        const int cnt = min(F, end - base);
        for (int t = 0; Q * t < cnt; ++t) {
            const int e = Q * t + q;                 // edge in chunk for this slot
            const float wt = __shfl(w, lbase + e);   // 0 for e >= cnt
            const int   ct = __shfl(c, lbase + e);   // 0 for e >= cnt (safe row)
            const uint4 hv = *(const uint4*)&hb[(size_t)ct * F + 8 * cl];
            acc[0] = fmaf(wt, bf_lo(hv.x), acc[0]);
            acc[1] = fmaf(wt, bf_hi(hv.x), acc[1]);
            acc[2] = fmaf(wt, bf_lo(hv.y), acc[2]);
            acc[3] = fmaf(wt, bf_hi(hv.y), acc[3]);
            acc[4] = fmaf(wt, bf_lo(hv.z), acc[4]);
            acc[5] = fmaf(wt, bf_hi(hv.z), acc[5]);
            acc[6] = fmaf(wt, bf_lo(hv.w), acc[6]);
            acc[7] = fmaf(wt, bf_hi(hv.w), acc[7]);
        }
    }

    // butterfly-reduce partial sums across the 8 q-slots (all lanes get total)
#pragma unroll
    for (int o = NL; o < F; o <<= 1) {
#pragma unroll
        for (int i = 0; i < 8; ++i) acc[i] += __shfl_xor(acc[i], o);
    }

    const float inv = 1.f / (s + 1e-16f);
    float val[8];
#pragma unroll
    for (int i = 0; i < 8; ++i) {
        val[i] = acc[i] * inv + bias[8 * cl + i];
        if (RELU) val[i] = fmaxf(val[i], 0.f);
    }
    if (LOGSM) {
        float lm = val[0];
#pragma unroll
        for (int i = 1; i < 8; ++i) lm = fmaxf(lm, val[i]);
#pragma unroll
        for (int o = 1; o < NL; o <<= 1) lm = fmaxf(lm, __shfl_xor(lm, o));
        float ex = 0.f;
#pragma unroll
        for (int i = 0; i < 8; ++i) ex += __expf(val[i] - lm);
#pragma unroll
        for (int o = 1; o < NL; o <<= 1) ex += __shfl_xor(ex, o);
        const float lse = lm + __logf(ex);
#pragma unroll
        for (int i = 0; i < 8; ++i) val[i] -= lse;
    }
    if (q == 0) {
        float4 v0 = make_float4(val[0], val[1], val[2], val[3]);
        float4 v1 = make_float4(val[4], val[5], val[6], val[7]);
        *(float4*)&out[(size_t)node * F + 8 * cl] = v0;
        *(float4*)&out[(size_t)node * F + 8 * cl + 4] = v1;
    }
}

// ---------------- launch ----------------

extern "C" void kernel_launch(void* const* d_in, const int* in_sizes, int n_in,
                              void* d_out, int out_size, void* d_ws, size_t ws_size,
                              hipStream_t stream) {
    const float* x  = (const float*)d_in[0];
    const int*   ei = (const int*)d_in[1];
    const float* W1 = (const float*)d_in[2];
    const float* a1s = (const float*)d_in[3];
    const float* a1d = (const float*)d_in[4];
    const float* b1  = (const float*)d_in[5];
    const float* W2 = (const float*)d_in[6];
    const float* a2s = (const float*)d_in[7];
    const float* a2d = (const float*)d_in[8];
    const float* b2  = (const float*)d_in[9];
    const float* W3 = (const float*)d_in[10];
    const float* a3s = (const float*)d_in[11];
    const float* a3d = (const float*)d_in[12];
    const float* b3  = (const float*)d_in[13];

    const int N = in_sizes[0] / 128;
    const int E = in_sizes[1] / 2;
    const int NBK = (N + 127) / 128;
    const int B = BIN_BLOCKS;

    char* wp = (char*)d_ws;
    auto alloc = [&](size_t bytes) -> void* {
        void* p = wp;
        wp += (bytes + 255) & ~(size_t)255;
        return p;
    };
    int* cnt     = (int*)alloc((size_t)N * 4);
    int* row_ptr = (int*)alloc((size_t)(N + 1) * 4);
    int* col     = (int*)alloc((size_t)(E + N) * 4);
    unsigned short* hb = (unsigned short*)alloc((size_t)N * 64 * 2);
    float* ss  = (float*)alloc((size_t)N * 4);
    float* sd  = (float*)alloc((size_t)N * 4);
    float* o1  = (float*)alloc((size_t)N * 64 * 4);
    float* o2  = (float*)alloc((size_t)N * 64 * 4);
    int* cntb  = (int*)alloc((size_t)NBK * B * 4);
    int* obb   = (int*)alloc(((size_t)NBK * B + 1) * 4);
    int* bsum  = (int*)alloc(1024 * 4);
    int* eb = (int*)o2;                               // alias: dead ranges don't overlap

    const int chunk = (E + B - 1) / B;
    const int nb2 = (NBK * B + SCAN_TILE - 1) / SCAN_TILE;
    const int nbn = (N + SCAN_TILE - 1) / SCAN_TILE;

    bin_hist_k<<<B, 256, 0, stream>>>(ei + E, E, cntb, NBK, chunk);
    scan_pass1<<<nb2, 256, 0, stream>>>(cntb, bsum, NBK * B);
    scan_pass2<<<1, 256, 0, stream>>>(bsum, obb, nb2, NBK * B);
    scan_pass3<<<nb2, 256, 0, stream>>>(cntb, bsum, obb, NBK * B);
    bin_scatter_k<<<B, 256, 0, stream>>>(ei, E, obb, eb, NBK, chunk);
    bucket_cnt_k<<<NBK, 256, 0, stream>>>(eb, obb, cnt, B, N);
    scan_pass1<<<nbn, 256, 0, stream>>>(cnt, bsum, N);
    scan_pass2<<<1, 256, 0, stream>>>(bsum, row_ptr, nbn, N);
    scan_pass3<<<nbn, 256, 0, stream>>>(cnt, bsum, row_ptr, N);
    bucket_scatter_k<<<NBK, 256, 0, stream>>>(eb, obb, row_ptr, col, B, N);

    // --- layer 1: 128 -> 64, relu ---
    gemm_tile_k<128, 64><<<(N + 63) / 64, 256, 0, stream>>>(x, W1, a1s, a1d, hb, ss, sd, N);
    gat_agg_k<64, true, false><<<(N + 3) / 4, 256, 0, stream>>>(row_ptr, col, hb, ss, sd, b1, o1, N);

    // --- layer 2: 64 -> 64, relu ---
    gemm_tile_k<64, 64><<<(N + 63) / 64, 256, 0, stream>>>(o1, W2, a2s, a2d, hb, ss, sd, N);
    gat_agg_k<64, true, false><<<(N + 3) / 4, 256, 0, stream>>>(row_ptr, col, hb, ss, sd, b2, o2, N);

    // --- layer 3: 64 -> 32, log_softmax ---
    gemm_tile_k<64, 32><<<(N + 127) / 128, 256, 0, stream>>>(o2, W3, a3s, a3d, hb, ss, sd, N);
    gat_agg_k<32, false, true><<<(N + 7) / 8, 256, 0, stream>>>(row_ptr, col, hb, ss, sd, b3,
                                                                (float*)d_out, N);
}

// Round 7
// 360.010 us; speedup vs baseline: 3.0469x; 1.0890x over previous
//
#include <hip/hip_runtime.h>
#include <hip/hip_fp16.h>
#include <cstddef>
#include <cstdint>

#define NEG_SLOPE 0.2f

__device__ __forceinline__ unsigned short f2bf(float f) {
    unsigned int u = __float_as_uint(f);
    u = (u + 0x7fff + ((u >> 16) & 1)) >> 16;   // round-to-nearest-even
    return (unsigned short)u;
}
__device__ __forceinline__ float bf_lo(unsigned int u) { return __uint_as_float(u << 16); }
__device__ __forceinline__ float bf_hi(unsigned int u) { return __uint_as_float(u & 0xffff0000u); }

// ---------------- hierarchical exclusive scan: in[n] -> out[n+1] ----------------

constexpr int SCAN_TILE = 1024;   // 256 threads x 4 elems

__global__ __launch_bounds__(256) void scan_pass1(const int* __restrict__ in,
                                                  int* __restrict__ bsum, int n) {
    const int tid = threadIdx.x;
    const int base = blockIdx.x * SCAN_TILE + tid * 4;
    int s = 0;
#pragma unroll
    for (int k = 0; k < 4; ++k) {
        int i = base + k;
        if (i < n) s += in[i];
    }
    for (int o = 1; o < 64; o <<= 1) s += __shfl_xor(s, o);
    __shared__ int wsum[4];
    if ((tid & 63) == 0) wsum[tid >> 6] = s;
    __syncthreads();
    if (tid == 0) bsum[blockIdx.x] = wsum[0] + wsum[1] + wsum[2] + wsum[3];
}

__global__ __launch_bounds__(256) void scan_pass2(int* __restrict__ bsum,
                                                  int* __restrict__ out,
                                                  int nb, int n) {
    __shared__ int sh[1024];
    const int tid = threadIdx.x;
    for (int i = tid; i < nb; i += 256) sh[i] = bsum[i];
    __syncthreads();
    if (tid == 0) {
        int run = 0;
        for (int i = 0; i < nb; ++i) { int c = sh[i]; sh[i] = run; run += c; }
        out[n] = run;                    // grand total
    }
    __syncthreads();
    for (int i = tid; i < nb; i += 256) bsum[i] = sh[i];
}

__global__ __launch_bounds__(256) void scan_pass3(const int* __restrict__ in,
                                                  const int* __restrict__ bsum,
                                                  int* __restrict__ out, int n) {
    const int tid = threadIdx.x;
    const int lane = tid & 63;
    const int wid = tid >> 6;
    const int base = blockIdx.x * SCAN_TILE + tid * 4;
    int v[4];
    int tsum = 0;
#pragma unroll
    for (int k = 0; k < 4; ++k) {
        int i = base + k;
        v[k] = (i < n) ? in[i] : 0;
        tsum += v[k];
    }
    int inc = tsum;
    for (int o = 1; o < 64; o <<= 1) {
        int t = __shfl_up(inc, o);
        if (lane >= o) inc += t;
    }
    __shared__ int wtot[4];
    if (lane == 63) wtot[wid] = inc;
    __syncthreads();
    int woff = 0;
    for (int w = 0; w < wid; ++w) woff += wtot[w];
    int off = bsum[blockIdx.x] + woff + (inc - tsum);
#pragma unroll
    for (int k = 0; k < 4; ++k) {
        int i = base + k;
        if (i < n) { out[i] = off; off += v[k]; }
    }
}

// ---------------- binned CSR build ----------------

constexpr int BIN_BLOCKS = 128;
constexpr int MAX_NBK = 1024;            // supports N <= 131072 (= packing limit)

__global__ __launch_bounds__(256) void bin_hist_k(const int* __restrict__ dst, int E,
                                                  int* __restrict__ cntb, int nbk,
                                                  int chunk) {
    __shared__ int hist[MAX_NBK];
    for (int i = threadIdx.x; i < nbk; i += 256) hist[i] = 0;
    __syncthreads();
    const int lo = blockIdx.x * chunk;
    const int hi = min(lo + chunk, E);
    for (int e = lo + threadIdx.x; e < hi; e += 256)
        atomicAdd(&hist[dst[e] >> 7], 1);
    __syncthreads();
    for (int i = threadIdx.x; i < nbk; i += 256)
        cntb[i * gridDim.x + blockIdx.x] = hist[i];   // bucket-major
}

__global__ __launch_bounds__(256) void bin_scatter_k(const int* __restrict__ ei, int E,
                                                     const int* __restrict__ obb,
                                                     int* __restrict__ eb, int nbk,
                                                     int chunk) {
    __shared__ int cur[MAX_NBK];
    for (int i = threadIdx.x; i < nbk; i += 256) cur[i] = 0;
    __syncthreads();
    const int lo = blockIdx.x * chunk;
    const int hi = min(lo + chunk, E);
    for (int e = lo + threadIdx.x; e < hi; e += 256) {
        int s = ei[e];
        int d = ei[E + e];
        int b = d >> 7;
        int idx = atomicAdd(&cur[b], 1);
        eb[obb[b * gridDim.x + blockIdx.x] + idx] = (s << 7) | (d & 127);
    }
}

__global__ __launch_bounds__(256) void bucket_cnt_k(const int* __restrict__ eb,
                                                    const int* __restrict__ obb,
                                                    int* __restrict__ cnt,
                                                    int B, int n) {
    __shared__ int c[128];
    const int b = blockIdx.x;
    const int t = threadIdx.x;
    const int beg = obb[b * B];
    const int end = obb[(b + 1) * B];
    if (t < 128) c[t] = 1;               // self-loop
    __syncthreads();
    for (int i = beg + t; i < end; i += 256)
        atomicAdd(&c[eb[i] & 127], 1);
    __syncthreads();
    const int node = b * 128 + t;
    if (t < 128 && node < n) cnt[node] = c[t];
}

__global__ __launch_bounds__(256) void bucket_scatter_k(const int* __restrict__ eb,
                                                        const int* __restrict__ obb,
                                                        const int* __restrict__ row_ptr,
                                                        int* __restrict__ col,
                                                        int B, int n) {
    __shared__ int c[128];
    __shared__ int rp[128];
    const int b = blockIdx.x;
    const int t = threadIdx.x;
    const int beg = obb[b * B];
    const int end = obb[(b + 1) * B];
    const int node = b * 128 + t;
    if (t < 128) {
        c[t] = 1;
        if (node < n) {
            rp[t] = row_ptr[node];
            col[rp[t]] = node;           // self-loop in slot 0
        }
    }
    __syncthreads();
    for (int i = beg + t; i < end; i += 256) {
        int p = eb[i];
        int dl = p & 127;
        int idx = atomicAdd(&c[dl], 1);
        col[rp[dl] + idx] = p >> 7;
    }
}

// ---------------- dense: LDS-tiled GEMM -> bf16 h + fused attention dots -------

template <int K, int F>
__launch_bounds__(256)
__global__ void gemm_tile_k(const float* __restrict__ x, const float* __restrict__ W,
                            const float* __restrict__ a_s, const float* __restrict__ a_d,
                            unsigned short* __restrict__ hb, float* __restrict__ ss,
                            float* __restrict__ sd, int n) {
    constexpr int KC = 64;
    constexpr int NCHUNK = K / KC;
    constexpr int CG = F / 4;
    constexpr int MT = 256 / CG * 4;
    constexpr int XS_STRIDE = KC + 4;

    __shared__ float xs[MT][XS_STRIDE];
    __shared__ float ws[KC][F];

    const int tid = threadIdx.x;
    const int cg = tid % CG;
    const int rg = tid / CG;
    const int base = blockIdx.x * MT;

    float4 acc[4];
#pragma unroll
    for (int i = 0; i < 4; ++i) acc[i] = make_float4(0.f, 0.f, 0.f, 0.f);

    for (int kc = 0; kc < NCHUNK; ++kc) {
#pragma unroll
        for (int i = 0; i < MT * KC / 4 / 256; ++i) {
            int flat = tid + i * 256;
            int row = flat / (KC / 4);
            int c4 = flat % (KC / 4);
            float4 v = make_float4(0.f, 0.f, 0.f, 0.f);
            if (base + row < n)
                v = *(const float4*)&x[(size_t)(base + row) * K + kc * KC + 4 * c4];
            *(float4*)&xs[row][4 * c4] = v;
        }
#pragma unroll
        for (int i = 0; i < KC * F / 4 / 256; ++i) {
            int flat = tid + i * 256;
            int wrow = flat / (F / 4);
            int wc4 = flat % (F / 4);
            *(float4*)&ws[wrow][4 * wc4] =
                *(const float4*)&W[(size_t)(kc * KC + wrow) * F + 4 * wc4];
        }
        __syncthreads();

#pragma unroll
        for (int k = 0; k < KC; k += 4) {
            float4 w0 = *(const float4*)&ws[k + 0][cg * 4];
            float4 w1 = *(const float4*)&ws[k + 1][cg * 4];
            float4 w2 = *(const float4*)&ws[k + 2][cg * 4];
            float4 w3 = *(const float4*)&ws[k + 3][cg * 4];
#pragma unroll
            for (int i = 0; i < 4; ++i) {
                float4 a = *(const float4*)&xs[rg * 4 + i][k];
                acc[i].x = fmaf(a.x, w0.x, acc[i].x);
                acc[i].y = fmaf(a.x, w0.y, acc[i].y);
                acc[i].z = fmaf(a.x, w0.z, acc[i].z);
                acc[i].w = fmaf(a.x, w0.w, acc[i].w);
                acc[i].x = fmaf(a.y, w1.x, acc[i].x);
                acc[i].y = fmaf(a.y, w1.y, acc[i].y);
                acc[i].z = fmaf(a.y, w1.z, acc[i].z);
                acc[i].w = fmaf(a.y, w1.w, acc[i].w);
                acc[i].x = fmaf(a.z, w2.x, acc[i].x);
                acc[i].y = fmaf(a.z, w2.y, acc[i].y);
                acc[i].z = fmaf(a.z, w2.z, acc[i].z);
                acc[i].w = fmaf(a.z, w2.w, acc[i].w);
                acc[i].x = fmaf(a.w, w3.x, acc[i].x);
                acc[i].y = fmaf(a.w, w3.y, acc[i].y);
                acc[i].z = fmaf(a.w, w3.z, acc[i].z);
                acc[i].w = fmaf(a.w, w3.w, acc[i].w);
            }
        }
        __syncthreads();
    }

    const float4 as4 = *(const float4*)&a_s[4 * cg];
    const float4 ad4 = *(const float4*)&a_d[4 * cg];
#pragma unroll
    for (int i = 0; i < 4; ++i) {
        const int node = base + rg * 4 + i;
        float ps = acc[i].x * as4.x + acc[i].y * as4.y + acc[i].z * as4.z + acc[i].w * as4.w;
        float pd = acc[i].x * ad4.x + acc[i].y * ad4.y + acc[i].z * ad4.z + acc[i].w * ad4.w;
#pragma unroll
        for (int o = CG / 2; o; o >>= 1) {
            ps += __shfl_xor(ps, o);
            pd += __shfl_xor(pd, o);
        }
        if (node < n) {
            ushort4 hv;
            hv.x = f2bf(acc[i].x); hv.y = f2bf(acc[i].y);
            hv.z = f2bf(acc[i].z); hv.w = f2bf(acc[i].w);
            *(ushort4*)&hb[(size_t)node * F + 4 * cg] = hv;
            if (cg == 0) { ss[node] = ps; sd[node] = pd; }
        }
    }
}

// ---------------- sparse: online-softmax aggregation, bf16 payload -------------
// Subgroup of S lanes per node (S <= F): lane = q*NL + cl. NL = F/8 lanes per
// row (16 B of bf16 each), Q = S/NL edge slots. Chunk = S edges: one logit per
// lane (fp32-exact ss/sd); w (fp16, 15 bits) and c (17 bits) packed into one
// u32 so the gather loop needs a single shuffle per iteration. Epilogue:
// butterfly-reduce acc across q slots, bias/relu/log-softmax, fp32 out.

template <int F, int S, bool RELU, bool LOGSM>
__launch_bounds__(256)
__global__ void gat_agg_k(const int* __restrict__ row_ptr, const int* __restrict__ col,
                          const unsigned short* __restrict__ hb,
                          const float* __restrict__ ss, const float* __restrict__ sd,
                          const float* __restrict__ bias,
                          float* __restrict__ out, int n) {
    constexpr int NPW = 64 / S;          // nodes per wave
    constexpr int NL = F / 8;            // lanes per row (8 bf16 channels each)
    constexpr int Q = S / NL;            // edge slots
    const int lane = threadIdx.x & 63;
    const int ls   = lane % S;           // lane in subgroup
    const int q    = ls / NL;            // edge slot
    const int cl   = ls % NL;            // channel octet index
    const int lbase = lane - ls;         // first lane of subgroup
    const int wave = (blockIdx.x * blockDim.x + threadIdx.x) >> 6;
    const int node = wave * NPW + lane / S;
    if (node >= n) return;

    const int beg = row_ptr[node];
    const int end = row_ptr[node + 1];
    const float sdv = sd[node];

    float m = -__builtin_inff();
    float s = 0.f;
    float acc[8];
#pragma unroll
    for (int i = 0; i < 8; ++i) acc[i] = 0.f;

    for (int base = beg; base < end; base += S) {
        const int j = base + ls;
        int   c = 0;
        float logit = -__builtin_inff();
        if (j < end) {
            c = col[j];
            float z = ss[c] + sdv;
            logit = (z > 0.f) ? z : NEG_SLOPE * z;
        }
        float cm = logit;
#pragma unroll
        for (int o = S / 2; o; o >>= 1) cm = fmaxf(cm, __shfl_xor(cm, o));
        const float newm = fmaxf(m, cm);
        const float scale = __expf(m - newm);     // first iter: exp(-inf)=0
        s *= scale;
#pragma unroll
        for (int i = 0; i < 8; ++i) acc[i] *= scale;
        const float w = __expf(logit - newm);     // inactive lanes -> 0
        float wsum = w;
#pragma unroll
        for (int o = S / 2; o; o >>= 1) wsum += __shfl_xor(wsum, o);
        s += wsum;
        m = newm;

        // pack: fp16(w) in bits [31:17] (w>=0 so sign bit is 0), c in [16:0]
        const unsigned int pk =
            ((unsigned int)__half_as_ushort(__float2half(w)) << 17) | (unsigned int)c;

        const int cnt = min(S, end - base);
        for (int t = 0; Q * t < cnt; ++t) {
            const int e = Q * t + q;                 // e < S (Q divides S)
            const unsigned int pe = __shfl(pk, lbase + e);
            const int   ct = (int)(pe & 0x1ffffu);
            const float wt = __half2float(__ushort_as_half((unsigned short)(pe >> 17)));
            const uint4 hv = *(const uint4*)&hb[(size_t)ct * F + 8 * cl];
            acc[0] = fmaf(wt, bf_lo(hv.x), acc[0]);
            acc[1] = fmaf(wt, bf_hi(hv.x), acc[1]);
            acc[2] = fmaf(wt, bf_lo(hv.y), acc[2]);
            acc[3] = fmaf(wt, bf_hi(hv.y), acc[3]);
            acc[4] = fmaf(wt, bf_lo(hv.z), acc[4]);
            acc[5] = fmaf(wt, bf_hi(hv.z), acc[5]);
            acc[6] = fmaf(wt, bf_lo(hv.w), acc[6]);
            acc[7] = fmaf(wt, bf_hi(hv.w), acc[7]);
        }
    }

    // butterfly-reduce partial sums across the Q edge slots
#pragma unroll
    for (int o = NL; o < S; o <<= 1) {
#pragma unroll
        for (int i = 0; i < 8; ++i) acc[i] += __shfl_xor(acc[i], o);
    }

    const float inv = 1.f / (s + 1e-16f);
    float val[8];
#pragma unroll
    for (int i = 0; i < 8; ++i) {
        val[i] = acc[i] * inv + bias[8 * cl + i];
        if (RELU) val[i] = fmaxf(val[i], 0.f);
    }
    if (LOGSM) {
        float lm = val[0];
#pragma unroll
        for (int i = 1; i < 8; ++i) lm = fmaxf(lm, val[i]);
#pragma unroll
        for (int o = 1; o < NL; o <<= 1) lm = fmaxf(lm, __shfl_xor(lm, o));
        float ex = 0.f;
#pragma unroll
        for (int i = 0; i < 8; ++i) ex += __expf(val[i] - lm);
#pragma unroll
        for (int o = 1; o < NL; o <<= 1) ex += __shfl_xor(ex, o);
        const float lse = lm + __logf(ex);
#pragma unroll
        for (int i = 0; i < 8; ++i) val[i] -= lse;
    }
    if (q == 0) {
        float4 v0 = make_float4(val[0], val[1], val[2], val[3]);
        float4 v1 = make_float4(val[4], val[5], val[6], val[7]);
        *(float4*)&out[(size_t)node * F + 8 * cl] = v0;
        *(float4*)&out[(size_t)node * F + 8 * cl + 4] = v1;
    }
}

// ---------------- launch ----------------

extern "C" void kernel_launch(void* const* d_in, const int* in_sizes, int n_in,
                              void* d_out, int out_size, void* d_ws, size_t ws_size,
                              hipStream_t stream) {
    const float* x  = (const float*)d_in[0];
    const int*   ei = (const int*)d_in[1];
    const float* W1 = (const float*)d_in[2];
    const float* a1s = (const float*)d_in[3];
    const float* a1d = (const float*)d_in[4];
    const float* b1  = (const float*)d_in[5];
    const float* W2 = (const float*)d_in[6];
    const float* a2s = (const float*)d_in[7];
    const float* a2d = (const float*)d_in[8];
    const float* b2  = (const float*)d_in[9];
    const float* W3 = (const float*)d_in[10];
    const float* a3s = (const float*)d_in[11];
    const float* a3d = (const float*)d_in[12];
    const float* b3  = (const float*)d_in[13];

    const int N = in_sizes[0] / 128;
    const int E = in_sizes[1] / 2;
    const int NBK = (N + 127) / 128;
    const int B = BIN_BLOCKS;

    char* wp = (char*)d_ws;
    auto alloc = [&](size_t bytes) -> void* {
        void* p = wp;
        wp += (bytes + 255) & ~(size_t)255;
        return p;
    };
    int* cnt     = (int*)alloc((size_t)N * 4);
    int* row_ptr = (int*)alloc((size_t)(N + 1) * 4);
    int* col     = (int*)alloc((size_t)(E + N) * 4);
    unsigned short* hb = (unsigned short*)alloc((size_t)N * 64 * 2);
    float* ss  = (float*)alloc((size_t)N * 4);
    float* sd  = (float*)alloc((size_t)N * 4);
    float* o1  = (float*)alloc((size_t)N * 64 * 4);
    float* o2  = (float*)alloc((size_t)N * 64 * 4);
    int* cntb  = (int*)alloc((size_t)NBK * B * 4);
    int* obb   = (int*)alloc(((size_t)NBK * B + 1) * 4);
    int* bsum  = (int*)alloc(1024 * 4);
    int* eb = (int*)o2;                               // alias: dead ranges don't overlap

    const int chunk = (E + B - 1) / B;
    const int nb2 = (NBK * B + SCAN_TILE - 1) / SCAN_TILE;
    const int nbn = (N + SCAN_TILE - 1) / SCAN_TILE;

    bin_hist_k<<<B, 256, 0, stream>>>(ei + E, E, cntb, NBK, chunk);
    scan_pass1<<<nb2, 256, 0, stream>>>(cntb, bsum, NBK * B);
    scan_pass2<<<1, 256, 0, stream>>>(bsum, obb, nb2, NBK * B);
    scan_pass3<<<nb2, 256, 0, stream>>>(cntb, bsum, obb, NBK * B);
    bin_scatter_k<<<B, 256, 0, stream>>>(ei, E, obb, eb, NBK, chunk);
    bucket_cnt_k<<<NBK, 256, 0, stream>>>(eb, obb, cnt, B, N);
    scan_pass1<<<nbn, 256, 0, stream>>>(cnt, bsum, N);
    scan_pass2<<<1, 256, 0, stream>>>(bsum, row_ptr, nbn, N);
    scan_pass3<<<nbn, 256, 0, stream>>>(cnt, bsum, row_ptr, N);
    bucket_scatter_k<<<NBK, 256, 0, stream>>>(eb, obb, row_ptr, col, B, N);

    // --- layer 1: 128 -> 64, relu ---  (agg: S=32 -> 8 nodes/block)
    gemm_tile_k<128, 64><<<(N + 63) / 64, 256, 0, stream>>>(x, W1, a1s, a1d, hb, ss, sd, N);
    gat_agg_k<64, 32, true, false><<<(N + 7) / 8, 256, 0, stream>>>(row_ptr, col, hb, ss, sd, b1, o1, N);

    // --- layer 2: 64 -> 64, relu ---
    gemm_tile_k<64, 64><<<(N + 63) / 64, 256, 0, stream>>>(o1, W2, a2s, a2d, hb, ss, sd, N);
    gat_agg_k<64, 32, true, false><<<(N + 7) / 8, 256, 0, stream>>>(row_ptr, col, hb, ss, sd, b2, o2, N);

    // --- layer 3: 64 -> 32, log_softmax ---  (agg: S=16 -> 16 nodes/block)
    gemm_tile_k<64, 32><<<(N + 127) / 128, 256, 0, stream>>>(o2, W3, a3s, a3d, hb, ss, sd, N);
    gat_agg_k<32, 16, false, true><<<(N + 15) / 16, 256, 0, stream>>>(row_ptr, col, hb, ss, sd, b3,
                                                                      (float*)d_out, N);
}

// Round 8
// 356.542 us; speedup vs baseline: 3.0765x; 1.0097x over previous
//
#include <hip/hip_runtime.h>
#include <hip/hip_fp16.h>
#include <cstddef>
#include <cstdint>

#define NEG_SLOPE 0.2f

__device__ __forceinline__ unsigned short f2bf(float f) {
    unsigned int u = __float_as_uint(f);
    u = (u + 0x7fff + ((u >> 16) & 1)) >> 16;   // round-to-nearest-even
    return (unsigned short)u;
}
__device__ __forceinline__ float bf_lo(unsigned int u) { return __uint_as_float(u << 16); }
__device__ __forceinline__ float bf_hi(unsigned int u) { return __uint_as_float(u & 0xffff0000u); }

// ---------------- hierarchical exclusive scan: in[n] -> out[n+1] ----------------

constexpr int SCAN_TILE = 1024;   // 256 threads x 4 elems

__global__ __launch_bounds__(256) void scan_pass1(const int* __restrict__ in,
                                                  int* __restrict__ bsum, int n) {
    const int tid = threadIdx.x;
    const int base = blockIdx.x * SCAN_TILE + tid * 4;
    int s = 0;
#pragma unroll
    for (int k = 0; k < 4; ++k) {
        int i = base + k;
        if (i < n) s += in[i];
    }
    for (int o = 1; o < 64; o <<= 1) s += __shfl_xor(s, o);
    __shared__ int wsum[4];
    if ((tid & 63) == 0) wsum[tid >> 6] = s;
    __syncthreads();
    if (tid == 0) bsum[blockIdx.x] = wsum[0] + wsum[1] + wsum[2] + wsum[3];
}

__global__ __launch_bounds__(256) void scan_pass2(int* __restrict__ bsum,
                                                  int* __restrict__ out,
                                                  int nb, int n) {
    __shared__ int sh[1024];
    const int tid = threadIdx.x;
    for (int i = tid; i < nb; i += 256) sh[i] = bsum[i];
    __syncthreads();
    if (tid == 0) {
        int run = 0;
        for (int i = 0; i < nb; ++i) { int c = sh[i]; sh[i] = run; run += c; }
        out[n] = run;                    // grand total
    }
    __syncthreads();
    for (int i = tid; i < nb; i += 256) bsum[i] = sh[i];
}

__global__ __launch_bounds__(256) void scan_pass3(const int* __restrict__ in,
                                                  const int* __restrict__ bsum,
                                                  int* __restrict__ out, int n) {
    const int tid = threadIdx.x;
    const int lane = tid & 63;
    const int wid = tid >> 6;
    const int base = blockIdx.x * SCAN_TILE + tid * 4;
    int v[4];
    int tsum = 0;
#pragma unroll
    for (int k = 0; k < 4; ++k) {
        int i = base + k;
        v[k] = (i < n) ? in[i] : 0;
        tsum += v[k];
    }
    int inc = tsum;
    for (int o = 1; o < 64; o <<= 1) {
        int t = __shfl_up(inc, o);
        if (lane >= o) inc += t;
    }
    __shared__ int wtot[4];
    if (lane == 63) wtot[wid] = inc;
    __syncthreads();
    int woff = 0;
    for (int w = 0; w < wid; ++w) woff += wtot[w];
    int off = bsum[blockIdx.x] + woff + (inc - tsum);
#pragma unroll
    for (int k = 0; k < 4; ++k) {
        int i = base + k;
        if (i < n) { out[i] = off; off += v[k]; }
    }
}

// ---------------- binned CSR build ----------------
// Bucket = dst >> 7 (128 nodes/bucket). Edges packed (src<<7)|dstLow (src<2^17).

constexpr int BIN_BLOCKS = 256;
constexpr int MAX_NBK = 1024;            // supports N <= 131072 (= packing limit)

__global__ __launch_bounds__(256) void bin_hist_k(const int* __restrict__ dst, int E,
                                                  int* __restrict__ cntb, int nbk,
                                                  int chunk) {
    __shared__ int hist[MAX_NBK];
    for (int i = threadIdx.x; i < nbk; i += 256) hist[i] = 0;
    __syncthreads();
    const int lo = blockIdx.x * chunk;
    const int hi = min(lo + chunk, E);
    for (int e = lo + threadIdx.x; e < hi; e += 256)
        atomicAdd(&hist[dst[e] >> 7], 1);
    __syncthreads();
    for (int i = threadIdx.x; i < nbk; i += 256)
        cntb[i * gridDim.x + blockIdx.x] = hist[i];   // bucket-major
}

// per-block obb slice cached in LDS -> per-edge path is LDS-only
__global__ __launch_bounds__(256) void bin_scatter_k(const int* __restrict__ ei, int E,
                                                     const int* __restrict__ obb,
                                                     int* __restrict__ eb, int nbk,
                                                     int chunk) {
    __shared__ int cur[MAX_NBK];
    __shared__ int off_s[MAX_NBK];
    const int B = gridDim.x;
    for (int i = threadIdx.x; i < nbk; i += 256) {
        cur[i] = 0;
        off_s[i] = obb[i * B + blockIdx.x];
    }
    __syncthreads();
    const int lo = blockIdx.x * chunk;
    const int hi = min(lo + chunk, E);
    for (int e = lo + threadIdx.x; e < hi; e += 256) {
        int s = ei[e];
        int d = ei[E + e];
        int b = d >> 7;
        int idx = atomicAdd(&cur[b], 1);
        eb[off_s[b] + idx] = (s << 7) | (d & 127);
    }
}

__global__ __launch_bounds__(256) void bucket_cnt_k(const int* __restrict__ eb,
                                                    const int* __restrict__ obb,
                                                    int* __restrict__ cnt,
                                                    int B, int n) {
    __shared__ int c[128];
    const int b = blockIdx.x;
    const int t = threadIdx.x;
    const int beg = obb[b * B];
    const int end = obb[(b + 1) * B];    // last bucket: obb[nbk*B] = total
    if (t < 128) c[t] = 1;               // self-loop
    __syncthreads();
    for (int i = beg + t; i < end; i += 256)
        atomicAdd(&c[eb[i] & 127], 1);
    __syncthreads();
    const int node = b * 128 + t;
    if (t < 128 && node < n) cnt[node] = c[t];
}

__global__ __launch_bounds__(256) void bucket_scatter_k(const int* __restrict__ eb,
                                                        const int* __restrict__ obb,
                                                        const int* __restrict__ row_ptr,
                                                        int* __restrict__ col,
                                                        int B, int n) {
    __shared__ int c[128];
    __shared__ int rp[128];
    const int b = blockIdx.x;
    const int t = threadIdx.x;
    const int beg = obb[b * B];
    const int end = obb[(b + 1) * B];
    const int node = b * 128 + t;
    if (t < 128) {
        c[t] = 1;
        if (node < n) {
            rp[t] = row_ptr[node];
            col[rp[t]] = node;           // self-loop in slot 0
        }
    }
    __syncthreads();
    for (int i = beg + t; i < end; i += 256) {
        int p = eb[i];
        int dl = p & 127;
        int idx = atomicAdd(&c[dl], 1);
        col[rp[dl] + idx] = p >> 7;
    }
}

// ---------------- dense: LDS-tiled GEMM -> bf16 h + fused attention dots -------
// ROWS = rows per thread (micro-tile ROWS x 4). F=64,ROWS=8: 128 FMA per
// 12 ds_read_b128 per k-step; MT=128 rows/block.

template <int K, int F, int ROWS>
__launch_bounds__(256)
__global__ void gemm_tile_k(const float* __restrict__ x, const float* __restrict__ W,
                            const float* __restrict__ a_s, const float* __restrict__ a_d,
                            unsigned short* __restrict__ hb, float* __restrict__ ss,
                            float* __restrict__ sd, int n) {
    constexpr int KC = 64;
    constexpr int NCHUNK = K / KC;
    constexpr int CG = F / 4;            // col groups
    constexpr int MT = (256 / CG) * ROWS;
    constexpr int XS_STRIDE = KC + 4;

    __shared__ float xs[MT][XS_STRIDE];
    __shared__ float ws[KC][F];

    const int tid = threadIdx.x;
    const int cg = tid % CG;
    const int rg = tid / CG;
    const int base = blockIdx.x * MT;

    float4 acc[ROWS];
#pragma unroll
    for (int i = 0; i < ROWS; ++i) acc[i] = make_float4(0.f, 0.f, 0.f, 0.f);

    for (int kc = 0; kc < NCHUNK; ++kc) {
#pragma unroll
        for (int i = 0; i < MT * KC / 4 / 256; ++i) {
            int flat = tid + i * 256;
            int row = flat / (KC / 4);
            int c4 = flat % (KC / 4);
            float4 v = make_float4(0.f, 0.f, 0.f, 0.f);
            if (base + row < n)
                v = *(const float4*)&x[(size_t)(base + row) * K + kc * KC + 4 * c4];
            *(float4*)&xs[row][4 * c4] = v;
        }
#pragma unroll
        for (int i = 0; i < KC * F / 4 / 256; ++i) {
            int flat = tid + i * 256;
            int wrow = flat / (F / 4);
            int wc4 = flat % (F / 4);
            *(float4*)&ws[wrow][4 * wc4] =
                *(const float4*)&W[(size_t)(kc * KC + wrow) * F + 4 * wc4];
        }
        __syncthreads();

#pragma unroll
        for (int k = 0; k < KC; k += 4) {
            float4 w0 = *(const float4*)&ws[k + 0][cg * 4];
            float4 w1 = *(const float4*)&ws[k + 1][cg * 4];
            float4 w2 = *(const float4*)&ws[k + 2][cg * 4];
            float4 w3 = *(const float4*)&ws[k + 3][cg * 4];
#pragma unroll
            for (int i = 0; i < ROWS; ++i) {
                float4 a = *(const float4*)&xs[rg * ROWS + i][k];
                acc[i].x = fmaf(a.x, w0.x, acc[i].x);
                acc[i].y = fmaf(a.x, w0.y, acc[i].y);
                acc[i].z = fmaf(a.x, w0.z, acc[i].z);
                acc[i].w = fmaf(a.x, w0.w, acc[i].w);
                acc[i].x = fmaf(a.y, w1.x, acc[i].x);
                acc[i].y = fmaf(a.y, w1.y, acc[i].y);
                acc[i].z = fmaf(a.y, w1.z, acc[i].z);
                acc[i].w = fmaf(a.y, w1.w, acc[i].w);
                acc[i].x = fmaf(a.z, w2.x, acc[i].x);
                acc[i].y = fmaf(a.z, w2.y, acc[i].y);
                acc[i].z = fmaf(a.z, w2.z, acc[i].z);
                acc[i].w = fmaf(a.z, w2.w, acc[i].w);
                acc[i].x = fmaf(a.w, w3.x, acc[i].x);
                acc[i].y = fmaf(a.w, w3.y, acc[i].y);
                acc[i].z = fmaf(a.w, w3.z, acc[i].z);
                acc[i].w = fmaf(a.w, w3.w, acc[i].w);
            }
        }
        __syncthreads();
    }

    const float4 as4 = *(const float4*)&a_s[4 * cg];
    const float4 ad4 = *(const float4*)&a_d[4 * cg];
#pragma unroll
    for (int i = 0; i < ROWS; ++i) {
        const int node = base + rg * ROWS + i;
        float ps = acc[i].x * as4.x + acc[i].y * as4.y + acc[i].z * as4.z + acc[i].w * as4.w;
        float pd = acc[i].x * ad4.x + acc[i].y * ad4.y + acc[i].z * ad4.z + acc[i].w * ad4.w;
#pragma unroll
        for (int o = CG / 2; o; o >>= 1) {
            ps += __shfl_xor(ps, o);
            pd += __shfl_xor(pd, o);
        }
        if (node < n) {
            ushort4 hv;
            hv.x = f2bf(acc[i].x); hv.y = f2bf(acc[i].y);
            hv.z = f2bf(acc[i].z); hv.w = f2bf(acc[i].w);
            *(ushort4*)&hb[(size_t)node * F + 4 * cg] = hv;
            if (cg == 0) { ss[node] = ps; sd[node] = pd; }
        }
    }
}

// ---------------- sparse: online-softmax aggregation, bf16 payload -------------

template <int F, int S, bool RELU, bool LOGSM>
__launch_bounds__(256)
__global__ void gat_agg_k(const int* __restrict__ row_ptr, const int* __restrict__ col,
                          const unsigned short* __restrict__ hb,
                          const float* __restrict__ ss, const float* __restrict__ sd,
                          const float* __restrict__ bias,
                          float* __restrict__ out, int n) {
    constexpr int NPW = 64 / S;          // nodes per wave
    constexpr int NL = F / 8;            // lanes per row (8 bf16 channels each)
    constexpr int Q = S / NL;            // edge slots
    const int lane = threadIdx.x & 63;
    const int ls   = lane % S;           // lane in subgroup
    const int q    = ls / NL;            // edge slot
    const int cl   = ls % NL;            // channel octet index
    const int lbase = lane - ls;         // first lane of subgroup
    const int wave = (blockIdx.x * blockDim.x + threadIdx.x) >> 6;
    const int node = wave * NPW + lane / S;
    if (node >= n) return;

    const int beg = row_ptr[node];
    const int end = row_ptr[node + 1];
    const float sdv = sd[node];

    float m = -__builtin_inff();
    float s = 0.f;
    float acc[8];
#pragma unroll
    for (int i = 0; i < 8; ++i) acc[i] = 0.f;

    for (int base = beg; base < end; base += S) {
        const int j = base + ls;
        int   c = 0;
        float logit = -__builtin_inff();
        if (j < end) {
            c = col[j];
            float z = ss[c] + sdv;
            logit = (z > 0.f) ? z : NEG_SLOPE * z;
        }
        float cm = logit;
#pragma unroll
        for (int o = S / 2; o; o >>= 1) cm = fmaxf(cm, __shfl_xor(cm, o));
        const float newm = fmaxf(m, cm);
        const float scale = __expf(m - newm);     // first iter: exp(-inf)=0
        s *= scale;
#pragma unroll
        for (int i = 0; i < 8; ++i) acc[i] *= scale;
        const float w = __expf(logit - newm);     // inactive lanes -> 0
        float wsum = w;
#pragma unroll
        for (int o = S / 2; o; o >>= 1) wsum += __shfl_xor(wsum, o);
        s += wsum;
        m = newm;

        // pack: fp16(w) in bits [31:17] (w>=0 so sign bit is 0), c in [16:0]
        const unsigned int pk =
            ((unsigned int)__half_as_ushort(__float2half(w)) << 17) | (unsigned int)c;

        const int cnt = min(S, end - base);
        for (int t = 0; Q * t < cnt; ++t) {
            const int e = Q * t + q;                 // e < S (Q divides S)
            const unsigned int pe = __shfl(pk, lbase + e);
            const int   ct = (int)(pe & 0x1ffffu);
            const float wt = __half2float(__ushort_as_half((unsigned short)(pe >> 17)));
            const uint4 hv = *(const uint4*)&hb[(size_t)ct * F + 8 * cl];
            acc[0] = fmaf(wt, bf_lo(hv.x), acc[0]);
            acc[1] = fmaf(wt, bf_hi(hv.x), acc[1]);
            acc[2] = fmaf(wt, bf_lo(hv.y), acc[2]);
            acc[3] = fmaf(wt, bf_hi(hv.y), acc[3]);
            acc[4] = fmaf(wt, bf_lo(hv.z), acc[4]);
            acc[5] = fmaf(wt, bf_hi(hv.z), acc[5]);
            acc[6] = fmaf(wt, bf_lo(hv.w), acc[6]);
            acc[7] = fmaf(wt, bf_hi(hv.w), acc[7]);
        }
    }

    // butterfly-reduce partial sums across the Q edge slots
#pragma unroll
    for (int o = NL; o < S; o <<= 1) {
#pragma unroll
        for (int i = 0; i < 8; ++i) acc[i] += __shfl_xor(acc[i], o);
    }

    const float inv = 1.f / (s + 1e-16f);
    float val[8];
#pragma unroll
    for (int i = 0; i < 8; ++i) {
        val[i] = acc[i] * inv + bias[8 * cl + i];
        if (RELU) val[i] = fmaxf(val[i], 0.f);
    }
    if (LOGSM) {
        float lm = val[0];
#pragma unroll
        for (int i = 1; i < 8; ++i) lm = fmaxf(lm, val[i]);
#pragma unroll
        for (int o = 1; o < NL; o <<= 1) lm = fmaxf(lm, __shfl_xor(lm, o));
        float ex = 0.f;
#pragma unroll
        for (int i = 0; i < 8; ++i) ex += __expf(val[i] - lm);
#pragma unroll
        for (int o = 1; o < NL; o <<= 1) ex += __shfl_xor(ex, o);
        const float lse = lm + __logf(ex);
#pragma unroll
        for (int i = 0; i < 8; ++i) val[i] -= lse;
    }
    if (q == 0) {
        float4 v0 = make_float4(val[0], val[1], val[2], val[3]);
        float4 v1 = make_float4(val[4], val[5], val[6], val[7]);
        *(float4*)&out[(size_t)node * F + 8 * cl] = v0;
        *(float4*)&out[(size_t)node * F + 8 * cl + 4] = v1;
    }
}

// ---------------- launch ----------------

extern "C" void kernel_launch(void* const* d_in, const int* in_sizes, int n_in,
                              void* d_out, int out_size, void* d_ws, size_t ws_size,
                              hipStream_t stream) {
    const float* x  = (const float*)d_in[0];
    const int*   ei = (const int*)d_in[1];
    const float* W1 = (const float*)d_in[2];
    const float* a1s = (const float*)d_in[3];
    const float* a1d = (const float*)d_in[4];
    const float* b1  = (const float*)d_in[5];
    const float* W2 = (const float*)d_in[6];
    const float* a2s = (const float*)d_in[7];
    const float* a2d = (const float*)d_in[8];
    const float* b2  = (const float*)d_in[9];
    const float* W3 = (const float*)d_in[10];
    const float* a3s = (const float*)d_in[11];
    const float* a3d = (const float*)d_in[12];
    const float* b3  = (const float*)d_in[13];

    const int N = in_sizes[0] / 128;
    const int E = in_sizes[1] / 2;
    const int NBK = (N + 127) / 128;
    const int B = BIN_BLOCKS;

    char* wp = (char*)d_ws;
    auto alloc = [&](size_t bytes) -> void* {
        void* p = wp;
        wp += (bytes + 255) & ~(size_t)255;
        return p;
    };
    int* cnt     = (int*)alloc((size_t)N * 4);
    int* row_ptr = (int*)alloc((size_t)(N + 1) * 4);
    int* col     = (int*)alloc((size_t)(E + N) * 4);
    unsigned short* hb = (unsigned short*)alloc((size_t)N * 64 * 2);
    float* ss  = (float*)alloc((size_t)N * 4);
    float* sd  = (float*)alloc((size_t)N * 4);
    float* o1  = (float*)alloc((size_t)N * 64 * 4);
    float* o2  = (float*)alloc((size_t)N * 64 * 4);
    int* cntb  = (int*)alloc((size_t)NBK * B * 4);
    int* obb   = (int*)alloc(((size_t)NBK * B + 1) * 4);
    int* bsum  = (int*)alloc(1024 * 4);
    int* eb = (int*)o2;                               // alias: dead ranges don't overlap

    const int chunk = (E + B - 1) / B;
    const int nb2 = (NBK * B + SCAN_TILE - 1) / SCAN_TILE;
    const int nbn = (N + SCAN_TILE - 1) / SCAN_TILE;

    bin_hist_k<<<B, 256, 0, stream>>>(ei + E, E, cntb, NBK, chunk);
    scan_pass1<<<nb2, 256, 0, stream>>>(cntb, bsum, NBK * B);
    scan_pass2<<<1, 256, 0, stream>>>(bsum, obb, nb2, NBK * B);
    scan_pass3<<<nb2, 256, 0, stream>>>(cntb, bsum, obb, NBK * B);
    bin_scatter_k<<<B, 256, 0, stream>>>(ei, E, obb, eb, NBK, chunk);
    bucket_cnt_k<<<NBK, 256, 0, stream>>>(eb, obb, cnt, B, N);
    scan_pass1<<<nbn, 256, 0, stream>>>(cnt, bsum, N);
    scan_pass2<<<1, 256, 0, stream>>>(bsum, row_ptr, nbn, N);
    scan_pass3<<<nbn, 256, 0, stream>>>(cnt, bsum, row_ptr, N);
    bucket_scatter_k<<<NBK, 256, 0, stream>>>(eb, obb, row_ptr, col, B, N);

    // --- layer 1: 128 -> 64, relu ---  (gemm: 128-row tile; agg: S=32)
    gemm_tile_k<128, 64, 8><<<(N + 127) / 128, 256, 0, stream>>>(x, W1, a1s, a1d, hb, ss, sd, N);
    gat_agg_k<64, 32, true, false><<<(N + 7) / 8, 256, 0, stream>>>(row_ptr, col, hb, ss, sd, b1, o1, N);

    // --- layer 2: 64 -> 64, relu ---
    gemm_tile_k<64, 64, 8><<<(N + 127) / 128, 256, 0, stream>>>(o1, W2, a2s, a2d, hb, ss, sd, N);
    gat_agg_k<64, 32, true, false><<<(N + 7) / 8, 256, 0, stream>>>(row_ptr, col, hb, ss, sd, b2, o2, N);

    // --- layer 3: 64 -> 32, log_softmax ---
    gemm_tile_k<64, 32, 4><<<(N + 127) / 128, 256, 0, stream>>>(o2, W3, a3s, a3d, hb, ss, sd, N);
    gat_agg_k<32, 16, false, true><<<(N + 15) / 16, 256, 0, stream>>>(row_ptr, col, hb, ss, sd, b3,
                                                                      (float*)d_out, N);
}

// Round 9
// 325.762 us; speedup vs baseline: 3.3672x; 1.0945x over previous
//
#include <hip/hip_runtime.h>
#include <hip/hip_fp16.h>
#include <cstddef>
#include <cstdint>

#define NEG_SLOPE 0.2f

__device__ __forceinline__ unsigned short f2bf(float f) {
    unsigned int u = __float_as_uint(f);
    u = (u + 0x7fff + ((u >> 16) & 1)) >> 16;   // round-to-nearest-even
    return (unsigned short)u;
}
__device__ __forceinline__ float bf_lo(unsigned int u) { return __uint_as_float(u << 16); }
__device__ __forceinline__ float bf_hi(unsigned int u) { return __uint_as_float(u & 0xffff0000u); }

typedef __attribute__((ext_vector_type(8))) short bf16x8;   // MFMA A/B frag (4 VGPRs)
typedef __attribute__((ext_vector_type(4))) float f32x4;    // MFMA C/D frag

// ---------------- hierarchical exclusive scan: in[n] -> out[n+1] ----------------

constexpr int SCAN_TILE = 1024;   // 256 threads x 4 elems

__global__ __launch_bounds__(256) void scan_pass1(const int* __restrict__ in,
                                                  int* __restrict__ bsum, int n) {
    const int tid = threadIdx.x;
    const int base = blockIdx.x * SCAN_TILE + tid * 4;
    int s = 0;
#pragma unroll
    for (int k = 0; k < 4; ++k) {
        int i = base + k;
        if (i < n) s += in[i];
    }
    for (int o = 1; o < 64; o <<= 1) s += __shfl_xor(s, o);
    __shared__ int wsum[4];
    if ((tid & 63) == 0) wsum[tid >> 6] = s;
    __syncthreads();
    if (tid == 0) bsum[blockIdx.x] = wsum[0] + wsum[1] + wsum[2] + wsum[3];
}

__global__ __launch_bounds__(256) void scan_pass2(int* __restrict__ bsum,
                                                  int* __restrict__ out,
                                                  int nb, int n) {
    __shared__ int sh[1024];
    const int tid = threadIdx.x;
    for (int i = tid; i < nb; i += 256) sh[i] = bsum[i];
    __syncthreads();
    if (tid == 0) {
        int run = 0;
        for (int i = 0; i < nb; ++i) { int c = sh[i]; sh[i] = run; run += c; }
        out[n] = run;                    // grand total
    }
    __syncthreads();
    for (int i = tid; i < nb; i += 256) bsum[i] = sh[i];
}

__global__ __launch_bounds__(256) void scan_pass3(const int* __restrict__ in,
                                                  const int* __restrict__ bsum,
                                                  int* __restrict__ out, int n) {
    const int tid = threadIdx.x;
    const int lane = tid & 63;
    const int wid = tid >> 6;
    const int base = blockIdx.x * SCAN_TILE + tid * 4;
    int v[4];
    int tsum = 0;
#pragma unroll
    for (int k = 0; k < 4; ++k) {
        int i = base + k;
        v[k] = (i < n) ? in[i] : 0;
        tsum += v[k];
    }
    int inc = tsum;
    for (int o = 1; o < 64; o <<= 1) {
        int t = __shfl_up(inc, o);
        if (lane >= o) inc += t;
    }
    __shared__ int wtot[4];
    if (lane == 63) wtot[wid] = inc;
    __syncthreads();
    int woff = 0;
    for (int w = 0; w < wid; ++w) woff += wtot[w];
    int off = bsum[blockIdx.x] + woff + (inc - tsum);
#pragma unroll
    for (int k = 0; k < 4; ++k) {
        int i = base + k;
        if (i < n) { out[i] = off; off += v[k]; }
    }
}

// ---------------- binned CSR build ----------------
// Bucket = dst >> 7 (128 nodes/bucket). Edges packed (src<<7)|dstLow (src<2^17).

constexpr int BIN_BLOCKS = 256;
constexpr int MAX_NBK = 1024;            // supports N <= 131072 (= packing limit)

__global__ __launch_bounds__(256) void bin_hist_k(const int* __restrict__ dst, int E,
                                                  int* __restrict__ cntb, int nbk,
                                                  int chunk) {
    __shared__ int hist[MAX_NBK];
    for (int i = threadIdx.x; i < nbk; i += 256) hist[i] = 0;
    __syncthreads();
    const int lo = blockIdx.x * chunk;
    const int hi = min(lo + chunk, E);
    for (int e = lo + threadIdx.x; e < hi; e += 256)
        atomicAdd(&hist[dst[e] >> 7], 1);
    __syncthreads();
    for (int i = threadIdx.x; i < nbk; i += 256)
        cntb[i * gridDim.x + blockIdx.x] = hist[i];   // bucket-major
}

// per-block obb slice cached in LDS -> per-edge path is LDS-only
__global__ __launch_bounds__(256) void bin_scatter_k(const int* __restrict__ ei, int E,
                                                     const int* __restrict__ obb,
                                                     int* __restrict__ eb, int nbk,
                                                     int chunk) {
    __shared__ int cur[MAX_NBK];
    __shared__ int off_s[MAX_NBK];
    const int B = gridDim.x;
    for (int i = threadIdx.x; i < nbk; i += 256) {
        cur[i] = 0;
        off_s[i] = obb[i * B + blockIdx.x];
    }
    __syncthreads();
    const int lo = blockIdx.x * chunk;
    const int hi = min(lo + chunk, E);
    for (int e = lo + threadIdx.x; e < hi; e += 256) {
        int s = ei[e];
        int d = ei[E + e];
        int b = d >> 7;
        int idx = atomicAdd(&cur[b], 1);
        eb[off_s[b] + idx] = (s << 7) | (d & 127);
    }
}

__global__ __launch_bounds__(256) void bucket_cnt_k(const int* __restrict__ eb,
                                                    const int* __restrict__ obb,
                                                    int* __restrict__ cnt,
                                                    int B, int n) {
    __shared__ int c[128];
    const int b = blockIdx.x;
    const int t = threadIdx.x;
    const int beg = obb[b * B];
    const int end = obb[(b + 1) * B];    // last bucket: obb[nbk*B] = total
    if (t < 128) c[t] = 1;               // self-loop
    __syncthreads();
    for (int i = beg + t; i < end; i += 256)
        atomicAdd(&c[eb[i] & 127], 1);
    __syncthreads();
    const int node = b * 128 + t;
    if (t < 128 && node < n) cnt[node] = c[t];
}

__global__ __launch_bounds__(256) void bucket_scatter_k(const int* __restrict__ eb,
                                                        const int* __restrict__ obb,
                                                        const int* __restrict__ row_ptr,
                                                        int* __restrict__ col,
                                                        int B, int n) {
    __shared__ int c[128];
    __shared__ int rp[128];
    const int b = blockIdx.x;
    const int t = threadIdx.x;
    const int beg = obb[b * B];
    const int end = obb[(b + 1) * B];
    const int node = b * 128 + t;
    if (t < 128) {
        c[t] = 1;
        if (node < n) {
            rp[t] = row_ptr[node];
            col[rp[t]] = node;           // self-loop in slot 0
        }
    }
    __syncthreads();
    for (int i = beg + t; i < end; i += 256) {
        int p = eb[i];
        int dl = p & 127;
        int idx = atomicAdd(&c[dl], 1);
        col[rp[dl] + idx] = p >> 7;
    }
}

// ---------------- dense: MFMA bf16 GEMM -> bf16 h + fused attention dots -------
// 64-row tile per 256-thread block (4 waves x 16 rows). Stage x (fp32->bf16)
// and W^T (fp32->bf16) into LDS once, single barrier, K-resident MFMA loop.
// mfma_f32_16x16x32_bf16: A[m=lane&15][k=(lane>>4)*8+j]; C/D: col=lane&15,
// row=(lane>>4)*4+reg (m89/m91-verified mapping). +8 bf16 pad -> 2-way bank
// alias (free, m136).

template <int K, int F>
__launch_bounds__(256)
__global__ void gemm_mfma_k(const float* __restrict__ x, const float* __restrict__ W,
                            const float* __restrict__ a_s, const float* __restrict__ a_d,
                            unsigned short* __restrict__ hb, float* __restrict__ ss,
                            float* __restrict__ sd, int n) {
    constexpr int MT = 64;               // rows per block
    constexpr int KP = K + 8;            // padded inner stride (bf16 elems)
    constexpr int NT = F / 16;           // n-tiles per wave
    constexpr int KC = K / 32;           // k-steps

    __shared__ unsigned short xb[MT * KP];
    __shared__ unsigned short wb[F * KP];

    const int tid = threadIdx.x;
    const int lane = tid & 63;
    const int wv = tid >> 6;             // wave id 0..3
    const int base = blockIdx.x * MT;

    // stage x rows -> bf16
    for (int i = tid; i < MT * K / 4; i += 256) {
        int row = i / (K / 4);
        int c4 = i % (K / 4);
        float4 v = make_float4(0.f, 0.f, 0.f, 0.f);
        if (base + row < n)
            v = *(const float4*)&x[(size_t)(base + row) * K + 4 * c4];
        ushort4 b;
        b.x = f2bf(v.x); b.y = f2bf(v.y); b.z = f2bf(v.z); b.w = f2bf(v.w);
        *(ushort4*)&xb[row * KP + 4 * c4] = b;
    }
    // stage W^T -> wb[ncol][k] bf16
    for (int i = tid; i < K * F / 4; i += 256) {
        int k = i / (F / 4);
        int n4 = i % (F / 4);
        float4 v = *(const float4*)&W[(size_t)k * F + 4 * n4];
        wb[(4 * n4 + 0) * KP + k] = f2bf(v.x);
        wb[(4 * n4 + 1) * KP + k] = f2bf(v.y);
        wb[(4 * n4 + 2) * KP + k] = f2bf(v.z);
        wb[(4 * n4 + 3) * KP + k] = f2bf(v.w);
    }
    __syncthreads();

    const int mrow = lane & 15;          // A row / D col within tile
    const int quad = lane >> 4;          // 0..3

    f32x4 acc[NT];
#pragma unroll
    for (int t = 0; t < NT; ++t) acc[t] = (f32x4){0.f, 0.f, 0.f, 0.f};

#pragma unroll
    for (int kc = 0; kc < KC; ++kc) {
        const int kof = kc * 32 + quad * 8;
        bf16x8 af = *(const bf16x8*)&xb[(wv * 16 + mrow) * KP + kof];
#pragma unroll
        for (int t = 0; t < NT; ++t) {
            bf16x8 bf = *(const bf16x8*)&wb[(t * 16 + mrow) * KP + kof];
            acc[t] = __builtin_amdgcn_mfma_f32_16x16x32_bf16(af, bf, acc[t], 0, 0, 0);
        }
    }

    // epilogue: h (bf16) + fused ss/sd dots from fp32 accumulators
    float as_c[NT], ad_c[NT];
#pragma unroll
    for (int t = 0; t < NT; ++t) { as_c[t] = a_s[t * 16 + mrow]; ad_c[t] = a_d[t * 16 + mrow]; }

#pragma unroll
    for (int r = 0; r < 4; ++r) {
        const int node = base + wv * 16 + quad * 4 + r;
        float ps = 0.f, pd = 0.f;
#pragma unroll
        for (int t = 0; t < NT; ++t) {
            ps = fmaf(acc[t][r], as_c[t], ps);
            pd = fmaf(acc[t][r], ad_c[t], pd);
        }
#pragma unroll
        for (int o = 1; o < 16; o <<= 1) {       // stays within the quad's 16 lanes
            ps += __shfl_xor(ps, o);
            pd += __shfl_xor(pd, o);
        }
        if (node < n) {
#pragma unroll
            for (int t = 0; t < NT; ++t)
                hb[(size_t)node * F + t * 16 + mrow] = f2bf(acc[t][r]);
            if (mrow == 0) { ss[node] = ps; sd[node] = pd; }
        }
    }
}

// ---------------- sparse: online-softmax aggregation, bf16 payload -------------

template <int F, int S, bool RELU, bool LOGSM>
__launch_bounds__(256)
__global__ void gat_agg_k(const int* __restrict__ row_ptr, const int* __restrict__ col,
                          const unsigned short* __restrict__ hb,
                          const float* __restrict__ ss, const float* __restrict__ sd,
                          const float* __restrict__ bias,
                          float* __restrict__ out, int n) {
    constexpr int NPW = 64 / S;          // nodes per wave
    constexpr int NL = F / 8;            // lanes per row (8 bf16 channels each)
    constexpr int Q = S / NL;            // edge slots
    const int lane = threadIdx.x & 63;
    const int ls   = lane % S;           // lane in subgroup
    const int q    = ls / NL;            // edge slot
    const int cl   = ls % NL;            // channel octet index
    const int lbase = lane - ls;         // first lane of subgroup
    const int wave = (blockIdx.x * blockDim.x + threadIdx.x) >> 6;
    const int node = wave * NPW + lane / S;
    if (node >= n) return;

    const int beg = row_ptr[node];
    const int end = row_ptr[node + 1];
    const float sdv = sd[node];

    float m = -__builtin_inff();
    float s = 0.f;
    float acc[8];
#pragma unroll
    for (int i = 0; i < 8; ++i) acc[i] = 0.f;

    for (int base = beg; base < end; base += S) {
        const int j = base + ls;
        int   c = 0;
        float logit = -__builtin_inff();
        if (j < end) {
            c = col[j];
            float z = ss[c] + sdv;
            logit = (z > 0.f) ? z : NEG_SLOPE * z;
        }
        float cm = logit;
#pragma unroll
        for (int o = S / 2; o; o >>= 1) cm = fmaxf(cm, __shfl_xor(cm, o));
        const float newm = fmaxf(m, cm);
        const float scale = __expf(m - newm);     // first iter: exp(-inf)=0
        s *= scale;
#pragma unroll
        for (int i = 0; i < 8; ++i) acc[i] *= scale;
        const float w = __expf(logit - newm);     // inactive lanes -> 0
        float wsum = w;
#pragma unroll
        for (int o = S / 2; o; o >>= 1) wsum += __shfl_xor(wsum, o);
        s += wsum;
        m = newm;

        // pack: fp16(w) in bits [31:17] (w>=0 so sign bit is 0), c in [16:0]
        const unsigned int pk =
            ((unsigned int)__half_as_ushort(__float2half(w)) << 17) | (unsigned int)c;

        const int cnt = min(S, end - base);
        for (int t = 0; Q * t < cnt; ++t) {
            const int e = Q * t + q;                 // e < S (Q divides S)
            const unsigned int pe = __shfl(pk, lbase + e);
            const int   ct = (int)(pe & 0x1ffffu);
            const float wt = __half2float(__ushort_as_half((unsigned short)(pe >> 17)));
            const uint4 hv = *(const uint4*)&hb[(size_t)ct * F + 8 * cl];
            acc[0] = fmaf(wt, bf_lo(hv.x), acc[0]);
            acc[1] = fmaf(wt, bf_hi(hv.x), acc[1]);
            acc[2] = fmaf(wt, bf_lo(hv.y), acc[2]);
            acc[3] = fmaf(wt, bf_hi(hv.y), acc[3]);
            acc[4] = fmaf(wt, bf_lo(hv.z), acc[4]);
            acc[5] = fmaf(wt, bf_hi(hv.z), acc[5]);
            acc[6] = fmaf(wt, bf_lo(hv.w), acc[6]);
            acc[7] = fmaf(wt, bf_hi(hv.w), acc[7]);
        }
    }

    // butterfly-reduce partial sums across the Q edge slots
#pragma unroll
    for (int o = NL; o < S; o <<= 1) {
#pragma unroll
        for (int i = 0; i < 8; ++i) acc[i] += __shfl_xor(acc[i], o);
    }

    const float inv = 1.f / (s + 1e-16f);
    float val[8];
#pragma unroll
    for (int i = 0; i < 8; ++i) {
        val[i] = acc[i] * inv + bias[8 * cl + i];
        if (RELU) val[i] = fmaxf(val[i], 0.f);
    }
    if (LOGSM) {
        float lm = val[0];
#pragma unroll
        for (int i = 1; i < 8; ++i) lm = fmaxf(lm, val[i]);
#pragma unroll
        for (int o = 1; o < NL; o <<= 1) lm = fmaxf(lm, __shfl_xor(lm, o));
        float ex = 0.f;
#pragma unroll
        for (int i = 0; i < 8; ++i) ex += __expf(val[i] - lm);
#pragma unroll
        for (int o = 1; o < NL; o <<= 1) ex += __shfl_xor(ex, o);
        const float lse = lm + __logf(ex);
#pragma unroll
        for (int i = 0; i < 8; ++i) val[i] -= lse;
    }
    if (q == 0) {
        float4 v0 = make_float4(val[0], val[1], val[2], val[3]);
        float4 v1 = make_float4(val[4], val[5], val[6], val[7]);
        *(float4*)&out[(size_t)node * F + 8 * cl] = v0;
        *(float4*)&out[(size_t)node * F + 8 * cl + 4] = v1;
    }
}

// ---------------- launch ----------------

extern "C" void kernel_launch(void* const* d_in, const int* in_sizes, int n_in,
                              void* d_out, int out_size, void* d_ws, size_t ws_size,
                              hipStream_t stream) {
    const float* x  = (const float*)d_in[0];
    const int*   ei = (const int*)d_in[1];
    const float* W1 = (const float*)d_in[2];
    const float* a1s = (const float*)d_in[3];
    const float* a1d = (const float*)d_in[4];
    const float* b1  = (const float*)d_in[5];
    const float* W2 = (const float*)d_in[6];
    const float* a2s = (const float*)d_in[7];
    const float* a2d = (const float*)d_in[8];
    const float* b2  = (const float*)d_in[9];
    const float* W3 = (const float*)d_in[10];
    const float* a3s = (const float*)d_in[11];
    const float* a3d = (const float*)d_in[12];
    const float* b3  = (const float*)d_in[13];

    const int N = in_sizes[0] / 128;
    const int E = in_sizes[1] / 2;
    const int NBK = (N + 127) / 128;
    const int B = BIN_BLOCKS;

    char* wp = (char*)d_ws;
    auto alloc = [&](size_t bytes) -> void* {
        void* p = wp;
        wp += (bytes + 255) & ~(size_t)255;
        return p;
    };
    int* cnt     = (int*)alloc((size_t)N * 4);
    int* row_ptr = (int*)alloc((size_t)(N + 1) * 4);
    int* col     = (int*)alloc((size_t)(E + N) * 4);
    unsigned short* hb = (unsigned short*)alloc((size_t)N * 64 * 2);
    float* ss  = (float*)alloc((size_t)N * 4);
    float* sd  = (float*)alloc((size_t)N * 4);
    float* o1  = (float*)alloc((size_t)N * 64 * 4);
    float* o2  = (float*)alloc((size_t)N * 64 * 4);
    int* cntb  = (int*)alloc((size_t)NBK * B * 4);
    int* obb   = (int*)alloc(((size_t)NBK * B + 1) * 4);
    int* bsum  = (int*)alloc(1024 * 4);
    int* eb = (int*)o2;                               // alias: dead ranges don't overlap

    const int chunk = (E + B - 1) / B;
    const int nb2 = (NBK * B + SCAN_TILE - 1) / SCAN_TILE;
    const int nbn = (N + SCAN_TILE - 1) / SCAN_TILE;

    bin_hist_k<<<B, 256, 0, stream>>>(ei + E, E, cntb, NBK, chunk);
    scan_pass1<<<nb2, 256, 0, stream>>>(cntb, bsum, NBK * B);
    scan_pass2<<<1, 256, 0, stream>>>(bsum, obb, nb2, NBK * B);
    scan_pass3<<<nb2, 256, 0, stream>>>(cntb, bsum, obb, NBK * B);
    bin_scatter_k<<<B, 256, 0, stream>>>(ei, E, obb, eb, NBK, chunk);
    bucket_cnt_k<<<NBK, 256, 0, stream>>>(eb, obb, cnt, B, N);
    scan_pass1<<<nbn, 256, 0, stream>>>(cnt, bsum, N);
    scan_pass2<<<1, 256, 0, stream>>>(bsum, row_ptr, nbn, N);
    scan_pass3<<<nbn, 256, 0, stream>>>(cnt, bsum, row_ptr, N);
    bucket_scatter_k<<<NBK, 256, 0, stream>>>(eb, obb, row_ptr, col, B, N);

    const int GB = (N + 63) / 64;

    // --- layer 1: 128 -> 64, relu ---
    gemm_mfma_k<128, 64><<<GB, 256, 0, stream>>>(x, W1, a1s, a1d, hb, ss, sd, N);
    gat_agg_k<64, 32, true, false><<<(N + 7) / 8, 256, 0, stream>>>(row_ptr, col, hb, ss, sd, b1, o1, N);

    // --- layer 2: 64 -> 64, relu ---
    gemm_mfma_k<64, 64><<<GB, 256, 0, stream>>>(o1, W2, a2s, a2d, hb, ss, sd, N);
    gat_agg_k<64, 32, true, false><<<(N + 7) / 8, 256, 0, stream>>>(row_ptr, col, hb, ss, sd, b2, o2, N);

    // --- layer 3: 64 -> 32, log_softmax ---
    gemm_mfma_k<64, 32><<<GB, 256, 0, stream>>>(o2, W3, a3s, a3d, hb, ss, sd, N);
    gat_agg_k<32, 16, false, true><<<(N + 15) / 16, 256, 0, stream>>>(row_ptr, col, hb, ss, sd, b3,
                                                                      (float*)d_out, N);
}

// Round 10
// 307.844 us; speedup vs baseline: 3.5632x; 1.0582x over previous
//
#include <hip/hip_runtime.h>
#include <hip/hip_fp16.h>
#include <cstddef>
#include <cstdint>

#define NEG_SLOPE 0.2f

__device__ __forceinline__ unsigned short f2bf(float f) {
    unsigned int u = __float_as_uint(f);
    u = (u + 0x7fff + ((u >> 16) & 1)) >> 16;   // round-to-nearest-even
    return (unsigned short)u;
}
__device__ __forceinline__ float bf_lo(unsigned int u) { return __uint_as_float(u << 16); }
__device__ __forceinline__ float bf_hi(unsigned int u) { return __uint_as_float(u & 0xffff0000u); }

typedef __attribute__((ext_vector_type(8))) short bf16x8;   // MFMA A/B frag (4 VGPRs)
typedef __attribute__((ext_vector_type(4))) float f32x4;    // MFMA C/D frag

// ---------------- hierarchical exclusive scan: in[n] -> out[n+1] ----------------

constexpr int SCAN_TILE = 1024;   // 256 threads x 4 elems

__global__ __launch_bounds__(256) void scan_pass1(const int* __restrict__ in,
                                                  int* __restrict__ bsum, int n) {
    const int tid = threadIdx.x;
    const int base = blockIdx.x * SCAN_TILE + tid * 4;
    int s = 0;
#pragma unroll
    for (int k = 0; k < 4; ++k) {
        int i = base + k;
        if (i < n) s += in[i];
    }
    for (int o = 1; o < 64; o <<= 1) s += __shfl_xor(s, o);
    __shared__ int wsum[4];
    if ((tid & 63) == 0) wsum[tid >> 6] = s;
    __syncthreads();
    if (tid == 0) bsum[blockIdx.x] = wsum[0] + wsum[1] + wsum[2] + wsum[3];
}

__global__ __launch_bounds__(256) void scan_pass2(int* __restrict__ bsum,
                                                  int* __restrict__ out,
                                                  int nb, int n) {
    __shared__ int sh[1024];
    const int tid = threadIdx.x;
    for (int i = tid; i < nb; i += 256) sh[i] = bsum[i];
    __syncthreads();
    if (tid == 0) {
        int run = 0;
        for (int i = 0; i < nb; ++i) { int c = sh[i]; sh[i] = run; run += c; }
        out[n] = run;                    // grand total
    }
    __syncthreads();
    for (int i = tid; i < nb; i += 256) bsum[i] = sh[i];
}

__global__ __launch_bounds__(256) void scan_pass3(const int* __restrict__ in,
                                                  const int* __restrict__ bsum,
                                                  int* __restrict__ out, int n) {
    const int tid = threadIdx.x;
    const int lane = tid & 63;
    const int wid = tid >> 6;
    const int base = blockIdx.x * SCAN_TILE + tid * 4;
    int v[4];
    int tsum = 0;
#pragma unroll
    for (int k = 0; k < 4; ++k) {
        int i = base + k;
        v[k] = (i < n) ? in[i] : 0;
        tsum += v[k];
    }
    int inc = tsum;
    for (int o = 1; o < 64; o <<= 1) {
        int t = __shfl_up(inc, o);
        if (lane >= o) inc += t;
    }
    __shared__ int wtot[4];
    if (lane == 63) wtot[wid] = inc;
    __syncthreads();
    int woff = 0;
    for (int w = 0; w < wid; ++w) woff += wtot[w];
    int off = bsum[blockIdx.x] + woff + (inc - tsum);
#pragma unroll
    for (int k = 0; k < 4; ++k) {
        int i = base + k;
        if (i < n) { out[i] = off; off += v[k]; }
    }
}

// ---------------- binned CSR build ----------------
// Bucket = dst >> 7 (128 nodes/bucket). Edges packed (src<<7)|dstLow (src<2^17).

constexpr int BIN_BLOCKS = 256;
constexpr int MAX_NBK = 1024;            // supports N <= 131072 (= packing limit)

__global__ __launch_bounds__(256) void bin_hist_k(const int* __restrict__ dst, int E,
                                                  int* __restrict__ cntb, int nbk,
                                                  int chunk) {
    __shared__ int hist[MAX_NBK];
    for (int i = threadIdx.x; i < nbk; i += 256) hist[i] = 0;
    __syncthreads();
    const int lo = blockIdx.x * chunk;
    const int hi = min(lo + chunk, E);
    for (int e = lo + threadIdx.x; e < hi; e += 256)
        atomicAdd(&hist[dst[e] >> 7], 1);
    __syncthreads();
    for (int i = threadIdx.x; i < nbk; i += 256)
        cntb[i * gridDim.x + blockIdx.x] = hist[i];   // bucket-major
}

// per-block obb slice cached in LDS -> per-edge path is LDS-only
__global__ __launch_bounds__(256) void bin_scatter_k(const int* __restrict__ ei, int E,
                                                     const int* __restrict__ obb,
                                                     int* __restrict__ eb, int nbk,
                                                     int chunk) {
    __shared__ int cur[MAX_NBK];
    __shared__ int off_s[MAX_NBK];
    const int B = gridDim.x;
    for (int i = threadIdx.x; i < nbk; i += 256) {
        cur[i] = 0;
        off_s[i] = obb[i * B + blockIdx.x];
    }
    __syncthreads();
    const int lo = blockIdx.x * chunk;
    const int hi = min(lo + chunk, E);
    for (int e = lo + threadIdx.x; e < hi; e += 256) {
        int s = ei[e];
        int d = ei[E + e];
        int b = d >> 7;
        int idx = atomicAdd(&cur[b], 1);
        eb[off_s[b] + idx] = (s << 7) | (d & 127);
    }
}

// fused per-bucket build: degrees -> LDS scan -> row_ptr + self-loops + scatter.
// Bucket b's region base = obb[b*B] + b*128 (all preceding buckets are full).
__global__ __launch_bounds__(256) void bucket_build_k(const int* __restrict__ eb,
                                                      const int* __restrict__ obb,
                                                      int* __restrict__ row_ptr,
                                                      int* __restrict__ col,
                                                      int B, int n, int nbk) {
    __shared__ int c[128];
    __shared__ int rp[128];
    const int b = blockIdx.x;
    const int t = threadIdx.x;
    const int beg = obb[b * B];
    const int end = obb[(b + 1) * B];    // obb[nbk*B] = total edges
    const int bbase = beg + b * 128;
    if (t < 128) c[t] = 1;               // self-loop pre-count
    __syncthreads();
    for (int i = beg + t; i < end; i += 256)
        atomicAdd(&c[eb[i] & 127], 1);
    __syncthreads();
    // exclusive scan of 128 degree counts (wave 0, 2 elems/lane)
    if (t < 64) {
        int v0 = c[2 * t], v1 = c[2 * t + 1];
        int pair = v0 + v1;
        int inc = pair;
        for (int o = 1; o < 64; o <<= 1) {
            int u = __shfl_up(inc, o);
            if (t >= o) inc += u;
        }
        int ex = inc - pair;
        rp[2 * t] = bbase + ex;
        rp[2 * t + 1] = bbase + ex + v0;
    }
    __syncthreads();
    const int node = b * 128 + t;
    if (t < 128 && node < n) {
        row_ptr[node] = rp[t];
        col[rp[t]] = node;               // self-loop in slot 0
    }
    if (b == 0 && t == 0) row_ptr[n] = obb[nbk * B] + n;
    // reset cur counters (slot 0 = self-loop) and scatter
    __syncthreads();
    if (t < 128) c[t] = 1;
    __syncthreads();
    for (int i = beg + t; i < end; i += 256) {
        int p = eb[i];
        int dl = p & 127;
        int idx = atomicAdd(&c[dl], 1);
        col[rp[dl] + idx] = p >> 7;
    }
}

// ---------------- dense: MFMA bf16 GEMM -> bf16 h + fused attention dots -------

template <int K, int F>
__launch_bounds__(256)
__global__ void gemm_mfma_k(const float* __restrict__ x, const float* __restrict__ W,
                            const float* __restrict__ a_s, const float* __restrict__ a_d,
                            unsigned short* __restrict__ hb, float* __restrict__ ss,
                            float* __restrict__ sd, int n) {
    constexpr int MT = 64;               // rows per block
    constexpr int KP = K + 8;            // padded inner stride (bf16 elems)
    constexpr int NT = F / 16;           // n-tiles per wave
    constexpr int KC = K / 32;           // k-steps

    __shared__ unsigned short xb[MT * KP];
    __shared__ unsigned short wb[F * KP];

    const int tid = threadIdx.x;
    const int lane = tid & 63;
    const int wv = tid >> 6;             // wave id 0..3
    const int base = blockIdx.x * MT;

    for (int i = tid; i < MT * K / 4; i += 256) {
        int row = i / (K / 4);
        int c4 = i % (K / 4);
        float4 v = make_float4(0.f, 0.f, 0.f, 0.f);
        if (base + row < n)
            v = *(const float4*)&x[(size_t)(base + row) * K + 4 * c4];
        ushort4 b;
        b.x = f2bf(v.x); b.y = f2bf(v.y); b.z = f2bf(v.z); b.w = f2bf(v.w);
        *(ushort4*)&xb[row * KP + 4 * c4] = b;
    }
    for (int i = tid; i < K * F / 4; i += 256) {
        int k = i / (F / 4);
        int n4 = i % (F / 4);
        float4 v = *(const float4*)&W[(size_t)k * F + 4 * n4];
        wb[(4 * n4 + 0) * KP + k] = f2bf(v.x);
        wb[(4 * n4 + 1) * KP + k] = f2bf(v.y);
        wb[(4 * n4 + 2) * KP + k] = f2bf(v.z);
        wb[(4 * n4 + 3) * KP + k] = f2bf(v.w);
    }
    __syncthreads();

    const int mrow = lane & 15;
    const int quad = lane >> 4;

    f32x4 acc[NT];
#pragma unroll
    for (int t = 0; t < NT; ++t) acc[t] = (f32x4){0.f, 0.f, 0.f, 0.f};

#pragma unroll
    for (int kc = 0; kc < KC; ++kc) {
        const int kof = kc * 32 + quad * 8;
        bf16x8 af = *(const bf16x8*)&xb[(wv * 16 + mrow) * KP + kof];
#pragma unroll
        for (int t = 0; t < NT; ++t) {
            bf16x8 bf = *(const bf16x8*)&wb[(t * 16 + mrow) * KP + kof];
            acc[t] = __builtin_amdgcn_mfma_f32_16x16x32_bf16(af, bf, acc[t], 0, 0, 0);
        }
    }

    float as_c[NT], ad_c[NT];
#pragma unroll
    for (int t = 0; t < NT; ++t) { as_c[t] = a_s[t * 16 + mrow]; ad_c[t] = a_d[t * 16 + mrow]; }

#pragma unroll
    for (int r = 0; r < 4; ++r) {
        const int node = base + wv * 16 + quad * 4 + r;
        float ps = 0.f, pd = 0.f;
#pragma unroll
        for (int t = 0; t < NT; ++t) {
            ps = fmaf(acc[t][r], as_c[t], ps);
            pd = fmaf(acc[t][r], ad_c[t], pd);
        }
#pragma unroll
        for (int o = 1; o < 16; o <<= 1) {
            ps += __shfl_xor(ps, o);
            pd += __shfl_xor(pd, o);
        }
        if (node < n) {
#pragma unroll
            for (int t = 0; t < NT; ++t)
                hb[(size_t)node * F + t * 16 + mrow] = f2bf(acc[t][r]);
            if (mrow == 0) { ss[node] = ps; sd[node] = pd; }
        }
    }
}

// ---------------- sparse: online-softmax aggregation, bf16 payload -------------
// Gather loop unrolled x2: two independent uint4 loads in flight per lane.

template <int F, int S, bool RELU, bool LOGSM>
__launch_bounds__(256)
__global__ void gat_agg_k(const int* __restrict__ row_ptr, const int* __restrict__ col,
                          const unsigned short* __restrict__ hb,
                          const float* __restrict__ ss, const float* __restrict__ sd,
                          const float* __restrict__ bias,
                          float* __restrict__ out, int n) {
    constexpr int NPW = 64 / S;          // nodes per wave
    constexpr int NL = F / 8;            // lanes per row (8 bf16 channels each)
    constexpr int Q = S / NL;            // edge slots
    const int lane = threadIdx.x & 63;
    const int ls   = lane % S;           // lane in subgroup
    const int q    = ls / NL;            // edge slot
    const int cl   = ls % NL;            // channel octet index
    const int lbase = lane - ls;         // first lane of subgroup
    const int wave = (blockIdx.x * blockDim.x + threadIdx.x) >> 6;
    const int node = wave * NPW + lane / S;
    if (node >= n) return;

    const int beg = row_ptr[node];
    const int end = row_ptr[node + 1];
    const float sdv = sd[node];

    float m = -__builtin_inff();
    float s = 0.f;
    float acc[8];
#pragma unroll
    for (int i = 0; i < 8; ++i) acc[i] = 0.f;

    for (int base = beg; base < end; base += S) {
        const int j = base + ls;
        int   c = 0;
        float logit = -__builtin_inff();
        if (j < end) {
            c = col[j];
            float z = ss[c] + sdv;
            logit = (z > 0.f) ? z : NEG_SLOPE * z;
        }
        float cm = logit;
#pragma unroll
        for (int o = S / 2; o; o >>= 1) cm = fmaxf(cm, __shfl_xor(cm, o));
        const float newm = fmaxf(m, cm);
        const float scale = __expf(m - newm);     // first iter: exp(-inf)=0
        s *= scale;
#pragma unroll
        for (int i = 0; i < 8; ++i) acc[i] *= scale;
        const float w = __expf(logit - newm);     // inactive lanes -> 0
        float wsum = w;
#pragma unroll
        for (int o = S / 2; o; o >>= 1) wsum += __shfl_xor(wsum, o);
        s += wsum;
        m = newm;

        // pack: fp16(w) in bits [31:17] (w>=0 so sign bit is 0), c in [16:0]
        const unsigned int pk =
            ((unsigned int)__half_as_ushort(__float2half(w)) << 17) | (unsigned int)c;

        const int cnt = min(S, end - base);
        int t = 0;
        for (; Q * (t + 1) < cnt; t += 2) {        // 2 edges/lane in flight
            const unsigned int pe0 = __shfl(pk, lbase + Q * t + q);
            const unsigned int pe1 = __shfl(pk, lbase + Q * (t + 1) + q);
            const uint4 hv0 = *(const uint4*)&hb[(size_t)(pe0 & 0x1ffffu) * F + 8 * cl];
            const uint4 hv1 = *(const uint4*)&hb[(size_t)(pe1 & 0x1ffffu) * F + 8 * cl];
            const float wt0 = __half2float(__ushort_as_half((unsigned short)(pe0 >> 17)));
            const float wt1 = __half2float(__ushort_as_half((unsigned short)(pe1 >> 17)));
            acc[0] = fmaf(wt0, bf_lo(hv0.x), acc[0]);
            acc[1] = fmaf(wt0, bf_hi(hv0.x), acc[1]);
            acc[2] = fmaf(wt0, bf_lo(hv0.y), acc[2]);
            acc[3] = fmaf(wt0, bf_hi(hv0.y), acc[3]);
            acc[4] = fmaf(wt0, bf_lo(hv0.z), acc[4]);
            acc[5] = fmaf(wt0, bf_hi(hv0.z), acc[5]);
            acc[6] = fmaf(wt0, bf_lo(hv0.w), acc[6]);
            acc[7] = fmaf(wt0, bf_hi(hv0.w), acc[7]);
            acc[0] = fmaf(wt1, bf_lo(hv1.x), acc[0]);
            acc[1] = fmaf(wt1, bf_hi(hv1.x), acc[1]);
            acc[2] = fmaf(wt1, bf_lo(hv1.y), acc[2]);
            acc[3] = fmaf(wt1, bf_hi(hv1.y), acc[3]);
            acc[4] = fmaf(wt1, bf_lo(hv1.z), acc[4]);
            acc[5] = fmaf(wt1, bf_hi(hv1.z), acc[5]);
            acc[6] = fmaf(wt1, bf_lo(hv1.w), acc[6]);
            acc[7] = fmaf(wt1, bf_hi(hv1.w), acc[7]);
        }
        if (Q * t < cnt) {
            const unsigned int pe = __shfl(pk, lbase + Q * t + q);
            const uint4 hv = *(const uint4*)&hb[(size_t)(pe & 0x1ffffu) * F + 8 * cl];
            const float wt = __half2float(__ushort_as_half((unsigned short)(pe >> 17)));
            acc[0] = fmaf(wt, bf_lo(hv.x), acc[0]);
            acc[1] = fmaf(wt, bf_hi(hv.x), acc[1]);
            acc[2] = fmaf(wt, bf_lo(hv.y), acc[2]);
            acc[3] = fmaf(wt, bf_hi(hv.y), acc[3]);
            acc[4] = fmaf(wt, bf_lo(hv.z), acc[4]);
            acc[5] = fmaf(wt, bf_hi(hv.z), acc[5]);
            acc[6] = fmaf(wt, bf_lo(hv.w), acc[6]);
            acc[7] = fmaf(wt, bf_hi(hv.w), acc[7]);
        }
    }

    // butterfly-reduce partial sums across the Q edge slots
#pragma unroll
    for (int o = NL; o < S; o <<= 1) {
#pragma unroll
        for (int i = 0; i < 8; ++i) acc[i] += __shfl_xor(acc[i], o);
    }

    const float inv = 1.f / (s + 1e-16f);
    float val[8];
#pragma unroll
    for (int i = 0; i < 8; ++i) {
        val[i] = acc[i] * inv + bias[8 * cl + i];
        if (RELU) val[i] = fmaxf(val[i], 0.f);
    }
    if (LOGSM) {
        float lm = val[0];
#pragma unroll
        for (int i = 1; i < 8; ++i) lm = fmaxf(lm, val[i]);
#pragma unroll
        for (int o = 1; o < NL; o <<= 1) lm = fmaxf(lm, __shfl_xor(lm, o));
        float ex = 0.f;
#pragma unroll
        for (int i = 0; i < 8; ++i) ex += __expf(val[i] - lm);
#pragma unroll
        for (int o = 1; o < NL; o <<= 1) ex += __shfl_xor(ex, o);
        const float lse = lm + __logf(ex);
#pragma unroll
        for (int i = 0; i < 8; ++i) val[i] -= lse;
    }
    if (q == 0) {
        float4 v0 = make_float4(val[0], val[1], val[2], val[3]);
        float4 v1 = make_float4(val[4], val[5], val[6], val[7]);
        *(float4*)&out[(size_t)node * F + 8 * cl] = v0;
        *(float4*)&out[(size_t)node * F + 8 * cl + 4] = v1;
    }
}

// ---------------- launch ----------------

extern "C" void kernel_launch(void* const* d_in, const int* in_sizes, int n_in,
                              void* d_out, int out_size, void* d_ws, size_t ws_size,
                              hipStream_t stream) {
    const float* x  = (const float*)d_in[0];
    const int*   ei = (const int*)d_in[1];
    const float* W1 = (const float*)d_in[2];
    const float* a1s = (const float*)d_in[3];
    const float* a1d = (const float*)d_in[4];
    const float* b1  = (const float*)d_in[5];
    const float* W2 = (const float*)d_in[6];
    const float* a2s = (const float*)d_in[7];
    const float* a2d = (const float*)d_in[8];
    const float* b2  = (const float*)d_in[9];
    const float* W3 = (const float*)d_in[10];
    const float* a3s = (const float*)d_in[11];
    const float* a3d = (const float*)d_in[12];
    const float* b3  = (const float*)d_in[13];

    const int N = in_sizes[0] / 128;
    const int E = in_sizes[1] / 2;
    const int NBK = (N + 127) / 128;
    const int B = BIN_BLOCKS;

    char* wp = (char*)d_ws;
    auto alloc = [&](size_t bytes) -> void* {
        void* p = wp;
        wp += (bytes + 255) & ~(size_t)255;
        return p;
    };
    int* row_ptr = (int*)alloc((size_t)(N + 1) * 4);
    int* col     = (int*)alloc((size_t)(E + N) * 4);
    unsigned short* hb = (unsigned short*)alloc((size_t)N * 64 * 2);
    float* ss  = (float*)alloc((size_t)N * 4);
    float* sd  = (float*)alloc((size_t)N * 4);
    float* o1  = (float*)alloc((size_t)N * 64 * 4);
    float* o2  = (float*)alloc((size_t)N * 64 * 4);
    int* cntb  = (int*)alloc((size_t)NBK * B * 4);
    int* obb   = (int*)alloc(((size_t)NBK * B + 1) * 4);
    int* bsum  = (int*)alloc(1024 * 4);
    int* eb = (int*)o2;                               // alias: dead ranges don't overlap

    const int chunk = (E + B - 1) / B;
    const int nb2 = (NBK * B + SCAN_TILE - 1) / SCAN_TILE;

    bin_hist_k<<<B, 256, 0, stream>>>(ei + E, E, cntb, NBK, chunk);
    scan_pass1<<<nb2, 256, 0, stream>>>(cntb, bsum, NBK * B);
    scan_pass2<<<1, 256, 0, stream>>>(bsum, obb, nb2, NBK * B);
    scan_pass3<<<nb2, 256, 0, stream>>>(cntb, bsum, obb, NBK * B);
    bin_scatter_k<<<B, 256, 0, stream>>>(ei, E, obb, eb, NBK, chunk);
    bucket_build_k<<<NBK, 256, 0, stream>>>(eb, obb, row_ptr, col, B, N, NBK);

    const int GB = (N + 63) / 64;

    // --- layer 1: 128 -> 64, relu ---
    gemm_mfma_k<128, 64><<<GB, 256, 0, stream>>>(x, W1, a1s, a1d, hb, ss, sd, N);
    gat_agg_k<64, 32, true, false><<<(N + 7) / 8, 256, 0, stream>>>(row_ptr, col, hb, ss, sd, b1, o1, N);

    // --- layer 2: 64 -> 64, relu ---
    gemm_mfma_k<64, 64><<<GB, 256, 0, stream>>>(o1, W2, a2s, a2d, hb, ss, sd, N);
    gat_agg_k<64, 32, true, false><<<(N + 7) / 8, 256, 0, stream>>>(row_ptr, col, hb, ss, sd, b2, o2, N);

    // --- layer 3: 64 -> 32, log_softmax ---
    gemm_mfma_k<64, 32><<<GB, 256, 0, stream>>>(o2, W3, a3s, a3d, hb, ss, sd, N);
    gat_agg_k<32, 16, false, true><<<(N + 15) / 16, 256, 0, stream>>>(row_ptr, col, hb, ss, sd, b3,
                                                                      (float*)d_out, N);
}

// Round 11
// 307.476 us; speedup vs baseline: 3.5675x; 1.0012x over previous
//
#include <hip/hip_runtime.h>
#include <hip/hip_fp16.h>
#include <cstddef>
#include <cstdint>

#define NEG_SLOPE 0.2f

__device__ __forceinline__ unsigned short f2bf(float f) {
    unsigned int u = __float_as_uint(f);
    u = (u + 0x7fff + ((u >> 16) & 1)) >> 16;   // round-to-nearest-even
    return (unsigned short)u;
}
__device__ __forceinline__ float bf_lo(unsigned int u) { return __uint_as_float(u << 16); }
__device__ __forceinline__ float bf_hi(unsigned int u) { return __uint_as_float(u & 0xffff0000u); }

typedef __attribute__((ext_vector_type(8))) short bf16x8;   // MFMA A/B frag (4 VGPRs)
typedef __attribute__((ext_vector_type(4))) float f32x4;    // MFMA C/D frag
typedef __attribute__((ext_vector_type(2))) float f32x2;    // v_pk_fma_f32 pair

// ---------------- binned CSR build ----------------
// Bucket = dst >> 7 (128 nodes/bucket). Edges packed (src<<7)|dstLow (src<2^17).
// Per-(bucket,block) slice offsets via atomicAdd return (order within bucket is
// irrelevant) -> no 200K-element scan; only a 782-entry scan of bucket totals.

constexpr int BIN_BLOCKS = 256;
constexpr int MAX_NBK = 1024;            // supports N <= 131072 (= packing limit)

__global__ __launch_bounds__(256) void zero_k(int* __restrict__ p, int n) {
    int i = blockIdx.x * blockDim.x + threadIdx.x;
    if (i < n) p[i] = 0;
}

__global__ __launch_bounds__(256) void bin_hist_k(const int* __restrict__ dst, int E,
                                                  int* __restrict__ btot,
                                                  int* __restrict__ blkoff,
                                                  int nbk, int chunk) {
    __shared__ int hist[MAX_NBK];
    for (int i = threadIdx.x; i < nbk; i += 256) hist[i] = 0;
    __syncthreads();
    const int lo = blockIdx.x * chunk;
    const int hi = min(lo + chunk, E);
    for (int e = lo + threadIdx.x; e < hi; e += 256)
        atomicAdd(&hist[dst[e] >> 7], 1);
    __syncthreads();
    const int B = gridDim.x;
    for (int i = threadIdx.x; i < nbk; i += 256)
        blkoff[i * B + blockIdx.x] = atomicAdd(&btot[i], hist[i]);
}

// exclusive scan of nbk (<=1024) bucket totals -> obk[nbk+1]
__global__ __launch_bounds__(256) void scan_small_k(const int* __restrict__ btot,
                                                    int* __restrict__ obk, int nbk) {
    __shared__ int sh[MAX_NBK];
    const int tid = threadIdx.x;
    for (int i = tid; i < nbk; i += 256) sh[i] = btot[i];
    __syncthreads();
    if (tid == 0) {
        int run = 0;
        for (int i = 0; i < nbk; ++i) { int c = sh[i]; sh[i] = run; run += c; }
        obk[nbk] = run;                  // total edge count
    }
    __syncthreads();
    for (int i = tid; i < nbk; i += 256) obk[i] = sh[i];
}

// per-block (bucket-base + block-offset) cached in LDS -> per-edge path LDS-only
__global__ __launch_bounds__(256) void bin_scatter_k(const int* __restrict__ ei, int E,
                                                     const int* __restrict__ obk,
                                                     const int* __restrict__ blkoff,
                                                     int* __restrict__ eb, int nbk,
                                                     int chunk) {
    __shared__ int cur[MAX_NBK];
    __shared__ int off_s[MAX_NBK];
    const int B = gridDim.x;
    for (int i = threadIdx.x; i < nbk; i += 256) {
        cur[i] = 0;
        off_s[i] = obk[i] + blkoff[i * B + blockIdx.x];
    }
    __syncthreads();
    const int lo = blockIdx.x * chunk;
    const int hi = min(lo + chunk, E);
    for (int e = lo + threadIdx.x; e < hi; e += 256) {
        int s = ei[e];
        int d = ei[E + e];
        int b = d >> 7;
        int idx = atomicAdd(&cur[b], 1);
        eb[off_s[b] + idx] = (s << 7) | (d & 127);
    }
}

// fused per-bucket build: degrees -> LDS scan -> row_ptr + self-loops + scatter.
__global__ __launch_bounds__(256) void bucket_build_k(const int* __restrict__ eb,
                                                      const int* __restrict__ obk,
                                                      int* __restrict__ row_ptr,
                                                      int* __restrict__ col,
                                                      int n, int nbk) {
    __shared__ int c[128];
    __shared__ int rp[128];
    const int b = blockIdx.x;
    const int t = threadIdx.x;
    const int beg = obk[b];
    const int end = obk[b + 1];
    const int bbase = beg + b * 128;     // preceding buckets are full (128 loops each)
    if (t < 128) c[t] = 1;               // self-loop pre-count
    __syncthreads();
    for (int i = beg + t; i < end; i += 256)
        atomicAdd(&c[eb[i] & 127], 1);
    __syncthreads();
    if (t < 64) {                        // exclusive scan of 128 degrees (wave 0)
        int v0 = c[2 * t], v1 = c[2 * t + 1];
        int pair = v0 + v1;
        int inc = pair;
        for (int o = 1; o < 64; o <<= 1) {
            int u = __shfl_up(inc, o);
            if (t >= o) inc += u;
        }
        int ex = inc - pair;
        rp[2 * t] = bbase + ex;
        rp[2 * t + 1] = bbase + ex + v0;
    }
    __syncthreads();
    const int node = b * 128 + t;
    if (t < 128 && node < n) {
        row_ptr[node] = rp[t];
        col[rp[t]] = node;               // self-loop in slot 0
    }
    if (b == 0 && t == 0) row_ptr[n] = obk[nbk] + n;
    __syncthreads();
    if (t < 128) c[t] = 1;
    __syncthreads();
    for (int i = beg + t; i < end; i += 256) {
        int p = eb[i];
        int dl = p & 127;
        int idx = atomicAdd(&c[dl], 1);
        col[rp[dl] + idx] = p >> 7;
    }
}

// ---------------- dense: MFMA bf16 GEMM -> bf16 h + fused attention dots -------

template <int K, int F>
__launch_bounds__(256)
__global__ void gemm_mfma_k(const float* __restrict__ x, const float* __restrict__ W,
                            const float* __restrict__ a_s, const float* __restrict__ a_d,
                            unsigned short* __restrict__ hb, float* __restrict__ ss,
                            float* __restrict__ sd, int n) {
    constexpr int MT = 64;               // rows per block
    constexpr int KP = K + 8;            // padded inner stride (bf16 elems)
    constexpr int NT = F / 16;           // n-tiles per wave
    constexpr int KC = K / 32;           // k-steps

    __shared__ unsigned short xb[MT * KP];
    __shared__ unsigned short wb[F * KP];

    const int tid = threadIdx.x;
    const int lane = tid & 63;
    const int wv = tid >> 6;             // wave id 0..3
    const int base = blockIdx.x * MT;

    for (int i = tid; i < MT * K / 4; i += 256) {
        int row = i / (K / 4);
        int c4 = i % (K / 4);
        float4 v = make_float4(0.f, 0.f, 0.f, 0.f);
        if (base + row < n)
            v = *(const float4*)&x[(size_t)(base + row) * K + 4 * c4];
        ushort4 b;
        b.x = f2bf(v.x); b.y = f2bf(v.y); b.z = f2bf(v.z); b.w = f2bf(v.w);
        *(ushort4*)&xb[row * KP + 4 * c4] = b;
    }
    for (int i = tid; i < K * F / 4; i += 256) {
        int k = i / (F / 4);
        int n4 = i % (F / 4);
        float4 v = *(const float4*)&W[(size_t)k * F + 4 * n4];
        wb[(4 * n4 + 0) * KP + k] = f2bf(v.x);
        wb[(4 * n4 + 1) * KP + k] = f2bf(v.y);
        wb[(4 * n4 + 2) * KP + k] = f2bf(v.z);
        wb[(4 * n4 + 3) * KP + k] = f2bf(v.w);
    }
    __syncthreads();

    const int mrow = lane & 15;
    const int quad = lane >> 4;

    f32x4 acc[NT];
#pragma unroll
    for (int t = 0; t < NT; ++t) acc[t] = (f32x4){0.f, 0.f, 0.f, 0.f};

#pragma unroll
    for (int kc = 0; kc < KC; ++kc) {
        const int kof = kc * 32 + quad * 8;
        bf16x8 af = *(const bf16x8*)&xb[(wv * 16 + mrow) * KP + kof];
#pragma unroll
        for (int t = 0; t < NT; ++t) {
            bf16x8 bf = *(const bf16x8*)&wb[(t * 16 + mrow) * KP + kof];
            acc[t] = __builtin_amdgcn_mfma_f32_16x16x32_bf16(af, bf, acc[t], 0, 0, 0);
        }
    }

    float as_c[NT], ad_c[NT];
#pragma unroll
    for (int t = 0; t < NT; ++t) { as_c[t] = a_s[t * 16 + mrow]; ad_c[t] = a_d[t * 16 + mrow]; }

#pragma unroll
    for (int r = 0; r < 4; ++r) {
        const int node = base + wv * 16 + quad * 4 + r;
        float ps = 0.f, pd = 0.f;
#pragma unroll
        for (int t = 0; t < NT; ++t) {
            ps = fmaf(acc[t][r], as_c[t], ps);
            pd = fmaf(acc[t][r], ad_c[t], pd);
        }
#pragma unroll
        for (int o = 1; o < 16; o <<= 1) {
            ps += __shfl_xor(ps, o);
            pd += __shfl_xor(pd, o);
        }
        if (node < n) {
#pragma unroll
            for (int t = 0; t < NT; ++t)
                hb[(size_t)node * F + t * 16 + mrow] = f2bf(acc[t][r]);
            if (mrow == 0) { ss[node] = ps; sd[node] = pd; }
        }
    }
}

// ---------------- sparse: softmax aggregation, self-loop-shifted exp ----------
// No online max: w = exp(logit - z0) with z0 = self-loop logit (per-node const,
// distribution-bounded, no overflow in fp32/bf16). Per-lane s accumulated
// locally, single butterfly at the end -> no per-chunk reductions, no cross-
// chunk dependency. Gather: 4 loads in flight, f32x2 (v_pk_fma_f32) accumulate.
// Pack: bf16(w) [sign-free, 15b] in [31:17], src idx (17b) in [16:0].

template <int F, int S, bool RELU, bool LOGSM>
__launch_bounds__(256)
__global__ void gat_agg_k(const int* __restrict__ row_ptr, const int* __restrict__ col,
                          const unsigned short* __restrict__ hb,
                          const float* __restrict__ ss, const float* __restrict__ sd,
                          const float* __restrict__ bias,
                          float* __restrict__ out, int n) {
    constexpr int NPW = 64 / S;          // nodes per wave
    constexpr int NL = F / 8;            // lanes per row (8 bf16 channels each)
    constexpr int Q = S / NL;            // edge slots
    const int lane = threadIdx.x & 63;
    const int ls   = lane % S;           // lane in subgroup
    const int q    = ls / NL;            // edge slot
    const int cl   = ls % NL;            // channel octet index
    const int lbase = lane - ls;         // first lane of subgroup
    const int wave = (blockIdx.x * blockDim.x + threadIdx.x) >> 6;
    const int node = wave * NPW + lane / S;
    if (node >= n) return;

    const int beg = row_ptr[node];
    const int end = row_ptr[node + 1];
    const float sdv = sd[node];
    float z0 = ss[node] + sdv;
    z0 = (z0 > 0.f) ? z0 : NEG_SLOPE * z0;     // self-loop logit = softmax shift

    float s = 0.f;
    f32x2 acc2[4];
#pragma unroll
    for (int i = 0; i < 4; ++i) acc2[i] = (f32x2){0.f, 0.f};

    for (int base = beg; base < end; base += S) {
        const int j = base + ls;
        int   c = 0;
        float logit = -__builtin_inff();
        if (j < end) {
            c = col[j];
            float z = ss[c] + sdv;
            logit = (z > 0.f) ? z : NEG_SLOPE * z;
        }
        const float w = __expf(logit - z0);      // inactive lanes -> 0
        s += w;
        const unsigned int pk = ((unsigned int)f2bf(w) << 17) | (unsigned int)c;

        auto gather = [&](int tt) {
            const unsigned int pe = __shfl(pk, lbase + Q * tt + q);
            const int ct = (int)(pe & 0x1ffffu);
            const float wt = __uint_as_float((pe >> 17) << 16);
            const uint4 hv = *(const uint4*)&hb[(size_t)ct * F + 8 * cl];
            f32x2 p;
            p.x = bf_lo(hv.x); p.y = bf_hi(hv.x); acc2[0] += p * wt;
            p.x = bf_lo(hv.y); p.y = bf_hi(hv.y); acc2[1] += p * wt;
            p.x = bf_lo(hv.z); p.y = bf_hi(hv.z); acc2[2] += p * wt;
            p.x = bf_lo(hv.w); p.y = bf_hi(hv.w); acc2[3] += p * wt;
        };

        const int cnt = min(S, end - base);
        int t = 0;
        for (; Q * (t + 3) < cnt; t += 4) {      // 4 edges/lane in flight
            gather(t); gather(t + 1); gather(t + 2); gather(t + 3);
        }
        for (; Q * (t + 1) < cnt; t += 2) { gather(t); gather(t + 1); }
        if (Q * t < cnt) gather(t);              // tail edges past cnt have w=0
    }

    // reduce s over the whole subgroup; acc across the Q edge slots
#pragma unroll
    for (int o = S / 2; o; o >>= 1) s += __shfl_xor(s, o);
    float val[8] = {acc2[0].x, acc2[0].y, acc2[1].x, acc2[1].y,
                    acc2[2].x, acc2[2].y, acc2[3].x, acc2[3].y};
#pragma unroll
    for (int o = NL; o < S; o <<= 1) {
#pragma unroll
        for (int i = 0; i < 8; ++i) val[i] += __shfl_xor(val[i], o);
    }

    const float inv = 1.f / (s + 1e-16f);
#pragma unroll
    for (int i = 0; i < 8; ++i) {
        val[i] = val[i] * inv + bias[8 * cl + i];
        if (RELU) val[i] = fmaxf(val[i], 0.f);
    }
    if (LOGSM) {
        float lm = val[0];
#pragma unroll
        for (int i = 1; i < 8; ++i) lm = fmaxf(lm, val[i]);
#pragma unroll
        for (int o = 1; o < NL; o <<= 1) lm = fmaxf(lm, __shfl_xor(lm, o));
        float ex = 0.f;
#pragma unroll
        for (int i = 0; i < 8; ++i) ex += __expf(val[i] - lm);
#pragma unroll
        for (int o = 1; o < NL; o <<= 1) ex += __shfl_xor(ex, o);
        const float lse = lm + __logf(ex);
#pragma unroll
        for (int i = 0; i < 8; ++i) val[i] -= lse;
    }
    if (q == 0) {
        float4 v0 = make_float4(val[0], val[1], val[2], val[3]);
        float4 v1 = make_float4(val[4], val[5], val[6], val[7]);
        *(float4*)&out[(size_t)node * F + 8 * cl] = v0;
        *(float4*)&out[(size_t)node * F + 8 * cl + 4] = v1;
    }
}

// ---------------- launch ----------------

extern "C" void kernel_launch(void* const* d_in, const int* in_sizes, int n_in,
                              void* d_out, int out_size, void* d_ws, size_t ws_size,
                              hipStream_t stream) {
    const float* x  = (const float*)d_in[0];
    const int*   ei = (const int*)d_in[1];
    const float* W1 = (const float*)d_in[2];
    const float* a1s = (const float*)d_in[3];
    const float* a1d = (const float*)d_in[4];
    const float* b1  = (const float*)d_in[5];
    const float* W2 = (const float*)d_in[6];
    const float* a2s = (const float*)d_in[7];
    const float* a2d = (const float*)d_in[8];
    const float* b2  = (const float*)d_in[9];
    const float* W3 = (const float*)d_in[10];
    const float* a3s = (const float*)d_in[11];
    const float* a3d = (const float*)d_in[12];
    const float* b3  = (const float*)d_in[13];

    const int N = in_sizes[0] / 128;
    const int E = in_sizes[1] / 2;
    const int NBK = (N + 127) / 128;
    const int B = BIN_BLOCKS;

    char* wp = (char*)d_ws;
    auto alloc = [&](size_t bytes) -> void* {
        void* p = wp;
        wp += (bytes + 255) & ~(size_t)255;
        return p;
    };
    int* row_ptr = (int*)alloc((size_t)(N + 1) * 4);
    int* col     = (int*)alloc((size_t)(E + N) * 4);
    unsigned short* hb = (unsigned short*)alloc((size_t)N * 64 * 2);
    float* ss  = (float*)alloc((size_t)N * 4);
    float* sd  = (float*)alloc((size_t)N * 4);
    float* o1  = (float*)alloc((size_t)N * 64 * 4);
    float* o2  = (float*)alloc((size_t)N * 64 * 4);
    int* btot   = (int*)alloc((size_t)NBK * 4);
    int* blkoff = (int*)alloc((size_t)NBK * B * 4);
    int* obk    = (int*)alloc((size_t)(NBK + 1) * 4);
    int* eb = (int*)o2;                               // alias: dead ranges don't overlap

    const int chunk = (E + B - 1) / B;

    zero_k<<<(NBK + 255) / 256, 256, 0, stream>>>(btot, NBK);
    bin_hist_k<<<B, 256, 0, stream>>>(ei + E, E, btot, blkoff, NBK, chunk);
    scan_small_k<<<1, 256, 0, stream>>>(btot, obk, NBK);
    bin_scatter_k<<<B, 256, 0, stream>>>(ei, E, obk, blkoff, eb, NBK, chunk);
    bucket_build_k<<<NBK, 256, 0, stream>>>(eb, obk, row_ptr, col, N, NBK);

    const int GB = (N + 63) / 64;

    // --- layer 1: 128 -> 64, relu ---
    gemm_mfma_k<128, 64><<<GB, 256, 0, stream>>>(x, W1, a1s, a1d, hb, ss, sd, N);
    gat_agg_k<64, 32, true, false><<<(N + 7) / 8, 256, 0, stream>>>(row_ptr, col, hb, ss, sd, b1, o1, N);

    // --- layer 2: 64 -> 64, relu ---
    gemm_mfma_k<64, 64><<<GB, 256, 0, stream>>>(o1, W2, a2s, a2d, hb, ss, sd, N);
    gat_agg_k<64, 32, true, false><<<(N + 7) / 8, 256, 0, stream>>>(row_ptr, col, hb, ss, sd, b2, o2, N);

    // --- layer 3: 64 -> 32, log_softmax ---
    gemm_mfma_k<64, 32><<<GB, 256, 0, stream>>>(o2, W3, a3s, a3d, hb, ss, sd, N);
    gat_agg_k<32, 16, false, true><<<(N + 15) / 16, 256, 0, stream>>>(row_ptr, col, hb, ss, sd, b3,
                                                                      (float*)d_out, N);
}

// Round 12
// 305.322 us; speedup vs baseline: 3.5927x; 1.0071x over previous
//
#include <hip/hip_runtime.h>
#include <hip/hip_fp16.h>
#include <cstddef>
#include <cstdint>

#define NEG_SLOPE 0.2f

__device__ __forceinline__ unsigned short f2bf(float f) {
    unsigned int u = __float_as_uint(f);
    u = (u + 0x7fff + ((u >> 16) & 1)) >> 16;   // round-to-nearest-even
    return (unsigned short)u;
}
__device__ __forceinline__ float bf_lo(unsigned int u) { return __uint_as_float(u << 16); }
__device__ __forceinline__ float bf_hi(unsigned int u) { return __uint_as_float(u & 0xffff0000u); }

typedef __attribute__((ext_vector_type(8))) short bf16x8;   // MFMA A/B frag (4 VGPRs)
typedef __attribute__((ext_vector_type(4))) float f32x4;    // MFMA C/D frag
typedef __attribute__((ext_vector_type(2))) float f32x2;    // v_pk_fma_f32 pair

// ---------------- binned CSR build ----------------
// Bucket = dst >> 7 (128 nodes/bucket). Edges packed (src<<7)|dstLow (src<2^17).
// Per-(bucket,block) slice offsets via atomicAdd return; only a 782-entry scan
// of bucket totals.

constexpr int BIN_BLOCKS = 256;
constexpr int MAX_NBK = 1024;            // supports N <= 131072 (= packing limit)

__global__ __launch_bounds__(256) void zero_k(int* __restrict__ p, int n) {
    int i = blockIdx.x * blockDim.x + threadIdx.x;
    if (i < n) p[i] = 0;
}

__global__ __launch_bounds__(256) void bin_hist_k(const int* __restrict__ dst, int E,
                                                  int* __restrict__ btot,
                                                  int* __restrict__ blkoff,
                                                  int nbk, int chunk) {
    __shared__ int hist[MAX_NBK];
    for (int i = threadIdx.x; i < nbk; i += 256) hist[i] = 0;
    __syncthreads();
    const int lo = blockIdx.x * chunk;
    const int hi = min(lo + chunk, E);
    for (int e = lo + threadIdx.x; e < hi; e += 256)
        atomicAdd(&hist[dst[e] >> 7], 1);
    __syncthreads();
    const int B = gridDim.x;
    for (int i = threadIdx.x; i < nbk; i += 256)
        blkoff[i * B + blockIdx.x] = atomicAdd(&btot[i], hist[i]);
}

// exclusive scan of nbk (<=1024) bucket totals -> obk[nbk+1]
__global__ __launch_bounds__(256) void scan_small_k(const int* __restrict__ btot,
                                                    int* __restrict__ obk, int nbk) {
    __shared__ int sh[MAX_NBK];
    const int tid = threadIdx.x;
    for (int i = tid; i < nbk; i += 256) sh[i] = btot[i];
    __syncthreads();
    if (tid == 0) {
        int run = 0;
        for (int i = 0; i < nbk; ++i) { int c = sh[i]; sh[i] = run; run += c; }
        obk[nbk] = run;                  // total edge count
    }
    __syncthreads();
    for (int i = tid; i < nbk; i += 256) obk[i] = sh[i];
}

// per-block (bucket-base + block-offset) cached in LDS -> per-edge path LDS-only
__global__ __launch_bounds__(256) void bin_scatter_k(const int* __restrict__ ei, int E,
                                                     const int* __restrict__ obk,
                                                     const int* __restrict__ blkoff,
                                                     int* __restrict__ eb, int nbk,
                                                     int chunk) {
    __shared__ int cur[MAX_NBK];
    __shared__ int off_s[MAX_NBK];
    const int B = gridDim.x;
    for (int i = threadIdx.x; i < nbk; i += 256) {
        cur[i] = 0;
        off_s[i] = obk[i] + blkoff[i * B + blockIdx.x];
    }
    __syncthreads();
    const int lo = blockIdx.x * chunk;
    const int hi = min(lo + chunk, E);
    for (int e = lo + threadIdx.x; e < hi; e += 256) {
        int s = ei[e];
        int d = ei[E + e];
        int b = d >> 7;
        int idx = atomicAdd(&cur[b], 1);
        eb[off_s[b] + idx] = (s << 7) | (d & 127);
    }
}

// fused per-bucket build: degrees -> LDS scan -> row_ptr + self-loops + scatter.
__global__ __launch_bounds__(256) void bucket_build_k(const int* __restrict__ eb,
                                                      const int* __restrict__ obk,
                                                      int* __restrict__ row_ptr,
                                                      int* __restrict__ col,
                                                      int n, int nbk) {
    __shared__ int c[128];
    __shared__ int rp[128];
    const int b = blockIdx.x;
    const int t = threadIdx.x;
    const int beg = obk[b];
    const int end = obk[b + 1];
    const int bbase = beg + b * 128;     // preceding buckets are full (128 loops each)
    if (t < 128) c[t] = 1;               // self-loop pre-count
    __syncthreads();
    for (int i = beg + t; i < end; i += 256)
        atomicAdd(&c[eb[i] & 127], 1);
    __syncthreads();
    if (t < 64) {                        // exclusive scan of 128 degrees (wave 0)
        int v0 = c[2 * t], v1 = c[2 * t + 1];
        int pair = v0 + v1;
        int inc = pair;
        for (int o = 1; o < 64; o <<= 1) {
            int u = __shfl_up(inc, o);
            if (t >= o) inc += u;
        }
        int ex = inc - pair;
        rp[2 * t] = bbase + ex;
        rp[2 * t + 1] = bbase + ex + v0;
    }
    __syncthreads();
    const int node = b * 128 + t;
    if (t < 128 && node < n) {
        row_ptr[node] = rp[t];
        col[rp[t]] = node;               // self-loop in slot 0
    }
    if (b == 0 && t == 0) row_ptr[n] = obk[nbk] + n;
    __syncthreads();
    if (t < 128) c[t] = 1;
    __syncthreads();
    for (int i = beg + t; i < end; i += 256) {
        int p = eb[i];
        int dl = p & 127;
        int idx = atomicAdd(&c[dl], 1);
        col[rp[dl] + idx] = p >> 7;
    }
}

// ---------------- dense: MFMA bf16 GEMM -> bf16 h + fused attention dots -------
// BIN: input already bf16 (copy-stage, no convert); else fp32 -> bf16 stage.

template <int K, int F, bool BIN>
__launch_bounds__(256)
__global__ void gemm_mfma_k(const void* __restrict__ xin, const float* __restrict__ W,
                            const float* __restrict__ a_s, const float* __restrict__ a_d,
                            unsigned short* __restrict__ hb, float* __restrict__ ss,
                            float* __restrict__ sd, int n) {
    constexpr int MT = 64;               // rows per block
    constexpr int KP = K + 8;            // padded inner stride (bf16 elems)
    constexpr int NT = F / 16;           // n-tiles per wave
    constexpr int KC = K / 32;           // k-steps

    __shared__ unsigned short xb[MT * KP];
    __shared__ unsigned short wb[F * KP];

    const int tid = threadIdx.x;
    const int lane = tid & 63;
    const int wv = tid >> 6;             // wave id 0..3
    const int base = blockIdx.x * MT;

    if (BIN) {
        const unsigned short* x = (const unsigned short*)xin;
        for (int i = tid; i < MT * K / 8; i += 256) {
            int row = i / (K / 8);
            int c8 = i % (K / 8);
            uint4 v = make_uint4(0u, 0u, 0u, 0u);
            if (base + row < n)
                v = *(const uint4*)&x[(size_t)(base + row) * K + 8 * c8];
            *(uint4*)&xb[row * KP + 8 * c8] = v;
        }
    } else {
        const float* x = (const float*)xin;
        for (int i = tid; i < MT * K / 4; i += 256) {
            int row = i / (K / 4);
            int c4 = i % (K / 4);
            float4 v = make_float4(0.f, 0.f, 0.f, 0.f);
            if (base + row < n)
                v = *(const float4*)&x[(size_t)(base + row) * K + 4 * c4];
            ushort4 b;
            b.x = f2bf(v.x); b.y = f2bf(v.y); b.z = f2bf(v.z); b.w = f2bf(v.w);
            *(ushort4*)&xb[row * KP + 4 * c4] = b;
        }
    }
    for (int i = tid; i < K * F / 4; i += 256) {
        int k = i / (F / 4);
        int n4 = i % (F / 4);
        float4 v = *(const float4*)&W[(size_t)k * F + 4 * n4];
        wb[(4 * n4 + 0) * KP + k] = f2bf(v.x);
        wb[(4 * n4 + 1) * KP + k] = f2bf(v.y);
        wb[(4 * n4 + 2) * KP + k] = f2bf(v.z);
        wb[(4 * n4 + 3) * KP + k] = f2bf(v.w);
    }
    __syncthreads();

    const int mrow = lane & 15;
    const int quad = lane >> 4;

    f32x4 acc[NT];
#pragma unroll
    for (int t = 0; t < NT; ++t) acc[t] = (f32x4){0.f, 0.f, 0.f, 0.f};

#pragma unroll
    for (int kc = 0; kc < KC; ++kc) {
        const int kof = kc * 32 + quad * 8;
        bf16x8 af = *(const bf16x8*)&xb[(wv * 16 + mrow) * KP + kof];
#pragma unroll
        for (int t = 0; t < NT; ++t) {
            bf16x8 bf = *(const bf16x8*)&wb[(t * 16 + mrow) * KP + kof];
            acc[t] = __builtin_amdgcn_mfma_f32_16x16x32_bf16(af, bf, acc[t], 0, 0, 0);
        }
    }

    float as_c[NT], ad_c[NT];
#pragma unroll
    for (int t = 0; t < NT; ++t) { as_c[t] = a_s[t * 16 + mrow]; ad_c[t] = a_d[t * 16 + mrow]; }

#pragma unroll
    for (int r = 0; r < 4; ++r) {
        const int node = base + wv * 16 + quad * 4 + r;
        float ps = 0.f, pd = 0.f;
#pragma unroll
        for (int t = 0; t < NT; ++t) {
            ps = fmaf(acc[t][r], as_c[t], ps);
            pd = fmaf(acc[t][r], ad_c[t], pd);
        }
#pragma unroll
        for (int o = 1; o < 16; o <<= 1) {
            ps += __shfl_xor(ps, o);
            pd += __shfl_xor(pd, o);
        }
        if (node < n) {
#pragma unroll
            for (int t = 0; t < NT; ++t)
                hb[(size_t)node * F + t * 16 + mrow] = f2bf(acc[t][r]);
            if (mrow == 0) { ss[node] = ps; sd[node] = pd; }
        }
    }
}

// ---------------- sparse: softmax aggregation, self-loop-shifted exp ----------
// OUTB: write bf16 (intermediate layers) vs fp32 (final output).

template <int F, int S, bool RELU, bool LOGSM, bool OUTB>
__launch_bounds__(256)
__global__ void gat_agg_k(const int* __restrict__ row_ptr, const int* __restrict__ col,
                          const unsigned short* __restrict__ hb,
                          const float* __restrict__ ss, const float* __restrict__ sd,
                          const float* __restrict__ bias,
                          void* __restrict__ outv, int n) {
    constexpr int NPW = 64 / S;          // nodes per wave
    constexpr int NL = F / 8;            // lanes per row (8 bf16 channels each)
    constexpr int Q = S / NL;            // edge slots
    const int lane = threadIdx.x & 63;
    const int ls   = lane % S;           // lane in subgroup
    const int q    = ls / NL;            // edge slot
    const int cl   = ls % NL;            // channel octet index
    const int lbase = lane - ls;         // first lane of subgroup
    const int wave = (blockIdx.x * blockDim.x + threadIdx.x) >> 6;
    const int node = wave * NPW + lane / S;
    if (node >= n) return;

    const int beg = row_ptr[node];
    const int end = row_ptr[node + 1];
    const float sdv = sd[node];
    float z0 = ss[node] + sdv;
    z0 = (z0 > 0.f) ? z0 : NEG_SLOPE * z0;     // self-loop logit = softmax shift

    float s = 0.f;
    f32x2 acc2[4];
#pragma unroll
    for (int i = 0; i < 4; ++i) acc2[i] = (f32x2){0.f, 0.f};

    for (int base = beg; base < end; base += S) {
        const int j = base + ls;
        int   c = 0;
        float logit = -__builtin_inff();
        if (j < end) {
            c = col[j];
            float z = ss[c] + sdv;
            logit = (z > 0.f) ? z : NEG_SLOPE * z;
        }
        const float w = __expf(logit - z0);      // inactive lanes -> 0
        s += w;
        const unsigned int pk = ((unsigned int)f2bf(w) << 17) | (unsigned int)c;

        auto gather = [&](int tt) {
            const unsigned int pe = __shfl(pk, lbase + Q * tt + q);
            const int ct = (int)(pe & 0x1ffffu);
            const float wt = __uint_as_float((pe >> 17) << 16);
            const uint4 hv = *(const uint4*)&hb[(size_t)ct * F + 8 * cl];
            f32x2 p;
            p.x = bf_lo(hv.x); p.y = bf_hi(hv.x); acc2[0] += p * wt;
            p.x = bf_lo(hv.y); p.y = bf_hi(hv.y); acc2[1] += p * wt;
            p.x = bf_lo(hv.z); p.y = bf_hi(hv.z); acc2[2] += p * wt;
            p.x = bf_lo(hv.w); p.y = bf_hi(hv.w); acc2[3] += p * wt;
        };

        const int cnt = min(S, end - base);
        int t = 0;
        for (; Q * (t + 3) < cnt; t += 4) {      // 4 edges/lane in flight
            gather(t); gather(t + 1); gather(t + 2); gather(t + 3);
        }
        for (; Q * (t + 1) < cnt; t += 2) { gather(t); gather(t + 1); }
        if (Q * t < cnt) gather(t);              // tail edges past cnt have w=0
    }

    // reduce s over the whole subgroup; acc across the Q edge slots
#pragma unroll
    for (int o = S / 2; o; o >>= 1) s += __shfl_xor(s, o);
    float val[8] = {acc2[0].x, acc2[0].y, acc2[1].x, acc2[1].y,
                    acc2[2].x, acc2[2].y, acc2[3].x, acc2[3].y};
#pragma unroll
    for (int o = NL; o < S; o <<= 1) {
#pragma unroll
        for (int i = 0; i < 8; ++i) val[i] += __shfl_xor(val[i], o);
    }

    const float inv = 1.f / (s + 1e-16f);
#pragma unroll
    for (int i = 0; i < 8; ++i) {
        val[i] = val[i] * inv + bias[8 * cl + i];
        if (RELU) val[i] = fmaxf(val[i], 0.f);
    }
    if (LOGSM) {
        float lm = val[0];
#pragma unroll
        for (int i = 1; i < 8; ++i) lm = fmaxf(lm, val[i]);
#pragma unroll
        for (int o = 1; o < NL; o <<= 1) lm = fmaxf(lm, __shfl_xor(lm, o));
        float ex = 0.f;
#pragma unroll
        for (int i = 0; i < 8; ++i) ex += __expf(val[i] - lm);
#pragma unroll
        for (int o = 1; o < NL; o <<= 1) ex += __shfl_xor(ex, o);
        const float lse = lm + __logf(ex);
#pragma unroll
        for (int i = 0; i < 8; ++i) val[i] -= lse;
    }
    if (q == 0) {
        if (OUTB) {
            unsigned short* out = (unsigned short*)outv;
            ushort4 p0, p1;
            p0.x = f2bf(val[0]); p0.y = f2bf(val[1]); p0.z = f2bf(val[2]); p0.w = f2bf(val[3]);
            p1.x = f2bf(val[4]); p1.y = f2bf(val[5]); p1.z = f2bf(val[6]); p1.w = f2bf(val[7]);
            *(ushort4*)&out[(size_t)node * F + 8 * cl] = p0;
            *(ushort4*)&out[(size_t)node * F + 8 * cl + 4] = p1;
        } else {
            float* out = (float*)outv;
            float4 v0 = make_float4(val[0], val[1], val[2], val[3]);
            float4 v1 = make_float4(val[4], val[5], val[6], val[7]);
            *(float4*)&out[(size_t)node * F + 8 * cl] = v0;
            *(float4*)&out[(size_t)node * F + 8 * cl + 4] = v1;
        }
    }
}

// ---------------- launch ----------------

extern "C" void kernel_launch(void* const* d_in, const int* in_sizes, int n_in,
                              void* d_out, int out_size, void* d_ws, size_t ws_size,
                              hipStream_t stream) {
    const float* x  = (const float*)d_in[0];
    const int*   ei = (const int*)d_in[1];
    const float* W1 = (const float*)d_in[2];
    const float* a1s = (const float*)d_in[3];
    const float* a1d = (const float*)d_in[4];
    const float* b1  = (const float*)d_in[5];
    const float* W2 = (const float*)d_in[6];
    const float* a2s = (const float*)d_in[7];
    const float* a2d = (const float*)d_in[8];
    const float* b2  = (const float*)d_in[9];
    const float* W3 = (const float*)d_in[10];
    const float* a3s = (const float*)d_in[11];
    const float* a3d = (const float*)d_in[12];
    const float* b3  = (const float*)d_in[13];

    const int N = in_sizes[0] / 128;
    const int E = in_sizes[1] / 2;
    const int NBK = (N + 127) / 128;
    const int B = BIN_BLOCKS;

    char* wp = (char*)d_ws;
    auto alloc = [&](size_t bytes) -> void* {
        void* p = wp;
        wp += (bytes + 255) & ~(size_t)255;
        return p;
    };
    int* row_ptr = (int*)alloc((size_t)(N + 1) * 4);
    int* col     = (int*)alloc((size_t)(E + N) * 4);
    unsigned short* hb  = (unsigned short*)alloc((size_t)N * 64 * 2);
    float* ss  = (float*)alloc((size_t)N * 4);
    float* sd  = (float*)alloc((size_t)N * 4);
    unsigned short* o1b = (unsigned short*)alloc((size_t)N * 64 * 2);
    unsigned short* o2b = (unsigned short*)alloc((size_t)N * 64 * 2);
    int* btot   = (int*)alloc((size_t)NBK * 4);
    int* blkoff = (int*)alloc((size_t)NBK * B * 4);
    int* obk    = (int*)alloc((size_t)(NBK + 1) * 4);
    int* eb     = (int*)alloc((size_t)E * 4);   // no aliasing (o2b smaller now)

    const int chunk = (E + B - 1) / B;

    zero_k<<<(NBK + 255) / 256, 256, 0, stream>>>(btot, NBK);
    bin_hist_k<<<B, 256, 0, stream>>>(ei + E, E, btot, blkoff, NBK, chunk);
    scan_small_k<<<1, 256, 0, stream>>>(btot, obk, NBK);
    bin_scatter_k<<<B, 256, 0, stream>>>(ei, E, obk, blkoff, eb, NBK, chunk);
    bucket_build_k<<<NBK, 256, 0, stream>>>(eb, obk, row_ptr, col, N, NBK);

    const int GB = (N + 63) / 64;

    // --- layer 1: 128 -> 64, relu ---
    gemm_mfma_k<128, 64, false><<<GB, 256, 0, stream>>>(x, W1, a1s, a1d, hb, ss, sd, N);
    gat_agg_k<64, 32, true, false, true><<<(N + 7) / 8, 256, 0, stream>>>(
        row_ptr, col, hb, ss, sd, b1, o1b, N);

    // --- layer 2: 64 -> 64, relu ---
    gemm_mfma_k<64, 64, true><<<GB, 256, 0, stream>>>(o1b, W2, a2s, a2d, hb, ss, sd, N);
    gat_agg_k<64, 32, true, false, true><<<(N + 7) / 8, 256, 0, stream>>>(
        row_ptr, col, hb, ss, sd, b2, o2b, N);

    // --- layer 3: 64 -> 32, log_softmax ---
    gemm_mfma_k<64, 32, true><<<GB, 256, 0, stream>>>(o2b, W3, a3s, a3d, hb, ss, sd, N);
    gat_agg_k<32, 16, false, true, false><<<(N + 15) / 16, 256, 0, stream>>>(
        row_ptr, col, hb, ss, sd, b3, d_out, N);
}